// Round 1
// baseline (3518.699 us; speedup 1.0000x reference)
//
#include <hip/hip_runtime.h>
#include <hip/hip_bf16.h>

// Problem constants (from reference): B=2, T=2048, D=1024, H=16, G=4, K=64, F=4096
#define EPSF 1e-6f
constexpr int Bsz  = 2;
constexpr int Tseq = 2048;
constexpr int Dmod = 1024;
constexpr int Hh   = 16;
constexpr int Gg   = 4;
constexpr int Kdim = 64;
constexpr int Ff   = 4096;
constexpr int Mrows = Bsz * Tseq;            // 4096 tokens

// ---------------------------------------------------------------------------
// RMSNorm over D=1024: one 256-thread block per token, float4 per thread.
// ---------------------------------------------------------------------------
__global__ __launch_bounds__(256) void rmsnorm_kernel(
    const float* __restrict__ x, const float* __restrict__ scale,
    float* __restrict__ out)
{
    const int row = blockIdx.x;
    const int tid = threadIdx.x;
    const float4* x4 = reinterpret_cast<const float4*>(x + (size_t)row * Dmod);
    float4 v = x4[tid];
    float ss = v.x * v.x + v.y * v.y + v.z * v.z + v.w * v.w;
    #pragma unroll
    for (int off = 32; off; off >>= 1) ss += __shfl_xor(ss, off, 64);
    __shared__ float part[4];
    if ((tid & 63) == 0) part[tid >> 6] = ss;
    __syncthreads();
    const float tot = part[0] + part[1] + part[2] + part[3];
    const float rstd = rsqrtf(tot * (1.0f / Dmod) + EPSF);
    const float4 sc = reinterpret_cast<const float4*>(scale)[tid];
    float4 o;
    o.x = v.x * rstd * sc.x;
    o.y = v.y * rstd * sc.y;
    o.z = v.z * rstd * sc.z;
    o.w = v.w * rstd * sc.w;
    reinterpret_cast<float4*>(out + (size_t)row * Dmod)[tid] = o;
}

// ---------------------------------------------------------------------------
// Tiled fp32 GEMM: C[M,N] = A[M,Kd] @ B[Kd,N] (+ residual). BM=BN=64, BK=16,
// 256 threads, 4x4 microtile. As transposed [k][m] with +4 pad (16B-aligned
// rows, conflict-free b128 reads); Bs natural [k][n].
// ---------------------------------------------------------------------------
template <int RES>
__global__ __launch_bounds__(256) void gemm_kernel(
    const float* __restrict__ A, const float* __restrict__ Bw,
    const float* __restrict__ res, float* __restrict__ C,
    int M, int N, int Kd)
{
    __shared__ float As[16][68];   // [k][m], pad 4 -> row stride 272B = 17*16B
    __shared__ float Bs[16][64];   // [k][n]

    const int tid = threadIdx.x;
    const int tx = tid & 15, ty = tid >> 4;
    const int n0 = blockIdx.x * 64, m0 = blockIdx.y * 64;

    const int la_m = tid >> 2;            // A tile row (0..63)
    const int la_k = (tid & 3) * 4;       // A tile k quad
    const int lb_k = tid >> 4;            // B tile k (0..15)
    const int lb_n = (tid & 15) * 4;      // B tile n quad

    const float* Ap = A + (size_t)(m0 + la_m) * Kd + la_k;
    const float* Bp = Bw + (size_t)lb_k * N + n0 + lb_n;

    float acc[4][4] = {};

    for (int k0 = 0; k0 < Kd; k0 += 16) {
        const float4 av = *reinterpret_cast<const float4*>(Ap + k0);
        const float4 bv = *reinterpret_cast<const float4*>(Bp + (size_t)k0 * N);
        __syncthreads();
        As[la_k + 0][la_m] = av.x;
        As[la_k + 1][la_m] = av.y;
        As[la_k + 2][la_m] = av.z;
        As[la_k + 3][la_m] = av.w;
        *reinterpret_cast<float4*>(&Bs[lb_k][lb_n]) = bv;
        __syncthreads();
        #pragma unroll
        for (int kk = 0; kk < 16; ++kk) {
            const float4 a = *reinterpret_cast<const float4*>(&As[kk][ty * 4]);
            const float4 b = *reinterpret_cast<const float4*>(&Bs[kk][tx * 4]);
            const float aa[4] = {a.x, a.y, a.z, a.w};
            const float bb[4] = {b.x, b.y, b.z, b.w};
            #pragma unroll
            for (int i = 0; i < 4; ++i)
                #pragma unroll
                for (int j = 0; j < 4; ++j)
                    acc[i][j] = fmaf(aa[i], bb[j], acc[i][j]);
        }
    }

    #pragma unroll
    for (int i = 0; i < 4; ++i) {
        const size_t off = (size_t)(m0 + ty * 4 + i) * N + n0 + tx * 4;
        float4 r = make_float4(acc[i][0], acc[i][1], acc[i][2], acc[i][3]);
        if (RES) {
            const float4 rv = *reinterpret_cast<const float4*>(res + off);
            r.x += rv.x; r.y += rv.y; r.z += rv.z; r.w += rv.w;
        }
        *reinterpret_cast<float4*>(C + off) = r;
    }
}

// ---------------------------------------------------------------------------
// Fused gate/up GEMM + silu(g)*u epilogue. Same tiling as gemm_kernel but two
// B operands sharing the A tile.
// ---------------------------------------------------------------------------
__global__ __launch_bounds__(256) void gateup_kernel(
    const float* __restrict__ A, const float* __restrict__ Wg,
    const float* __restrict__ Wu, float* __restrict__ C,
    int M, int N, int Kd)
{
    __shared__ float As[16][68];
    __shared__ float Gs[16][64];
    __shared__ float Us[16][64];

    const int tid = threadIdx.x;
    const int tx = tid & 15, ty = tid >> 4;
    const int n0 = blockIdx.x * 64, m0 = blockIdx.y * 64;

    const int la_m = tid >> 2;
    const int la_k = (tid & 3) * 4;
    const int lb_k = tid >> 4;
    const int lb_n = (tid & 15) * 4;

    const float* Ap = A + (size_t)(m0 + la_m) * Kd + la_k;
    const float* Gp = Wg + (size_t)lb_k * N + n0 + lb_n;
    const float* Up = Wu + (size_t)lb_k * N + n0 + lb_n;

    float accg[4][4] = {};
    float accu[4][4] = {};

    for (int k0 = 0; k0 < Kd; k0 += 16) {
        const float4 av = *reinterpret_cast<const float4*>(Ap + k0);
        const float4 gv = *reinterpret_cast<const float4*>(Gp + (size_t)k0 * N);
        const float4 uv = *reinterpret_cast<const float4*>(Up + (size_t)k0 * N);
        __syncthreads();
        As[la_k + 0][la_m] = av.x;
        As[la_k + 1][la_m] = av.y;
        As[la_k + 2][la_m] = av.z;
        As[la_k + 3][la_m] = av.w;
        *reinterpret_cast<float4*>(&Gs[lb_k][lb_n]) = gv;
        *reinterpret_cast<float4*>(&Us[lb_k][lb_n]) = uv;
        __syncthreads();
        #pragma unroll
        for (int kk = 0; kk < 16; ++kk) {
            const float4 a = *reinterpret_cast<const float4*>(&As[kk][ty * 4]);
            const float4 g = *reinterpret_cast<const float4*>(&Gs[kk][tx * 4]);
            const float4 u = *reinterpret_cast<const float4*>(&Us[kk][tx * 4]);
            const float aa[4] = {a.x, a.y, a.z, a.w};
            const float gg[4] = {g.x, g.y, g.z, g.w};
            const float uu[4] = {u.x, u.y, u.z, u.w};
            #pragma unroll
            for (int i = 0; i < 4; ++i)
                #pragma unroll
                for (int j = 0; j < 4; ++j) {
                    accg[i][j] = fmaf(aa[i], gg[j], accg[i][j]);
                    accu[i][j] = fmaf(aa[i], uu[j], accu[i][j]);
                }
        }
    }

    #pragma unroll
    for (int i = 0; i < 4; ++i) {
        float4 r;
        float* rp = &r.x;
        #pragma unroll
        for (int j = 0; j < 4; ++j) {
            const float g = accg[i][j];
            const float sig = 1.0f / (1.0f + __expf(-g));
            rp[j] = g * sig * accu[i][j];
        }
        const size_t off = (size_t)(m0 + ty * 4 + i) * N + n0 + tx * 4;
        *reinterpret_cast<float4*>(C + off) = r;
    }
}

// ---------------------------------------------------------------------------
// Fused per-head RMSNorm (over K=64) + RoPE. One wave per (token, head).
// Lane l holds element l; partner via shfl_xor(32).
// ---------------------------------------------------------------------------
__global__ __launch_bounds__(256) void qknorm_rope_kernel(
    float* __restrict__ x, const float* __restrict__ nsc,
    const float* __restrict__ sinp, const float* __restrict__ cosp, int NH)
{
    const int lane = threadIdx.x & 63;
    const int w = threadIdx.x >> 6;
    const int head = blockIdx.x * 4 + w;            // (b*T + t)*NH + h
    const int bt = head / NH;                       // b*T + t
    const size_t base = (size_t)head * 64;

    const float v = x[base + lane];
    float ss = v * v;
    #pragma unroll
    for (int off = 32; off; off >>= 1) ss += __shfl_xor(ss, off, 64);
    const float rstd = rsqrtf(ss * (1.0f / 64.0f) + EPSF);
    const float nv = v * rstd * nsc[lane];

    const float p = __shfl_xor(nv, 32, 64);
    const float s = sinp[(size_t)bt * 32 + (lane & 31)];
    const float c = cosp[(size_t)bt * 32 + (lane & 31)];
    const float o = (lane < 32) ? (nv * c - p * s) : (nv * c + p * s);
    x[base + lane] = o;
}

// ---------------------------------------------------------------------------
// Flash-style causal attention, fp32. Block = 256 thr, Br=64 q-rows, Bc=32
// keys/iter. GQA: head h uses kv group h/4. Scale (K^-0.5) folded into Q load.
// LDS ~42 KB. Grid: (T/64, B*H).
// ---------------------------------------------------------------------------
__global__ __launch_bounds__(256) void attn_kernel(
    const float* __restrict__ Q, const float* __restrict__ Kb,
    const float* __restrict__ V, float* __restrict__ O)
{
    __shared__ float Qs[64 * 65];     // [r][k] pad 65
    __shared__ float Ks[32 * 65];     // [s][k] pad 65
    __shared__ float Vs[32 * 64];     // [s][k] no pad
    __shared__ float Ss[64 * 33];     // [r][c] pad 33
    __shared__ float m_s[64], l_s[64], al_s[64];

    const int tid = threadIdx.x;
    const int tx = tid & 15, ty = tid >> 4;
    const int q0 = blockIdx.x * 64;
    const int bh = blockIdx.y;
    const int b = bh / Hh, h = bh % Hh, g = h >> 2;   // R = 4

    // Load Q tile scaled by K^-0.5
    #pragma unroll
    for (int i = 0; i < 16; ++i) {
        const int e = tid + i * 256;
        const int r = e >> 6, c = e & 63;
        Qs[r * 65 + c] =
            Q[((size_t)((b * Tseq + q0 + r) * Hh + h)) * 64 + c] * 0.125f;
    }
    if (tid < 64) { m_s[tid] = -1e30f; l_s[tid] = 0.0f; }

    float o_acc[4][4] = {};
    const int ntiles = (q0 >> 5) + 2;

    for (int it = 0; it < ntiles; ++it) {
        const int s0 = it * 32;
        __syncthreads();   // protect prior-iter LDS / Q-tile+stats init
        #pragma unroll
        for (int i = 0; i < 8; ++i) {
            const int e = tid + i * 256;
            const int r = e >> 6, c = e & 63;
            const size_t gi = ((size_t)((b * Tseq + s0 + r) * Gg + g)) * 64 + c;
            Ks[r * 65 + c] = Kb[gi];
            Vs[r * 64 + c] = V[gi];
        }
        __syncthreads();

        // S = Q @ K^T  (rows ty*4.., cols tx*2..)
        float sacc[4][2] = {};
        #pragma unroll
        for (int k = 0; k < 64; ++k) {
            float a[4], bb[2];
            #pragma unroll
            for (int i = 0; i < 4; ++i) a[i] = Qs[(ty * 4 + i) * 65 + k];
            #pragma unroll
            for (int j = 0; j < 2; ++j) bb[j] = Ks[(tx * 2 + j) * 65 + k];
            #pragma unroll
            for (int i = 0; i < 4; ++i)
                #pragma unroll
                for (int j = 0; j < 2; ++j)
                    sacc[i][j] = fmaf(a[i], bb[j], sacc[i][j]);
        }
        // masked store to LDS
        #pragma unroll
        for (int i = 0; i < 4; ++i)
            #pragma unroll
            for (int j = 0; j < 2; ++j) {
                const int r_g = q0 + ty * 4 + i;
                const int c_g = s0 + tx * 2 + j;
                Ss[(ty * 4 + i) * 33 + tx * 2 + j] =
                    (c_g > r_g) ? -1e30f : sacc[i][j];
            }
        __syncthreads();

        // row max + alpha
        if (tid < 64) {
            float mx = m_s[tid];
            #pragma unroll 8
            for (int c = 0; c < 32; ++c) mx = fmaxf(mx, Ss[tid * 33 + c]);
            al_s[tid] = __expf(m_s[tid] - mx);
            m_s[tid] = mx;
        }
        __syncthreads();

        // exponentiate in place (all 256 threads)
        #pragma unroll
        for (int i = 0; i < 8; ++i) {
            const int e = tid + i * 256;
            const int r = e >> 5, c = e & 31;
            Ss[r * 33 + c] = __expf(Ss[r * 33 + c] - m_s[r]);
        }
        __syncthreads();

        // row sum -> l
        if (tid < 64) {
            float sum = 0.0f;
            #pragma unroll 8
            for (int c = 0; c < 32; ++c) sum += Ss[tid * 33 + c];
            l_s[tid] = l_s[tid] * al_s[tid] + sum;
        }
        __syncthreads();

        // rescale O, accumulate P @ V
        #pragma unroll
        for (int i = 0; i < 4; ++i) {
            const float al = al_s[ty * 4 + i];
            #pragma unroll
            for (int j = 0; j < 4; ++j) o_acc[i][j] *= al;
        }
        #pragma unroll 8
        for (int c = 0; c < 32; ++c) {
            float p[4], vv[4];
            #pragma unroll
            for (int i = 0; i < 4; ++i) p[i] = Ss[(ty * 4 + i) * 33 + c];
            #pragma unroll
            for (int j = 0; j < 4; ++j) vv[j] = Vs[c * 64 + tx * 4 + j];
            #pragma unroll
            for (int i = 0; i < 4; ++i)
                #pragma unroll
                for (int j = 0; j < 4; ++j)
                    o_acc[i][j] = fmaf(p[i], vv[j], o_acc[i][j]);
        }
    }
    __syncthreads();   // l_s final values

    #pragma unroll
    for (int i = 0; i < 4; ++i) {
        const float inv_l = 1.0f / l_s[ty * 4 + i];
        #pragma unroll
        for (int j = 0; j < 4; ++j) {
            O[((size_t)((b * Tseq + q0 + ty * 4 + i) * Hh + h)) * 64 +
              tx * 4 + j] = o_acc[i][j] * inv_l;
        }
    }
}

// ---------------------------------------------------------------------------
// Host launcher
// ---------------------------------------------------------------------------
extern "C" void kernel_launch(void* const* d_in, const int* in_sizes, int n_in,
                              void* d_out, int out_size, void* d_ws,
                              size_t ws_size, hipStream_t stream)
{
    const float* hidden = (const float*)d_in[0];
    const float* sinp   = (const float*)d_in[1];
    const float* cosp   = (const float*)d_in[2];
    // d_in[3] = mask (bool) — causal, handled analytically
    const float* ln1    = (const float*)d_in[4];
    const float* ln2    = (const float*)d_in[5];
    const float* qn     = (const float*)d_in[6];
    const float* kn     = (const float*)d_in[7];
    const float* q_w    = (const float*)d_in[8];
    const float* k_w    = (const float*)d_in[9];
    const float* v_w    = (const float*)d_in[10];
    const float* o_w    = (const float*)d_in[11];
    const float* gate_w = (const float*)d_in[12];
    const float* up_w   = (const float*)d_in[13];
    const float* down_w = (const float*)d_in[14];
    float* out = (float*)d_out;

    // Workspace layout (floats). Total 30M floats = 120 MB.
    float* ws = (float*)d_ws;
    const size_t M4 = (size_t)1 << 22;   // 4M floats = 16 MB
    float* X  = ws;                      // x = rmsnorm(hidden)        [4M]
    float* Qb = ws + M4;                 // q proj                     [4M]
    float* Kb = ws + 2 * M4;             // k proj                     [1M]
    float* Vb = Kb + (M4 >> 2);          // v proj                     [1M]
    float* Y  = ws + (size_t)10 * (M4 >> 2); // rmsnorm(hidden2)       [4M]
    float* FF = ws + (size_t)14 * (M4 >> 2); // silu(g)*u              [16M]
    float* Ab = X;                       // attention out (reuse X)
    float* H2 = Qb;                      // hidden + attn@o_w (reuse Q)

    // 1. x = rmsnorm(hidden, ln1)
    rmsnorm_kernel<<<Mrows, 256, 0, stream>>>(hidden, ln1, X);

    // 2. q/k/v projections
    gemm_kernel<0><<<dim3(Hh * Kdim / 64, Mrows / 64), 256, 0, stream>>>(
        X, q_w, nullptr, Qb, Mrows, Hh * Kdim, Dmod);
    gemm_kernel<0><<<dim3(Gg * Kdim / 64, Mrows / 64), 256, 0, stream>>>(
        X, k_w, nullptr, Kb, Mrows, Gg * Kdim, Dmod);
    gemm_kernel<0><<<dim3(Gg * Kdim / 64, Mrows / 64), 256, 0, stream>>>(
        X, v_w, nullptr, Vb, Mrows, Gg * Kdim, Dmod);

    // 3. per-head RMSNorm + RoPE (in place)
    qknorm_rope_kernel<<<Mrows * Hh / 4, 256, 0, stream>>>(Qb, qn, sinp, cosp, Hh);
    qknorm_rope_kernel<<<Mrows * Gg / 4, 256, 0, stream>>>(Kb, kn, sinp, cosp, Gg);

    // 4. causal attention
    attn_kernel<<<dim3(Tseq / 64, Bsz * Hh), 256, 0, stream>>>(Qb, Kb, Vb, Ab);

    // 5. hidden2 = hidden + attn @ o_w
    gemm_kernel<1><<<dim3(Dmod / 64, Mrows / 64), 256, 0, stream>>>(
        Ab, o_w, hidden, H2, Mrows, Dmod, Hh * Kdim);

    // 6. y = rmsnorm(hidden2, ln2)
    rmsnorm_kernel<<<Mrows, 256, 0, stream>>>(H2, ln2, Y);

    // 7. ff = silu(y@gate_w) * (y@up_w)
    gateup_kernel<<<dim3(Ff / 64, Mrows / 64), 256, 0, stream>>>(
        Y, gate_w, up_w, FF, Mrows, Ff, Dmod);

    // 8. out = hidden2 + ff @ down_w
    gemm_kernel<1><<<dim3(Dmod / 64, Mrows / 64), 256, 0, stream>>>(
        FF, down_w, H2, out, Mrows, Dmod, Ff);
}

// Round 2
// 2837.204 us; speedup vs baseline: 1.2402x; 1.2402x over previous
//
#include <hip/hip_runtime.h>
#include <hip/hip_bf16.h>

// Problem constants (from reference): B=2, T=2048, D=1024, H=16, G=4, K=64, F=4096
#define EPSF 1e-6f
constexpr int Bsz  = 2;
constexpr int Tseq = 2048;
constexpr int Dmod = 1024;
constexpr int Hh   = 16;
constexpr int Gg   = 4;
constexpr int Kdim = 64;
constexpr int Ff   = 4096;
constexpr int Mrows = Bsz * Tseq;            // 4096 tokens

// ---------------------------------------------------------------------------
// RMSNorm over D=1024: one 256-thread block per token, float4 per thread.
// ---------------------------------------------------------------------------
__global__ __launch_bounds__(256) void rmsnorm_kernel(
    const float* __restrict__ x, const float* __restrict__ scale,
    float* __restrict__ out)
{
    const int row = blockIdx.x;
    const int tid = threadIdx.x;
    const float4* x4 = reinterpret_cast<const float4*>(x + (size_t)row * Dmod);
    float4 v = x4[tid];
    float ss = v.x * v.x + v.y * v.y + v.z * v.z + v.w * v.w;
    #pragma unroll
    for (int off = 32; off; off >>= 1) ss += __shfl_xor(ss, off, 64);
    __shared__ float part[4];
    if ((tid & 63) == 0) part[tid >> 6] = ss;
    __syncthreads();
    const float tot = part[0] + part[1] + part[2] + part[3];
    const float rstd = rsqrtf(tot * (1.0f / Dmod) + EPSF);
    const float4 sc = reinterpret_cast<const float4*>(scale)[tid];
    float4 o;
    o.x = v.x * rstd * sc.x;
    o.y = v.y * rstd * sc.y;
    o.z = v.z * rstd * sc.z;
    o.w = v.w * rstd * sc.w;
    reinterpret_cast<float4*>(out + (size_t)row * Dmod)[tid] = o;
}

// ---------------------------------------------------------------------------
// Tiled fp32 GEMM: C[M,N] = A[M,Kd] @ B[Kd,N] (+ residual). BM=BN=64, BK=16,
// 256 threads, 4x4 microtile.
// ---------------------------------------------------------------------------
template <int RES>
__global__ __launch_bounds__(256) void gemm_kernel(
    const float* __restrict__ A, const float* __restrict__ Bw,
    const float* __restrict__ res, float* __restrict__ C,
    int M, int N, int Kd)
{
    __shared__ float As[16][68];   // [k][m], pad 4 -> row stride 272B = 17*16B
    __shared__ float Bs[16][64];   // [k][n]

    const int tid = threadIdx.x;
    const int tx = tid & 15, ty = tid >> 4;
    const int n0 = blockIdx.x * 64, m0 = blockIdx.y * 64;

    const int la_m = tid >> 2;            // A tile row (0..63)
    const int la_k = (tid & 3) * 4;       // A tile k quad
    const int lb_k = tid >> 4;            // B tile k (0..15)
    const int lb_n = (tid & 15) * 4;      // B tile n quad

    const float* Ap = A + (size_t)(m0 + la_m) * Kd + la_k;
    const float* Bp = Bw + (size_t)lb_k * N + n0 + lb_n;

    float acc[4][4] = {};

    for (int k0 = 0; k0 < Kd; k0 += 16) {
        const float4 av = *reinterpret_cast<const float4*>(Ap + k0);
        const float4 bv = *reinterpret_cast<const float4*>(Bp + (size_t)k0 * N);
        __syncthreads();
        As[la_k + 0][la_m] = av.x;
        As[la_k + 1][la_m] = av.y;
        As[la_k + 2][la_m] = av.z;
        As[la_k + 3][la_m] = av.w;
        *reinterpret_cast<float4*>(&Bs[lb_k][lb_n]) = bv;
        __syncthreads();
        #pragma unroll
        for (int kk = 0; kk < 16; ++kk) {
            const float4 a = *reinterpret_cast<const float4*>(&As[kk][ty * 4]);
            const float4 b = *reinterpret_cast<const float4*>(&Bs[kk][tx * 4]);
            const float aa[4] = {a.x, a.y, a.z, a.w};
            const float bb[4] = {b.x, b.y, b.z, b.w};
            #pragma unroll
            for (int i = 0; i < 4; ++i)
                #pragma unroll
                for (int j = 0; j < 4; ++j)
                    acc[i][j] = fmaf(aa[i], bb[j], acc[i][j]);
        }
    }

    #pragma unroll
    for (int i = 0; i < 4; ++i) {
        const size_t off = (size_t)(m0 + ty * 4 + i) * N + n0 + tx * 4;
        float4 r = make_float4(acc[i][0], acc[i][1], acc[i][2], acc[i][3]);
        if (RES) {
            const float4 rv = *reinterpret_cast<const float4*>(res + off);
            r.x += rv.x; r.y += rv.y; r.z += rv.z; r.w += rv.w;
        }
        *reinterpret_cast<float4*>(C + off) = r;
    }
}

// ---------------------------------------------------------------------------
// Fused gate/up GEMM + silu(g)*u epilogue.
// ---------------------------------------------------------------------------
__global__ __launch_bounds__(256) void gateup_kernel(
    const float* __restrict__ A, const float* __restrict__ Wg,
    const float* __restrict__ Wu, float* __restrict__ C,
    int M, int N, int Kd)
{
    __shared__ float As[16][68];
    __shared__ float Gs[16][64];
    __shared__ float Us[16][64];

    const int tid = threadIdx.x;
    const int tx = tid & 15, ty = tid >> 4;
    const int n0 = blockIdx.x * 64, m0 = blockIdx.y * 64;

    const int la_m = tid >> 2;
    const int la_k = (tid & 3) * 4;
    const int lb_k = tid >> 4;
    const int lb_n = (tid & 15) * 4;

    const float* Ap = A + (size_t)(m0 + la_m) * Kd + la_k;
    const float* Gp = Wg + (size_t)lb_k * N + n0 + lb_n;
    const float* Up = Wu + (size_t)lb_k * N + n0 + lb_n;

    float accg[4][4] = {};
    float accu[4][4] = {};

    for (int k0 = 0; k0 < Kd; k0 += 16) {
        const float4 av = *reinterpret_cast<const float4*>(Ap + k0);
        const float4 gv = *reinterpret_cast<const float4*>(Gp + (size_t)k0 * N);
        const float4 uv = *reinterpret_cast<const float4*>(Up + (size_t)k0 * N);
        __syncthreads();
        As[la_k + 0][la_m] = av.x;
        As[la_k + 1][la_m] = av.y;
        As[la_k + 2][la_m] = av.z;
        As[la_k + 3][la_m] = av.w;
        *reinterpret_cast<float4*>(&Gs[lb_k][lb_n]) = gv;
        *reinterpret_cast<float4*>(&Us[lb_k][lb_n]) = uv;
        __syncthreads();
        #pragma unroll
        for (int kk = 0; kk < 16; ++kk) {
            const float4 a = *reinterpret_cast<const float4*>(&As[kk][ty * 4]);
            const float4 g = *reinterpret_cast<const float4*>(&Gs[kk][tx * 4]);
            const float4 u = *reinterpret_cast<const float4*>(&Us[kk][tx * 4]);
            const float aa[4] = {a.x, a.y, a.z, a.w};
            const float gg[4] = {g.x, g.y, g.z, g.w};
            const float uu[4] = {u.x, u.y, u.z, u.w};
            #pragma unroll
            for (int i = 0; i < 4; ++i)
                #pragma unroll
                for (int j = 0; j < 4; ++j) {
                    accg[i][j] = fmaf(aa[i], gg[j], accg[i][j]);
                    accu[i][j] = fmaf(aa[i], uu[j], accu[i][j]);
                }
        }
    }

    #pragma unroll
    for (int i = 0; i < 4; ++i) {
        float4 r;
        float* rp = &r.x;
        #pragma unroll
        for (int j = 0; j < 4; ++j) {
            const float g = accg[i][j];
            const float sig = 1.0f / (1.0f + __expf(-g));
            rp[j] = g * sig * accu[i][j];
        }
        const size_t off = (size_t)(m0 + ty * 4 + i) * N + n0 + tx * 4;
        *reinterpret_cast<float4*>(C + off) = r;
    }
}

// ---------------------------------------------------------------------------
// Fused per-head RMSNorm (over K=64) + RoPE. One wave per (token, head).
// ---------------------------------------------------------------------------
__global__ __launch_bounds__(256) void qknorm_rope_kernel(
    float* __restrict__ x, const float* __restrict__ nsc,
    const float* __restrict__ sinp, const float* __restrict__ cosp, int NH)
{
    const int lane = threadIdx.x & 63;
    const int w = threadIdx.x >> 6;
    const int head = blockIdx.x * 4 + w;            // (b*T + t)*NH + h
    const int bt = head / NH;                       // b*T + t
    const size_t base = (size_t)head * 64;

    const float v = x[base + lane];
    float ss = v * v;
    #pragma unroll
    for (int off = 32; off; off >>= 1) ss += __shfl_xor(ss, off, 64);
    const float rstd = rsqrtf(ss * (1.0f / 64.0f) + EPSF);
    const float nv = v * rstd * nsc[lane];

    const float p = __shfl_xor(nv, 32, 64);
    const float s = sinp[(size_t)bt * 32 + (lane & 31)];
    const float c = cosp[(size_t)bt * 32 + (lane & 31)];
    const float o = (lane < 32) ? (nv * c - p * s) : (nv * c + p * s);
    x[base + lane] = o;
}

// ---------------------------------------------------------------------------
// Flash-style causal attention v2, fp32.
// Br=Bc=64, 256 threads as 16x16 grid, 4x4 microtile/thread.
// All LDS traffic is aligned b128 (row pad 68 floats = 17*16B).
// Softmax stats (m,l) live in registers, reduced across the 16-lane row
// group with __shfl_xor(width=16) -- no LDS, no partial-thread phases.
// 3 barriers per key tile. Per-element mask only on the diagonal tile.
// Grid: (T/64, B*H). GQA: head h -> kv group h/4. Scale folded into Q.
// ---------------------------------------------------------------------------
__global__ __launch_bounds__(256) void attn_kernel(
    const float* __restrict__ Q, const float* __restrict__ Kb,
    const float* __restrict__ V, float* __restrict__ O)
{
    __shared__ float Qs[64][68];
    __shared__ float Ks[64][68];
    __shared__ float Vs[64][68];
    __shared__ float Ss[64][68];

    const int tid = threadIdx.x;
    const int tx = tid & 15;          // col group (0..15) -> cols tx*4..tx*4+3
    const int ty = tid >> 4;          // row group (0..15) -> rows ty*4..ty*4+3
    const int q0 = blockIdx.x * 64;
    const int bh = blockIdx.y;
    const int b = bh / Hh, h = bh % Hh, g = h >> 2;   // R = 4

    const int lr = tid >> 4;          // load row base (0..15)
    const int lc = (tid & 15) * 4;    // load col quad

    // Load Q tile (scaled by K^-0.5) into LDS. Visible after first barrier.
    #pragma unroll
    for (int p = 0; p < 4; ++p) {
        const int r = lr + p * 16;
        const float4 qv = *reinterpret_cast<const float4*>(
            &Q[((size_t)((b * Tseq + q0 + r) * Hh + h)) * 64 + lc]);
        float4 qs;
        qs.x = qv.x * 0.125f; qs.y = qv.y * 0.125f;
        qs.z = qv.z * 0.125f; qs.w = qv.w * 0.125f;
        *reinterpret_cast<float4*>(&Qs[r][lc]) = qs;
    }

    float o_acc[4][4] = {};
    float m_r[4], l_r[4];
    #pragma unroll
    for (int i = 0; i < 4; ++i) { m_r[i] = -1e30f; l_r[i] = 0.0f; }

    const int ntiles = blockIdx.x + 1;   // full tiles + diagonal

    for (int it = 0; it < ntiles; ++it) {
        const int s0 = it * 64;
        const bool diag = (it == ntiles - 1);

        // Prefetch K/V tile into registers (overlaps other waves' PV).
        float4 kr[4], vr[4];
        #pragma unroll
        for (int p = 0; p < 4; ++p) {
            const int r = lr + p * 16;
            const size_t gi =
                ((size_t)((b * Tseq + s0 + r) * Gg + g)) * 64 + lc;
            kr[p] = *reinterpret_cast<const float4*>(&Kb[gi]);
            vr[p] = *reinterpret_cast<const float4*>(&V[gi]);
        }

        __syncthreads();   // prior iter done reading Ks/Vs/Ss
        #pragma unroll
        for (int p = 0; p < 4; ++p) {
            const int r = lr + p * 16;
            *reinterpret_cast<float4*>(&Ks[r][lc]) = kr[p];
            *reinterpret_cast<float4*>(&Vs[r][lc]) = vr[p];
        }
        __syncthreads();   // K/V (and Q on iter 0) visible

        // S = Q @ K^T, 4x4 per thread, b128 LDS reads.
        float sacc[4][4] = {};
        #pragma unroll
        for (int kq = 0; kq < 16; ++kq) {
            float4 qv[4], kv[4];
            #pragma unroll
            for (int i = 0; i < 4; ++i)
                qv[i] = *reinterpret_cast<const float4*>(&Qs[ty * 4 + i][kq * 4]);
            #pragma unroll
            for (int j = 0; j < 4; ++j)
                kv[j] = *reinterpret_cast<const float4*>(&Ks[tx * 4 + j][kq * 4]);
            #pragma unroll
            for (int i = 0; i < 4; ++i)
                #pragma unroll
                for (int j = 0; j < 4; ++j) {
                    sacc[i][j] = fmaf(qv[i].x, kv[j].x, sacc[i][j]);
                    sacc[i][j] = fmaf(qv[i].y, kv[j].y, sacc[i][j]);
                    sacc[i][j] = fmaf(qv[i].z, kv[j].z, sacc[i][j]);
                    sacc[i][j] = fmaf(qv[i].w, kv[j].w, sacc[i][j]);
                }
        }

        if (diag) {
            #pragma unroll
            for (int i = 0; i < 4; ++i)
                #pragma unroll
                for (int j = 0; j < 4; ++j)
                    if (tx * 4 + j > ty * 4 + i) sacc[i][j] = -1e30f;
        }

        // Online softmax, stats in registers (row group = 16 consecutive lanes)
        #pragma unroll
        for (int i = 0; i < 4; ++i) {
            float mx = fmaxf(fmaxf(sacc[i][0], sacc[i][1]),
                             fmaxf(sacc[i][2], sacc[i][3]));
            #pragma unroll
            for (int off = 1; off < 16; off <<= 1)
                mx = fmaxf(mx, __shfl_xor(mx, off, 16));
            const float mnew = fmaxf(m_r[i], mx);
            const float alpha = __expf(m_r[i] - mnew);
            m_r[i] = mnew;

            float4 pv;
            pv.x = __expf(sacc[i][0] - mnew);
            pv.y = __expf(sacc[i][1] - mnew);
            pv.z = __expf(sacc[i][2] - mnew);
            pv.w = __expf(sacc[i][3] - mnew);
            float rs = pv.x + pv.y + pv.z + pv.w;
            #pragma unroll
            for (int off = 1; off < 16; off <<= 1)
                rs += __shfl_xor(rs, off, 16);
            l_r[i] = l_r[i] * alpha + rs;

            #pragma unroll
            for (int j = 0; j < 4; ++j) o_acc[i][j] *= alpha;
            *reinterpret_cast<float4*>(&Ss[ty * 4 + i][tx * 4]) = pv;
        }
        __syncthreads();   // P visible

        // O += P @ V, 4x4 per thread, b128 LDS reads.
        #pragma unroll
        for (int cq = 0; cq < 16; ++cq) {
            float4 pr[4], vv[4];
            #pragma unroll
            for (int i = 0; i < 4; ++i)
                pr[i] = *reinterpret_cast<const float4*>(&Ss[ty * 4 + i][cq * 4]);
            #pragma unroll
            for (int jj = 0; jj < 4; ++jj)
                vv[jj] = *reinterpret_cast<const float4*>(&Vs[cq * 4 + jj][tx * 4]);
            #pragma unroll
            for (int i = 0; i < 4; ++i) {
                const float pe[4] = {pr[i].x, pr[i].y, pr[i].z, pr[i].w};
                #pragma unroll
                for (int jj = 0; jj < 4; ++jj) {
                    o_acc[i][0] = fmaf(pe[jj], vv[jj].x, o_acc[i][0]);
                    o_acc[i][1] = fmaf(pe[jj], vv[jj].y, o_acc[i][1]);
                    o_acc[i][2] = fmaf(pe[jj], vv[jj].z, o_acc[i][2]);
                    o_acc[i][3] = fmaf(pe[jj], vv[jj].w, o_acc[i][3]);
                }
            }
        }
    }

    // Epilogue: normalize and store (coalesced float4).
    #pragma unroll
    for (int i = 0; i < 4; ++i) {
        const float inv_l = 1.0f / l_r[i];
        float4 o;
        o.x = o_acc[i][0] * inv_l;
        o.y = o_acc[i][1] * inv_l;
        o.z = o_acc[i][2] * inv_l;
        o.w = o_acc[i][3] * inv_l;
        *reinterpret_cast<float4*>(
            &O[((size_t)((b * Tseq + q0 + ty * 4 + i) * Hh + h)) * 64 +
               tx * 4]) = o;
    }
}

// ---------------------------------------------------------------------------
// Host launcher
// ---------------------------------------------------------------------------
extern "C" void kernel_launch(void* const* d_in, const int* in_sizes, int n_in,
                              void* d_out, int out_size, void* d_ws,
                              size_t ws_size, hipStream_t stream)
{
    const float* hidden = (const float*)d_in[0];
    const float* sinp   = (const float*)d_in[1];
    const float* cosp   = (const float*)d_in[2];
    // d_in[3] = mask (bool) — causal, handled analytically
    const float* ln1    = (const float*)d_in[4];
    const float* ln2    = (const float*)d_in[5];
    const float* qn     = (const float*)d_in[6];
    const float* kn     = (const float*)d_in[7];
    const float* q_w    = (const float*)d_in[8];
    const float* k_w    = (const float*)d_in[9];
    const float* v_w    = (const float*)d_in[10];
    const float* o_w    = (const float*)d_in[11];
    const float* gate_w = (const float*)d_in[12];
    const float* up_w   = (const float*)d_in[13];
    const float* down_w = (const float*)d_in[14];
    float* out = (float*)d_out;

    // Workspace layout (floats). Total 30M floats = 120 MB.
    float* ws = (float*)d_ws;
    const size_t M4 = (size_t)1 << 22;   // 4M floats = 16 MB
    float* X  = ws;                      // x = rmsnorm(hidden)        [4M]
    float* Qb = ws + M4;                 // q proj                     [4M]
    float* Kb = ws + 2 * M4;             // k proj                     [1M]
    float* Vb = Kb + (M4 >> 2);          // v proj                     [1M]
    float* Y  = ws + (size_t)10 * (M4 >> 2); // rmsnorm(hidden2)       [4M]
    float* FF = ws + (size_t)14 * (M4 >> 2); // silu(g)*u              [16M]
    float* Ab = X;                       // attention out (reuse X)
    float* H2 = Qb;                      // hidden + attn@o_w (reuse Q)

    // 1. x = rmsnorm(hidden, ln1)
    rmsnorm_kernel<<<Mrows, 256, 0, stream>>>(hidden, ln1, X);

    // 2. q/k/v projections
    gemm_kernel<0><<<dim3(Hh * Kdim / 64, Mrows / 64), 256, 0, stream>>>(
        X, q_w, nullptr, Qb, Mrows, Hh * Kdim, Dmod);
    gemm_kernel<0><<<dim3(Gg * Kdim / 64, Mrows / 64), 256, 0, stream>>>(
        X, k_w, nullptr, Kb, Mrows, Gg * Kdim, Dmod);
    gemm_kernel<0><<<dim3(Gg * Kdim / 64, Mrows / 64), 256, 0, stream>>>(
        X, v_w, nullptr, Vb, Mrows, Gg * Kdim, Dmod);

    // 3. per-head RMSNorm + RoPE (in place)
    qknorm_rope_kernel<<<Mrows * Hh / 4, 256, 0, stream>>>(Qb, qn, sinp, cosp, Hh);
    qknorm_rope_kernel<<<Mrows * Gg / 4, 256, 0, stream>>>(Kb, kn, sinp, cosp, Gg);

    // 4. causal attention
    attn_kernel<<<dim3(Tseq / 64, Bsz * Hh), 256, 0, stream>>>(Qb, Kb, Vb, Ab);

    // 5. hidden2 = hidden + attn @ o_w
    gemm_kernel<1><<<dim3(Dmod / 64, Mrows / 64), 256, 0, stream>>>(
        Ab, o_w, hidden, H2, Mrows, Dmod, Hh * Kdim);

    // 6. y = rmsnorm(hidden2, ln2)
    rmsnorm_kernel<<<Mrows, 256, 0, stream>>>(H2, ln2, Y);

    // 7. ff = silu(y@gate_w) * (y@up_w)
    gateup_kernel<<<dim3(Ff / 64, Mrows / 64), 256, 0, stream>>>(
        Y, gate_w, up_w, FF, Mrows, Ff, Dmod);

    // 8. out = hidden2 + ff @ down_w
    gemm_kernel<1><<<dim3(Dmod / 64, Mrows / 64), 256, 0, stream>>>(
        FF, down_w, H2, out, Mrows, Dmod, Ff);
}

// Round 3
// 1935.973 us; speedup vs baseline: 1.8175x; 1.4655x over previous
//
#include <hip/hip_runtime.h>
#include <hip/hip_bf16.h>

// Problem constants: B=2, T=2048, D=1024, H=16, G=4, K=64, F=4096
#define EPSF 1e-6f
constexpr int Bsz  = 2;
constexpr int Tseq = 2048;
constexpr int Dmod = 1024;
constexpr int Hh   = 16;
constexpr int Gg   = 4;
constexpr int Ff   = 4096;
constexpr int Mrows = Bsz * Tseq;          // 4096 tokens
constexpr int QKVN = 1536;                 // fused q(1024)|k(256)|v(256)

typedef __attribute__((ext_vector_type(8))) short bf16x8;   // 8 bf16 (4 VGPRs)
typedef __attribute__((ext_vector_type(4))) float f32x4;
typedef unsigned short u16;

// RNE fp32 -> bf16 (bit pattern as u16)
__device__ inline u16 f2bf(float x) {
    union { float f; unsigned u; } v; v.f = x;
    unsigned r = v.u + 0x7fff + ((v.u >> 16) & 1);
    return (u16)(r >> 16);
}
__device__ inline float bf2f(u16 h) {
    union { unsigned u; float f; } v; v.u = ((unsigned)h) << 16; return v.f;
}

// ---------------------------------------------------------------------------
// Weight prep: W[Kd][N] fp32 -> Th[N][Kd] bf16 (hi) and optional Tl (lo).
// 32x32 LDS transpose tiles. Grid (N/32, Kd/32), 256 threads.
// ---------------------------------------------------------------------------
template <int LO>
__global__ __launch_bounds__(256) void wprep_kernel(
    const float* __restrict__ W, u16* __restrict__ Th, u16* __restrict__ Tl,
    int Kd, int N)
{
    __shared__ float tile[32][33];
    const int n0 = blockIdx.x * 32, k0 = blockIdx.y * 32;
    const int r = threadIdx.x >> 3, c4 = (threadIdx.x & 7) * 4;
    const float4 v = *reinterpret_cast<const float4*>(&W[(size_t)(k0 + r) * N + n0 + c4]);
    tile[r][c4 + 0] = v.x; tile[r][c4 + 1] = v.y;
    tile[r][c4 + 2] = v.z; tile[r][c4 + 3] = v.w;
    __syncthreads();
    const int nl = threadIdx.x >> 3, kq = (threadIdx.x & 7) * 4;
    float x0 = tile[kq + 0][nl], x1 = tile[kq + 1][nl];
    float x2 = tile[kq + 2][nl], x3 = tile[kq + 3][nl];
    ushort4 h;
    h.x = f2bf(x0); h.y = f2bf(x1); h.z = f2bf(x2); h.w = f2bf(x3);
    *reinterpret_cast<ushort4*>(&Th[(size_t)(n0 + nl) * Kd + k0 + kq]) = h;
    if (LO) {
        ushort4 l;
        l.x = f2bf(x0 - bf2f(h.x)); l.y = f2bf(x1 - bf2f(h.y));
        l.z = f2bf(x2 - bf2f(h.z)); l.w = f2bf(x3 - bf2f(h.w));
        *reinterpret_cast<ushort4*>(&Tl[(size_t)(n0 + nl) * Kd + k0 + kq]) = l;
    }
}

// ---------------------------------------------------------------------------
// RMSNorm over D=1024 -> bf16 hi (+ optional lo). One block per token.
// ---------------------------------------------------------------------------
template <int LO>
__global__ __launch_bounds__(256) void rmsnorm_split_kernel(
    const float* __restrict__ x, const float* __restrict__ scale,
    u16* __restrict__ oh, u16* __restrict__ ol)
{
    const int row = blockIdx.x;
    const int tid = threadIdx.x;
    const float4 v = reinterpret_cast<const float4*>(x + (size_t)row * Dmod)[tid];
    float ss = v.x * v.x + v.y * v.y + v.z * v.z + v.w * v.w;
    #pragma unroll
    for (int off = 32; off; off >>= 1) ss += __shfl_xor(ss, off, 64);
    __shared__ float part[4];
    if ((tid & 63) == 0) part[tid >> 6] = ss;
    __syncthreads();
    const float tot = part[0] + part[1] + part[2] + part[3];
    const float rstd = rsqrtf(tot * (1.0f / Dmod) + EPSF);
    const float4 sc = reinterpret_cast<const float4*>(scale)[tid];
    float o0 = v.x * rstd * sc.x, o1 = v.y * rstd * sc.y;
    float o2 = v.z * rstd * sc.z, o3 = v.w * rstd * sc.w;
    ushort4 h;
    h.x = f2bf(o0); h.y = f2bf(o1); h.z = f2bf(o2); h.w = f2bf(o3);
    *reinterpret_cast<ushort4*>(&oh[(size_t)row * Dmod + tid * 4]) = h;
    if (LO) {
        ushort4 l;
        l.x = f2bf(o0 - bf2f(h.x)); l.y = f2bf(o1 - bf2f(h.y));
        l.z = f2bf(o2 - bf2f(h.z)); l.w = f2bf(o3 - bf2f(h.w));
        *reinterpret_cast<ushort4*>(&ol[(size_t)row * Dmod + tid * 4]) = l;
    }
}

// ---------------------------------------------------------------------------
// Split-bf16 MFMA GEMM: C[M][N] fp32 = A @ B (+res).
// A as bf16 hi(/lo) [M][Kd]; B as bf16 hi(/lo) [N][Kd] (pre-transposed).
// 128x128 tile, 256 thr = 4 waves (2x2 of 64x64), 16x16x32 MFMA, BK=32.
// Split: C ~= Ah*Bh + Ah*Bl + Al*Bh  (fp32-quality).
// ---------------------------------------------------------------------------
template <int ASPLIT, int BSPLIT, int RES>
__global__ __launch_bounds__(256) void mfma_gemm_kernel(
    const u16* __restrict__ Ah, const u16* __restrict__ Al,
    const u16* __restrict__ Bh, const u16* __restrict__ Bl,
    const float* __restrict__ res, float* __restrict__ C,
    int M, int N, int Kd)
{
    __shared__ u16 As_h[128 * 32];
    __shared__ u16 As_l[128 * 32];
    __shared__ u16 Bs_h[128 * 32];
    __shared__ u16 Bs_l[128 * 32];

    const int tid = threadIdx.x;
    const int lane = tid & 63, wave = tid >> 6;
    const int wm = (wave >> 1) * 64, wn = (wave & 1) * 64;
    const int m0 = blockIdx.y * 128, n0 = blockIdx.x * 128;
    const int fm = lane & 15, fq = (lane >> 4) * 8;

    f32x4 acc[4][4];
    #pragma unroll
    for (int i = 0; i < 4; ++i)
        #pragma unroll
        for (int j = 0; j < 4; ++j) acc[i][j] = (f32x4){0.f, 0.f, 0.f, 0.f};

    const int sr = tid >> 2, sq = (tid & 3) * 8;   // staging: 64 rows/pass, 8-col quads

    for (int k0 = 0; k0 < Kd; k0 += 32) {
        __syncthreads();
        #pragma unroll
        for (int p = 0; p < 2; ++p) {
            const int row = sr + p * 64;
            const size_t ga = (size_t)(m0 + row) * Kd + k0 + sq;
            const size_t gb = (size_t)(n0 + row) * Kd + k0 + sq;
            const int ls = row * 32 + sq;
            *reinterpret_cast<uint4*>(&As_h[ls]) =
                *reinterpret_cast<const uint4*>(&Ah[ga]);
            if (ASPLIT)
                *reinterpret_cast<uint4*>(&As_l[ls]) =
                    *reinterpret_cast<const uint4*>(&Al[ga]);
            *reinterpret_cast<uint4*>(&Bs_h[ls]) =
                *reinterpret_cast<const uint4*>(&Bh[gb]);
            if (BSPLIT)
                *reinterpret_cast<uint4*>(&Bs_l[ls]) =
                    *reinterpret_cast<const uint4*>(&Bl[gb]);
        }
        __syncthreads();

        bf16x8 ah[4], al[4], bh[4], bl[4];
        #pragma unroll
        for (int t = 0; t < 4; ++t) {
            ah[t] = *reinterpret_cast<const bf16x8*>(&As_h[(wm + t * 16 + fm) * 32 + fq]);
            bh[t] = *reinterpret_cast<const bf16x8*>(&Bs_h[(wn + t * 16 + fm) * 32 + fq]);
            if (ASPLIT)
                al[t] = *reinterpret_cast<const bf16x8*>(&As_l[(wm + t * 16 + fm) * 32 + fq]);
            if (BSPLIT)
                bl[t] = *reinterpret_cast<const bf16x8*>(&Bs_l[(wn + t * 16 + fm) * 32 + fq]);
        }
        #pragma unroll
        for (int mt = 0; mt < 4; ++mt)
            #pragma unroll
            for (int nt = 0; nt < 4; ++nt) {
                acc[mt][nt] = __builtin_amdgcn_mfma_f32_16x16x32_bf16(
                    ah[mt], bh[nt], acc[mt][nt], 0, 0, 0);
                if (BSPLIT)
                    acc[mt][nt] = __builtin_amdgcn_mfma_f32_16x16x32_bf16(
                        ah[mt], bl[nt], acc[mt][nt], 0, 0, 0);
                if (ASPLIT)
                    acc[mt][nt] = __builtin_amdgcn_mfma_f32_16x16x32_bf16(
                        al[mt], bh[nt], acc[mt][nt], 0, 0, 0);
            }
    }

    // C/D layout: col = lane&15, row = (lane>>4)*4 + reg
    const int cr = (lane >> 4) * 4, cn = lane & 15;
    #pragma unroll
    for (int mt = 0; mt < 4; ++mt)
        #pragma unroll
        for (int nt = 0; nt < 4; ++nt)
            #pragma unroll
            for (int r = 0; r < 4; ++r) {
                const int gm = m0 + wm + mt * 16 + cr + r;
                const int gn = n0 + wn + nt * 16 + cn;
                float v = acc[mt][nt][r];
                if (RES) v += res[(size_t)gm * N + gn];
                C[(size_t)gm * N + gn] = v;
            }
}

// ---------------------------------------------------------------------------
// Fused gate/up MFMA GEMM + silu epilogue. A = Y hi/lo (split), Bg/Bu hi.
// Output FF bf16 (hi only). Same tiling as mfma_gemm.
// ---------------------------------------------------------------------------
__global__ __launch_bounds__(256) void mfma_gateup_kernel(
    const u16* __restrict__ Ah, const u16* __restrict__ Al,
    const u16* __restrict__ Bg, const u16* __restrict__ Bu,
    u16* __restrict__ FF, int M, int N, int Kd)
{
    __shared__ u16 As_h[128 * 32];
    __shared__ u16 As_l[128 * 32];
    __shared__ u16 Gs[128 * 32];
    __shared__ u16 Us[128 * 32];

    const int tid = threadIdx.x;
    const int lane = tid & 63, wave = tid >> 6;
    const int wm = (wave >> 1) * 64, wn = (wave & 1) * 64;
    const int m0 = blockIdx.y * 128, n0 = blockIdx.x * 128;
    const int fm = lane & 15, fq = (lane >> 4) * 8;

    f32x4 accg[4][4], accu[4][4];
    #pragma unroll
    for (int i = 0; i < 4; ++i)
        #pragma unroll
        for (int j = 0; j < 4; ++j) {
            accg[i][j] = (f32x4){0.f, 0.f, 0.f, 0.f};
            accu[i][j] = (f32x4){0.f, 0.f, 0.f, 0.f};
        }

    const int sr = tid >> 2, sq = (tid & 3) * 8;

    for (int k0 = 0; k0 < Kd; k0 += 32) {
        __syncthreads();
        #pragma unroll
        for (int p = 0; p < 2; ++p) {
            const int row = sr + p * 64;
            const size_t ga = (size_t)(m0 + row) * Kd + k0 + sq;
            const size_t gb = (size_t)(n0 + row) * Kd + k0 + sq;
            const int ls = row * 32 + sq;
            *reinterpret_cast<uint4*>(&As_h[ls]) =
                *reinterpret_cast<const uint4*>(&Ah[ga]);
            *reinterpret_cast<uint4*>(&As_l[ls]) =
                *reinterpret_cast<const uint4*>(&Al[ga]);
            *reinterpret_cast<uint4*>(&Gs[ls]) =
                *reinterpret_cast<const uint4*>(&Bg[gb]);
            *reinterpret_cast<uint4*>(&Us[ls]) =
                *reinterpret_cast<const uint4*>(&Bu[gb]);
        }
        __syncthreads();

        bf16x8 ah[4], al[4], bg[4], bu[4];
        #pragma unroll
        for (int t = 0; t < 4; ++t) {
            ah[t] = *reinterpret_cast<const bf16x8*>(&As_h[(wm + t * 16 + fm) * 32 + fq]);
            al[t] = *reinterpret_cast<const bf16x8*>(&As_l[(wm + t * 16 + fm) * 32 + fq]);
            bg[t] = *reinterpret_cast<const bf16x8*>(&Gs[(wn + t * 16 + fm) * 32 + fq]);
            bu[t] = *reinterpret_cast<const bf16x8*>(&Us[(wn + t * 16 + fm) * 32 + fq]);
        }
        #pragma unroll
        for (int mt = 0; mt < 4; ++mt)
            #pragma unroll
            for (int nt = 0; nt < 4; ++nt) {
                accg[mt][nt] = __builtin_amdgcn_mfma_f32_16x16x32_bf16(
                    ah[mt], bg[nt], accg[mt][nt], 0, 0, 0);
                accg[mt][nt] = __builtin_amdgcn_mfma_f32_16x16x32_bf16(
                    al[mt], bg[nt], accg[mt][nt], 0, 0, 0);
                accu[mt][nt] = __builtin_amdgcn_mfma_f32_16x16x32_bf16(
                    ah[mt], bu[nt], accu[mt][nt], 0, 0, 0);
                accu[mt][nt] = __builtin_amdgcn_mfma_f32_16x16x32_bf16(
                    al[mt], bu[nt], accu[mt][nt], 0, 0, 0);
            }
    }

    const int cr = (lane >> 4) * 4, cn = lane & 15;
    #pragma unroll
    for (int mt = 0; mt < 4; ++mt)
        #pragma unroll
        for (int nt = 0; nt < 4; ++nt)
            #pragma unroll
            for (int r = 0; r < 4; ++r) {
                const int gm = m0 + wm + mt * 16 + cr + r;
                const int gn = n0 + wn + nt * 16 + cn;
                const float g = accg[mt][nt][r];
                const float ff = (g / (1.0f + __expf(-g))) * accu[mt][nt][r];
                FF[(size_t)gm * N + gn] = f2bf(ff);
            }
}

// ---------------------------------------------------------------------------
// Fused per-head RMSNorm (over 64) + RoPE, in place on fp32 buffer with row
// stride rs. One wave per (token, head).
// ---------------------------------------------------------------------------
__global__ __launch_bounds__(256) void qknorm_rope_kernel(
    float* __restrict__ x, const float* __restrict__ nsc,
    const float* __restrict__ sinp, const float* __restrict__ cosp,
    int NH, int rs)
{
    const int lane = threadIdx.x & 63;
    const int w = threadIdx.x >> 6;
    const int head = blockIdx.x * 4 + w;
    const int bt = head / NH;
    const int h = head % NH;
    const size_t base = (size_t)bt * rs + h * 64;

    const float v = x[base + lane];
    float ss = v * v;
    #pragma unroll
    for (int off = 32; off; off >>= 1) ss += __shfl_xor(ss, off, 64);
    const float rstd = rsqrtf(ss * (1.0f / 64.0f) + EPSF);
    const float nv = v * rstd * nsc[lane];

    const float p = __shfl_xor(nv, 32, 64);
    const float s = sinp[(size_t)bt * 32 + (lane & 31)];
    const float c = cosp[(size_t)bt * 32 + (lane & 31)];
    const float o = (lane < 32) ? (nv * c - p * s) : (nv * c + p * s);
    x[base + lane] = o;
}

// ---------------------------------------------------------------------------
// Flash-style causal attention (fp32 compute), QKV packed rows (stride 1536),
// output split to bf16 hi/lo. Br=Bc=64, 256 thr, 4x4 microtile.
// ---------------------------------------------------------------------------
__global__ __launch_bounds__(256) void attn_kernel(
    const float* __restrict__ Qp, const float* __restrict__ Kp,
    const float* __restrict__ Vp, u16* __restrict__ AOh, u16* __restrict__ AOl)
{
    __shared__ float Qs[64][68];
    __shared__ float Ks[64][68];
    __shared__ float Vs[64][68];
    __shared__ float Ss[64][68];

    const int tid = threadIdx.x;
    const int tx = tid & 15;
    const int ty = tid >> 4;
    const int q0 = blockIdx.x * 64;
    const int bh = blockIdx.y;
    const int b = bh / Hh, h = bh % Hh, g = h >> 2;

    const int lr = tid >> 4;
    const int lc = (tid & 15) * 4;

    #pragma unroll
    for (int p = 0; p < 4; ++p) {
        const int r = lr + p * 16;
        const float4 qv = *reinterpret_cast<const float4*>(
            &Qp[((size_t)(b * Tseq + q0 + r)) * QKVN + h * 64 + lc]);
        float4 qs;
        qs.x = qv.x * 0.125f; qs.y = qv.y * 0.125f;
        qs.z = qv.z * 0.125f; qs.w = qv.w * 0.125f;
        *reinterpret_cast<float4*>(&Qs[r][lc]) = qs;
    }

    float o_acc[4][4] = {};
    float m_r[4], l_r[4];
    #pragma unroll
    for (int i = 0; i < 4; ++i) { m_r[i] = -1e30f; l_r[i] = 0.0f; }

    const int ntiles = blockIdx.x + 1;

    for (int it = 0; it < ntiles; ++it) {
        const int s0 = it * 64;
        const bool diag = (it == ntiles - 1);

        float4 kr[4], vr[4];
        #pragma unroll
        for (int p = 0; p < 4; ++p) {
            const int r = lr + p * 16;
            const size_t gi = ((size_t)(b * Tseq + s0 + r)) * QKVN + g * 64 + lc;
            kr[p] = *reinterpret_cast<const float4*>(&Kp[gi]);
            vr[p] = *reinterpret_cast<const float4*>(&Vp[gi]);
        }

        __syncthreads();
        #pragma unroll
        for (int p = 0; p < 4; ++p) {
            const int r = lr + p * 16;
            *reinterpret_cast<float4*>(&Ks[r][lc]) = kr[p];
            *reinterpret_cast<float4*>(&Vs[r][lc]) = vr[p];
        }
        __syncthreads();

        float sacc[4][4] = {};
        #pragma unroll
        for (int kq = 0; kq < 16; ++kq) {
            float4 qv[4], kv[4];
            #pragma unroll
            for (int i = 0; i < 4; ++i)
                qv[i] = *reinterpret_cast<const float4*>(&Qs[ty * 4 + i][kq * 4]);
            #pragma unroll
            for (int j = 0; j < 4; ++j)
                kv[j] = *reinterpret_cast<const float4*>(&Ks[tx * 4 + j][kq * 4]);
            #pragma unroll
            for (int i = 0; i < 4; ++i)
                #pragma unroll
                for (int j = 0; j < 4; ++j) {
                    sacc[i][j] = fmaf(qv[i].x, kv[j].x, sacc[i][j]);
                    sacc[i][j] = fmaf(qv[i].y, kv[j].y, sacc[i][j]);
                    sacc[i][j] = fmaf(qv[i].z, kv[j].z, sacc[i][j]);
                    sacc[i][j] = fmaf(qv[i].w, kv[j].w, sacc[i][j]);
                }
        }

        if (diag) {
            #pragma unroll
            for (int i = 0; i < 4; ++i)
                #pragma unroll
                for (int j = 0; j < 4; ++j)
                    if (tx * 4 + j > ty * 4 + i) sacc[i][j] = -1e30f;
        }

        #pragma unroll
        for (int i = 0; i < 4; ++i) {
            float mx = fmaxf(fmaxf(sacc[i][0], sacc[i][1]),
                             fmaxf(sacc[i][2], sacc[i][3]));
            #pragma unroll
            for (int off = 1; off < 16; off <<= 1)
                mx = fmaxf(mx, __shfl_xor(mx, off, 16));
            const float mnew = fmaxf(m_r[i], mx);
            const float alpha = __expf(m_r[i] - mnew);
            m_r[i] = mnew;

            float4 pv;
            pv.x = __expf(sacc[i][0] - mnew);
            pv.y = __expf(sacc[i][1] - mnew);
            pv.z = __expf(sacc[i][2] - mnew);
            pv.w = __expf(sacc[i][3] - mnew);
            float rs = pv.x + pv.y + pv.z + pv.w;
            #pragma unroll
            for (int off = 1; off < 16; off <<= 1)
                rs += __shfl_xor(rs, off, 16);
            l_r[i] = l_r[i] * alpha + rs;

            #pragma unroll
            for (int j = 0; j < 4; ++j) o_acc[i][j] *= alpha;
            *reinterpret_cast<float4*>(&Ss[ty * 4 + i][tx * 4]) = pv;
        }
        __syncthreads();

        #pragma unroll
        for (int cq = 0; cq < 16; ++cq) {
            float4 pr[4], vv[4];
            #pragma unroll
            for (int i = 0; i < 4; ++i)
                pr[i] = *reinterpret_cast<const float4*>(&Ss[ty * 4 + i][cq * 4]);
            #pragma unroll
            for (int jj = 0; jj < 4; ++jj)
                vv[jj] = *reinterpret_cast<const float4*>(&Vs[cq * 4 + jj][tx * 4]);
            #pragma unroll
            for (int i = 0; i < 4; ++i) {
                const float pe[4] = {pr[i].x, pr[i].y, pr[i].z, pr[i].w};
                #pragma unroll
                for (int jj = 0; jj < 4; ++jj) {
                    o_acc[i][0] = fmaf(pe[jj], vv[jj].x, o_acc[i][0]);
                    o_acc[i][1] = fmaf(pe[jj], vv[jj].y, o_acc[i][1]);
                    o_acc[i][2] = fmaf(pe[jj], vv[jj].z, o_acc[i][2]);
                    o_acc[i][3] = fmaf(pe[jj], vv[jj].w, o_acc[i][3]);
                }
            }
        }
    }

    // Epilogue: normalize, split to bf16 hi/lo, store (8B per store).
    #pragma unroll
    for (int i = 0; i < 4; ++i) {
        const float inv_l = 1.0f / l_r[i];
        const size_t off =
            (size_t)(b * Tseq + q0 + ty * 4 + i) * (Hh * 64) + h * 64 + tx * 4;
        ushort4 hv, lv;
        float o[4];
        #pragma unroll
        for (int j = 0; j < 4; ++j) o[j] = o_acc[i][j] * inv_l;
        hv.x = f2bf(o[0]); hv.y = f2bf(o[1]); hv.z = f2bf(o[2]); hv.w = f2bf(o[3]);
        lv.x = f2bf(o[0] - bf2f(hv.x)); lv.y = f2bf(o[1] - bf2f(hv.y));
        lv.z = f2bf(o[2] - bf2f(hv.z)); lv.w = f2bf(o[3] - bf2f(hv.w));
        *reinterpret_cast<ushort4*>(&AOh[off]) = hv;
        *reinterpret_cast<ushort4*>(&AOl[off]) = lv;
    }
}

// ---------------------------------------------------------------------------
// Host launcher
// ---------------------------------------------------------------------------
extern "C" void kernel_launch(void* const* d_in, const int* in_sizes, int n_in,
                              void* d_out, int out_size, void* d_ws,
                              size_t ws_size, hipStream_t stream)
{
    const float* hidden = (const float*)d_in[0];
    const float* sinp   = (const float*)d_in[1];
    const float* cosp   = (const float*)d_in[2];
    // d_in[3] = mask — causal, handled analytically
    const float* ln1    = (const float*)d_in[4];
    const float* ln2    = (const float*)d_in[5];
    const float* qn     = (const float*)d_in[6];
    const float* kn     = (const float*)d_in[7];
    const float* q_w    = (const float*)d_in[8];
    const float* k_w    = (const float*)d_in[9];
    const float* v_w    = (const float*)d_in[10];
    const float* o_w    = (const float*)d_in[11];
    const float* gate_w = (const float*)d_in[12];
    const float* up_w   = (const float*)d_in[13];
    const float* down_w = (const float*)d_in[14];
    float* out = (float*)d_out;

    // Workspace layout (116.5 MB total)
    u16* QKVT = (u16*)d_ws;                               // [1536][1024] bf16
    u16* OTh  = QKVT + (size_t)1536 * 1024;               // [1024][1024]
    u16* OTl  = OTh + (size_t)1024 * 1024;
    u16* GTh  = OTl + (size_t)1024 * 1024;                // [4096][1024]
    u16* UTh  = GTh + (size_t)4096 * 1024;
    u16* DTh  = UTh + (size_t)4096 * 1024;                // [1024][4096]
    u16* Xh   = DTh + (size_t)1024 * 4096;                // [4096][1024]
    float* QKV = (float*)(Xh + (size_t)4096 * 1024);      // [4096][1536] fp32
    u16* AOh  = (u16*)(QKV + (size_t)4096 * QKVN);        // [4096][1024]
    u16* AOl  = AOh + (size_t)4096 * 1024;
    u16* FFh  = AOl + (size_t)4096 * 1024;                // [4096][4096]
    float* H2 = QKV;                                       // reuse (QKV dead post-attn)
    u16* Yh = AOh; u16* Yl = AOl;                          // reuse (AO dead post-o)

    // 0. Weight prep (transpose + bf16 split where needed)
    wprep_kernel<0><<<dim3(32, 32), 256, 0, stream>>>(q_w, QKVT, nullptr, 1024, 1024);
    wprep_kernel<0><<<dim3(8, 32), 256, 0, stream>>>(k_w, QKVT + (size_t)1024 * 1024, nullptr, 1024, 256);
    wprep_kernel<0><<<dim3(8, 32), 256, 0, stream>>>(v_w, QKVT + (size_t)1280 * 1024, nullptr, 1024, 256);
    wprep_kernel<1><<<dim3(32, 32), 256, 0, stream>>>(o_w, OTh, OTl, 1024, 1024);
    wprep_kernel<0><<<dim3(128, 32), 256, 0, stream>>>(gate_w, GTh, nullptr, 1024, 4096);
    wprep_kernel<0><<<dim3(128, 32), 256, 0, stream>>>(up_w, UTh, nullptr, 1024, 4096);
    wprep_kernel<0><<<dim3(32, 128), 256, 0, stream>>>(down_w, DTh, nullptr, 4096, 1024);

    // 1. x = rmsnorm(hidden, ln1) -> bf16 hi
    rmsnorm_split_kernel<0><<<Mrows, 256, 0, stream>>>(hidden, ln1, Xh, nullptr);

    // 2. fused qkv projection -> QKV fp32 [4096][1536]
    mfma_gemm_kernel<0, 0, 0><<<dim3(QKVN / 128, Mrows / 128), 256, 0, stream>>>(
        Xh, nullptr, QKVT, nullptr, nullptr, QKV, Mrows, QKVN, 1024);

    // 3. per-head RMSNorm + RoPE in place
    qknorm_rope_kernel<<<Mrows * Hh / 4, 256, 0, stream>>>(QKV, qn, sinp, cosp, Hh, QKVN);
    qknorm_rope_kernel<<<Mrows * Gg / 4, 256, 0, stream>>>(QKV + 1024, kn, sinp, cosp, Gg, QKVN);

    // 4. causal attention -> AO bf16 hi/lo
    attn_kernel<<<dim3(Tseq / 64, Bsz * Hh), 256, 0, stream>>>(
        QKV, QKV + 1024, QKV + 1280, AOh, AOl);

    // 5. hidden2 = hidden + attn @ o_w  (split x split)
    mfma_gemm_kernel<1, 1, 1><<<dim3(8, 32), 256, 0, stream>>>(
        AOh, AOl, OTh, OTl, hidden, H2, Mrows, Dmod, 1024);

    // 6. y = rmsnorm(hidden2, ln2) -> bf16 hi/lo
    rmsnorm_split_kernel<1><<<Mrows, 256, 0, stream>>>(H2, ln2, Yh, Yl);

    // 7. ff = silu(y@gate_w) * (y@up_w) -> FF bf16
    mfma_gateup_kernel<<<dim3(32, 32), 256, 0, stream>>>(
        Yh, Yl, GTh, UTh, FFh, Mrows, Ff, 1024);

    // 8. out = hidden2 + ff @ down_w
    mfma_gemm_kernel<0, 0, 1><<<dim3(8, 32), 256, 0, stream>>>(
        FFh, nullptr, DTh, nullptr, H2, out, Mrows, Dmod, 4096);
}

// Round 4
// 900.571 us; speedup vs baseline: 3.9072x; 2.1497x over previous
//
#include <hip/hip_runtime.h>
#include <hip/hip_bf16.h>

// Problem constants: B=2, T=2048, D=1024, H=16, G=4, K=64, F=4096
#define EPSF 1e-6f
constexpr int Bsz  = 2;
constexpr int Tseq = 2048;
constexpr int Dmod = 1024;
constexpr int Hh   = 16;
constexpr int Gg   = 4;
constexpr int Ff   = 4096;
constexpr int Mrows = Bsz * Tseq;          // 4096 tokens
constexpr int QKVN = 1536;                 // fused q(1024)|k(256)|v(256)

typedef __attribute__((ext_vector_type(8))) short bf16x8;   // 8 bf16 (4 VGPRs)
typedef __attribute__((ext_vector_type(4))) float f32x4;
typedef unsigned short u16;

// RNE fp32 -> bf16 (bit pattern as u16)
__device__ inline u16 f2bf(float x) {
    union { float f; unsigned u; } v; v.f = x;
    unsigned r = v.u + 0x7fff + ((v.u >> 16) & 1);
    return (u16)(r >> 16);
}
__device__ inline float bf2f(u16 h) {
    union { unsigned u; float f; } v; v.u = ((unsigned)h) << 16; return v.f;
}

// ---------------------------------------------------------------------------
// Weight prep: W[Kd][N] fp32 -> Th[N][Kd] bf16 (hi) and optional Tl (lo).
// ---------------------------------------------------------------------------
template <int LO>
__global__ __launch_bounds__(256) void wprep_kernel(
    const float* __restrict__ W, u16* __restrict__ Th, u16* __restrict__ Tl,
    int Kd, int N)
{
    __shared__ float tile[32][33];
    const int n0 = blockIdx.x * 32, k0 = blockIdx.y * 32;
    const int r = threadIdx.x >> 3, c4 = (threadIdx.x & 7) * 4;
    const float4 v = *reinterpret_cast<const float4*>(&W[(size_t)(k0 + r) * N + n0 + c4]);
    tile[r][c4 + 0] = v.x; tile[r][c4 + 1] = v.y;
    tile[r][c4 + 2] = v.z; tile[r][c4 + 3] = v.w;
    __syncthreads();
    const int nl = threadIdx.x >> 3, kq = (threadIdx.x & 7) * 4;
    float x0 = tile[kq + 0][nl], x1 = tile[kq + 1][nl];
    float x2 = tile[kq + 2][nl], x3 = tile[kq + 3][nl];
    ushort4 h;
    h.x = f2bf(x0); h.y = f2bf(x1); h.z = f2bf(x2); h.w = f2bf(x3);
    *reinterpret_cast<ushort4*>(&Th[(size_t)(n0 + nl) * Kd + k0 + kq]) = h;
    if (LO) {
        ushort4 l;
        l.x = f2bf(x0 - bf2f(h.x)); l.y = f2bf(x1 - bf2f(h.y));
        l.z = f2bf(x2 - bf2f(h.z)); l.w = f2bf(x3 - bf2f(h.w));
        *reinterpret_cast<ushort4*>(&Tl[(size_t)(n0 + nl) * Kd + k0 + kq]) = l;
    }
}

// ---------------------------------------------------------------------------
// RMSNorm over D=1024 -> bf16 hi (+ optional lo). One block per token.
// ---------------------------------------------------------------------------
template <int LO>
__global__ __launch_bounds__(256) void rmsnorm_split_kernel(
    const float* __restrict__ x, const float* __restrict__ scale,
    u16* __restrict__ oh, u16* __restrict__ ol)
{
    const int row = blockIdx.x;
    const int tid = threadIdx.x;
    const float4 v = reinterpret_cast<const float4*>(x + (size_t)row * Dmod)[tid];
    float ss = v.x * v.x + v.y * v.y + v.z * v.z + v.w * v.w;
    #pragma unroll
    for (int off = 32; off; off >>= 1) ss += __shfl_xor(ss, off, 64);
    __shared__ float part[4];
    if ((tid & 63) == 0) part[tid >> 6] = ss;
    __syncthreads();
    const float tot = part[0] + part[1] + part[2] + part[3];
    const float rstd = rsqrtf(tot * (1.0f / Dmod) + EPSF);
    const float4 sc = reinterpret_cast<const float4*>(scale)[tid];
    float o0 = v.x * rstd * sc.x, o1 = v.y * rstd * sc.y;
    float o2 = v.z * rstd * sc.z, o3 = v.w * rstd * sc.w;
    ushort4 h;
    h.x = f2bf(o0); h.y = f2bf(o1); h.z = f2bf(o2); h.w = f2bf(o3);
    *reinterpret_cast<ushort4*>(&oh[(size_t)row * Dmod + tid * 4]) = h;
    if (LO) {
        ushort4 l;
        l.x = f2bf(o0 - bf2f(h.x)); l.y = f2bf(o1 - bf2f(h.y));
        l.z = f2bf(o2 - bf2f(h.z)); l.w = f2bf(o3 - bf2f(h.w));
        *reinterpret_cast<ushort4*>(&ol[(size_t)row * Dmod + tid * 4]) = l;
    }
}

// ---------------------------------------------------------------------------
// Split-bf16 MFMA GEMM (unchanged from round 3).
// ---------------------------------------------------------------------------
template <int ASPLIT, int BSPLIT, int RES>
__global__ __launch_bounds__(256) void mfma_gemm_kernel(
    const u16* __restrict__ Ah, const u16* __restrict__ Al,
    const u16* __restrict__ Bh, const u16* __restrict__ Bl,
    const float* __restrict__ res, float* __restrict__ C,
    int M, int N, int Kd)
{
    __shared__ u16 As_h[128 * 32];
    __shared__ u16 As_l[128 * 32];
    __shared__ u16 Bs_h[128 * 32];
    __shared__ u16 Bs_l[128 * 32];

    const int tid = threadIdx.x;
    const int lane = tid & 63, wave = tid >> 6;
    const int wm = (wave >> 1) * 64, wn = (wave & 1) * 64;
    const int m0 = blockIdx.y * 128, n0 = blockIdx.x * 128;
    const int fm = lane & 15, fq = (lane >> 4) * 8;

    f32x4 acc[4][4];
    #pragma unroll
    for (int i = 0; i < 4; ++i)
        #pragma unroll
        for (int j = 0; j < 4; ++j) acc[i][j] = (f32x4){0.f, 0.f, 0.f, 0.f};

    const int sr = tid >> 2, sq = (tid & 3) * 8;

    for (int k0 = 0; k0 < Kd; k0 += 32) {
        __syncthreads();
        #pragma unroll
        for (int p = 0; p < 2; ++p) {
            const int row = sr + p * 64;
            const size_t ga = (size_t)(m0 + row) * Kd + k0 + sq;
            const size_t gb = (size_t)(n0 + row) * Kd + k0 + sq;
            const int ls = row * 32 + sq;
            *reinterpret_cast<uint4*>(&As_h[ls]) =
                *reinterpret_cast<const uint4*>(&Ah[ga]);
            if (ASPLIT)
                *reinterpret_cast<uint4*>(&As_l[ls]) =
                    *reinterpret_cast<const uint4*>(&Al[ga]);
            *reinterpret_cast<uint4*>(&Bs_h[ls]) =
                *reinterpret_cast<const uint4*>(&Bh[gb]);
            if (BSPLIT)
                *reinterpret_cast<uint4*>(&Bs_l[ls]) =
                    *reinterpret_cast<const uint4*>(&Bl[gb]);
        }
        __syncthreads();

        bf16x8 ah[4], al[4], bh[4], bl[4];
        #pragma unroll
        for (int t = 0; t < 4; ++t) {
            ah[t] = *reinterpret_cast<const bf16x8*>(&As_h[(wm + t * 16 + fm) * 32 + fq]);
            bh[t] = *reinterpret_cast<const bf16x8*>(&Bs_h[(wn + t * 16 + fm) * 32 + fq]);
            if (ASPLIT)
                al[t] = *reinterpret_cast<const bf16x8*>(&As_l[(wm + t * 16 + fm) * 32 + fq]);
            if (BSPLIT)
                bl[t] = *reinterpret_cast<const bf16x8*>(&Bs_l[(wn + t * 16 + fm) * 32 + fq]);
        }
        #pragma unroll
        for (int mt = 0; mt < 4; ++mt)
            #pragma unroll
            for (int nt = 0; nt < 4; ++nt) {
                acc[mt][nt] = __builtin_amdgcn_mfma_f32_16x16x32_bf16(
                    ah[mt], bh[nt], acc[mt][nt], 0, 0, 0);
                if (BSPLIT)
                    acc[mt][nt] = __builtin_amdgcn_mfma_f32_16x16x32_bf16(
                        ah[mt], bl[nt], acc[mt][nt], 0, 0, 0);
                if (ASPLIT)
                    acc[mt][nt] = __builtin_amdgcn_mfma_f32_16x16x32_bf16(
                        al[mt], bh[nt], acc[mt][nt], 0, 0, 0);
            }
    }

    const int cr = (lane >> 4) * 4, cn = lane & 15;
    #pragma unroll
    for (int mt = 0; mt < 4; ++mt)
        #pragma unroll
        for (int nt = 0; nt < 4; ++nt)
            #pragma unroll
            for (int r = 0; r < 4; ++r) {
                const int gm = m0 + wm + mt * 16 + cr + r;
                const int gn = n0 + wn + nt * 16 + cn;
                float v = acc[mt][nt][r];
                if (RES) v += res[(size_t)gm * N + gn];
                C[(size_t)gm * N + gn] = v;
            }
}

// ---------------------------------------------------------------------------
// Fused gate/up MFMA GEMM + silu epilogue (unchanged from round 3).
// ---------------------------------------------------------------------------
__global__ __launch_bounds__(256) void mfma_gateup_kernel(
    const u16* __restrict__ Ah, const u16* __restrict__ Al,
    const u16* __restrict__ Bg, const u16* __restrict__ Bu,
    u16* __restrict__ FF, int M, int N, int Kd)
{
    __shared__ u16 As_h[128 * 32];
    __shared__ u16 As_l[128 * 32];
    __shared__ u16 Gs[128 * 32];
    __shared__ u16 Us[128 * 32];

    const int tid = threadIdx.x;
    const int lane = tid & 63, wave = tid >> 6;
    const int wm = (wave >> 1) * 64, wn = (wave & 1) * 64;
    const int m0 = blockIdx.y * 128, n0 = blockIdx.x * 128;
    const int fm = lane & 15, fq = (lane >> 4) * 8;

    f32x4 accg[4][4], accu[4][4];
    #pragma unroll
    for (int i = 0; i < 4; ++i)
        #pragma unroll
        for (int j = 0; j < 4; ++j) {
            accg[i][j] = (f32x4){0.f, 0.f, 0.f, 0.f};
            accu[i][j] = (f32x4){0.f, 0.f, 0.f, 0.f};
        }

    const int sr = tid >> 2, sq = (tid & 3) * 8;

    for (int k0 = 0; k0 < Kd; k0 += 32) {
        __syncthreads();
        #pragma unroll
        for (int p = 0; p < 2; ++p) {
            const int row = sr + p * 64;
            const size_t ga = (size_t)(m0 + row) * Kd + k0 + sq;
            const size_t gb = (size_t)(n0 + row) * Kd + k0 + sq;
            const int ls = row * 32 + sq;
            *reinterpret_cast<uint4*>(&As_h[ls]) =
                *reinterpret_cast<const uint4*>(&Ah[ga]);
            *reinterpret_cast<uint4*>(&As_l[ls]) =
                *reinterpret_cast<const uint4*>(&Al[ga]);
            *reinterpret_cast<uint4*>(&Gs[ls]) =
                *reinterpret_cast<const uint4*>(&Bg[gb]);
            *reinterpret_cast<uint4*>(&Us[ls]) =
                *reinterpret_cast<const uint4*>(&Bu[gb]);
        }
        __syncthreads();

        bf16x8 ah[4], al[4], bg[4], bu[4];
        #pragma unroll
        for (int t = 0; t < 4; ++t) {
            ah[t] = *reinterpret_cast<const bf16x8*>(&As_h[(wm + t * 16 + fm) * 32 + fq]);
            al[t] = *reinterpret_cast<const bf16x8*>(&As_l[(wm + t * 16 + fm) * 32 + fq]);
            bg[t] = *reinterpret_cast<const bf16x8*>(&Gs[(wn + t * 16 + fm) * 32 + fq]);
            bu[t] = *reinterpret_cast<const bf16x8*>(&Us[(wn + t * 16 + fm) * 32 + fq]);
        }
        #pragma unroll
        for (int mt = 0; mt < 4; ++mt)
            #pragma unroll
            for (int nt = 0; nt < 4; ++nt) {
                accg[mt][nt] = __builtin_amdgcn_mfma_f32_16x16x32_bf16(
                    ah[mt], bg[nt], accg[mt][nt], 0, 0, 0);
                accg[mt][nt] = __builtin_amdgcn_mfma_f32_16x16x32_bf16(
                    al[mt], bg[nt], accg[mt][nt], 0, 0, 0);
                accu[mt][nt] = __builtin_amdgcn_mfma_f32_16x16x32_bf16(
                    ah[mt], bu[nt], accu[mt][nt], 0, 0, 0);
                accu[mt][nt] = __builtin_amdgcn_mfma_f32_16x16x32_bf16(
                    al[mt], bu[nt], accu[mt][nt], 0, 0, 0);
            }
    }

    const int cr = (lane >> 4) * 4, cn = lane & 15;
    #pragma unroll
    for (int mt = 0; mt < 4; ++mt)
        #pragma unroll
        for (int nt = 0; nt < 4; ++nt)
            #pragma unroll
            for (int r = 0; r < 4; ++r) {
                const int gm = m0 + wm + mt * 16 + cr + r;
                const int gn = n0 + wn + nt * 16 + cn;
                const float g = accg[mt][nt][r];
                const float ff = (g / (1.0f + __expf(-g))) * accu[mt][nt][r];
                FF[(size_t)gm * N + gn] = f2bf(ff);
            }
}

// ---------------------------------------------------------------------------
// Per-head RMSNorm + RoPE, reading fp32 QKV (stride 1536), writing bf16 hi/lo
// (scale folded in: Q gets K^-0.5). One wave per (token, head).
// ---------------------------------------------------------------------------
__global__ __launch_bounds__(256) void qkrope_bf16_kernel(
    const float* __restrict__ src, const float* __restrict__ nsc,
    const float* __restrict__ sinp, const float* __restrict__ cosp,
    u16* __restrict__ outh, u16* __restrict__ outl,
    int NH, float oscale)
{
    const int lane = threadIdx.x & 63;
    const int w = threadIdx.x >> 6;
    const int head = blockIdx.x * 4 + w;
    const int bt = head / NH;
    const int h = head % NH;

    const float v = src[(size_t)bt * QKVN + h * 64 + lane];
    float ss = v * v;
    #pragma unroll
    for (int off = 32; off; off >>= 1) ss += __shfl_xor(ss, off, 64);
    const float rstd = rsqrtf(ss * (1.0f / 64.0f) + EPSF);
    const float nv = v * rstd * nsc[lane];

    const float p = __shfl_xor(nv, 32, 64);
    const float s = sinp[(size_t)bt * 32 + (lane & 31)];
    const float c = cosp[(size_t)bt * 32 + (lane & 31)];
    const float o = ((lane < 32) ? (nv * c - p * s) : (nv * c + p * s)) * oscale;

    const size_t oi = (size_t)bt * (NH * 64) + h * 64 + lane;
    const u16 hi = f2bf(o);
    outh[oi] = hi;
    outl[oi] = f2bf(o - bf2f(hi));
}

// ---------------------------------------------------------------------------
// V transpose + bf16 split: QKV fp32 V-part [b][t][g*64+d] ->
// Vt[(b*4+g)*64+d][t] bf16 hi/lo. Grid (T/64, B*G), 256 threads.
// ---------------------------------------------------------------------------
__global__ __launch_bounds__(256) void vtrans_kernel(
    const float* __restrict__ QKV, u16* __restrict__ Vth, u16* __restrict__ Vtl)
{
    __shared__ float tile[64][65];
    const int t0 = blockIdx.x * 64;
    const int bg = blockIdx.y;
    const int b = bg >> 2, g = bg & 3;
    const int tid = threadIdx.x;

    const int tl = tid >> 4, dq = (tid & 15) * 4;
    #pragma unroll
    for (int p = 0; p < 4; ++p) {
        const int t = tl + p * 16;
        const float4 v = *reinterpret_cast<const float4*>(
            &QKV[(size_t)(b * Tseq + t0 + t) * QKVN + 1280 + g * 64 + dq]);
        tile[t][dq + 0] = v.x; tile[t][dq + 1] = v.y;
        tile[t][dq + 2] = v.z; tile[t][dq + 3] = v.w;
    }
    __syncthreads();

    const int d = tid >> 2, tq = (tid & 3) * 16;
    u16 hv[16], lv[16];
    #pragma unroll
    for (int i = 0; i < 16; ++i) {
        const float v = tile[tq + i][d];
        hv[i] = f2bf(v);
        lv[i] = f2bf(v - bf2f(hv[i]));
    }
    const size_t oi = ((size_t)(bg * 64 + d)) * Tseq + t0 + tq;
    *reinterpret_cast<uint4*>(&Vth[oi])     = *reinterpret_cast<uint4*>(&hv[0]);
    *reinterpret_cast<uint4*>(&Vth[oi + 8]) = *reinterpret_cast<uint4*>(&hv[8]);
    *reinterpret_cast<uint4*>(&Vtl[oi])     = *reinterpret_cast<uint4*>(&lv[0]);
    *reinterpret_cast<uint4*>(&Vtl[oi + 8]) = *reinterpret_cast<uint4*>(&lv[8]);
}

// ---------------------------------------------------------------------------
// MFMA flash attention, barrier-free.
// One wave = one 16-row q-strip, full causal kv loop (Bc=64).
// S = Qh*Kh + Ql*Kh + Qh*Kl (split, ~fp32); PV = P*Vh + P*Vl.
// Q frags in registers; K/V frags direct from global (L2-resident);
// P round-trips through wave-private LDS (C-layout -> A-layout).
// Block = 4 independent waves. blockIdx%8 -> (b,g) for XCD/L2 locality.
// ---------------------------------------------------------------------------
__global__ __launch_bounds__(256) void attn_mfma_kernel(
    const u16* __restrict__ Qh, const u16* __restrict__ Ql,
    const u16* __restrict__ Kh, const u16* __restrict__ Kl,
    const u16* __restrict__ Vth, const u16* __restrict__ Vtl,
    u16* __restrict__ AOh, u16* __restrict__ AOl)
{
    __shared__ u16 Ps[4][16 * 72];   // wave-private P tile, stride 72 (144B rows)

    const int wave = threadIdx.x >> 6, lane = threadIdx.x & 63;
    const int l15 = lane & 15, quad = lane >> 4;

    // blockIdx -> (b,g) in low 3 bits; strip within (b,g) from the rest.
    const int bg = blockIdx.x & 7;
    const int b = bg >> 2, g = bg & 3;
    const int strip = (blockIdx.x >> 3) * 4 + wave;   // 0..511 within (b,g)
    const int h = g * 4 + (strip >> 7);
    const int q0 = (strip & 127) * 16;

    // Q fragments (A-layout: row=l15, k=quad*8+j), scale already folded.
    bf16x8 qh[2], ql[2];
    {
        const size_t qrow = (size_t)(b * Tseq + q0 + l15) * 1024 + h * 64;
        #pragma unroll
        for (int ks = 0; ks < 2; ++ks) {
            qh[ks] = *reinterpret_cast<const bf16x8*>(&Qh[qrow + ks * 32 + quad * 8]);
            ql[ks] = *reinterpret_cast<const bf16x8*>(&Ql[qrow + ks * 32 + quad * 8]);
        }
    }

    f32x4 oacc[4];
    #pragma unroll
    for (int nt = 0; nt < 4; ++nt) oacc[nt] = (f32x4){0.f, 0.f, 0.f, 0.f};
    float m_r[4], l_r[4];
    #pragma unroll
    for (int r = 0; r < 4; ++r) { m_r[r] = -1e30f; l_r[r] = 0.0f; }

    u16* psw = &Ps[wave][0];
    const size_t kbase = (size_t)(b * Tseq) * 256 + g * 64;
    const size_t vbase = (size_t)(bg * 64) * Tseq;

    for (int s0 = 0; s0 <= q0; s0 += 64) {
        const bool diag = (s0 + 64 > q0);

        // ---- S = Q K^T (split x3) ----
        f32x4 sacc[4];
        #pragma unroll
        for (int nt = 0; nt < 4; ++nt) sacc[nt] = (f32x4){0.f, 0.f, 0.f, 0.f};

        #pragma unroll
        for (int ks = 0; ks < 2; ++ks) {
            bf16x8 kh[4], kl[4];
            #pragma unroll
            for (int nt = 0; nt < 4; ++nt) {
                const size_t ka = kbase + (size_t)(s0 + nt * 16 + l15) * 256 + ks * 32 + quad * 8;
                kh[nt] = *reinterpret_cast<const bf16x8*>(&Kh[ka]);
                kl[nt] = *reinterpret_cast<const bf16x8*>(&Kl[ka]);
            }
            #pragma unroll
            for (int nt = 0; nt < 4; ++nt) {
                sacc[nt] = __builtin_amdgcn_mfma_f32_16x16x32_bf16(qh[ks], kh[nt], sacc[nt], 0, 0, 0);
                sacc[nt] = __builtin_amdgcn_mfma_f32_16x16x32_bf16(ql[ks], kh[nt], sacc[nt], 0, 0, 0);
                sacc[nt] = __builtin_amdgcn_mfma_f32_16x16x32_bf16(qh[ks], kl[nt], sacc[nt], 0, 0, 0);
            }
        }

        if (diag) {
            #pragma unroll
            for (int nt = 0; nt < 4; ++nt) {
                const int sg = s0 + nt * 16 + l15;
                #pragma unroll
                for (int r = 0; r < 4; ++r)
                    if (sg > q0 + quad * 4 + r) sacc[nt][r] = -1e30f;
            }
        }

        // ---- online softmax (stats per lane for its 4 q-rows) ----
        #pragma unroll
        for (int r = 0; r < 4; ++r) {
            float mx = fmaxf(fmaxf(sacc[0][r], sacc[1][r]),
                             fmaxf(sacc[2][r], sacc[3][r]));
            #pragma unroll
            for (int off = 1; off < 16; off <<= 1)
                mx = fmaxf(mx, __shfl_xor(mx, off, 16));
            const float mnew = fmaxf(m_r[r], mx);
            const float alpha = __expf(m_r[r] - mnew);
            m_r[r] = mnew;

            float rs = 0.0f;
            #pragma unroll
            for (int nt = 0; nt < 4; ++nt) {
                const float p = __expf(sacc[nt][r] - mnew);
                sacc[nt][r] = p;
                rs += p;
            }
            #pragma unroll
            for (int off = 1; off < 16; off <<= 1)
                rs += __shfl_xor(rs, off, 16);
            l_r[r] = l_r[r] * alpha + rs;
            #pragma unroll
            for (int nt = 0; nt < 4; ++nt) oacc[nt][r] *= alpha;
            // P (C-layout) -> LDS [q][s], stride 72
            #pragma unroll
            for (int nt = 0; nt < 4; ++nt)
                psw[(quad * 4 + r) * 72 + nt * 16 + l15] = f2bf(sacc[nt][r]);
        }
        // wave-private LDS: compiler inserts lgkmcnt wait; no barrier needed.

        // ---- O += P V (split V x2) ----
        #pragma unroll
        for (int ks = 0; ks < 2; ++ks) {
            const bf16x8 pa = *reinterpret_cast<const bf16x8*>(
                &psw[l15 * 72 + ks * 32 + quad * 8]);
            bf16x8 vh[4], vl[4];
            #pragma unroll
            for (int nt = 0; nt < 4; ++nt) {
                const size_t va = vbase + (size_t)(nt * 16 + l15) * Tseq + s0 + ks * 32 + quad * 8;
                vh[nt] = *reinterpret_cast<const bf16x8*>(&Vth[va]);
                vl[nt] = *reinterpret_cast<const bf16x8*>(&Vtl[va]);
            }
            #pragma unroll
            for (int nt = 0; nt < 4; ++nt) {
                oacc[nt] = __builtin_amdgcn_mfma_f32_16x16x32_bf16(pa, vh[nt], oacc[nt], 0, 0, 0);
                oacc[nt] = __builtin_amdgcn_mfma_f32_16x16x32_bf16(pa, vl[nt], oacc[nt], 0, 0, 0);
            }
        }
    }

    // ---- epilogue: normalize, split bf16, store ----
    #pragma unroll
    for (int r = 0; r < 4; ++r) {
        const float inv = 1.0f / l_r[r];
        const size_t orow = (size_t)(b * Tseq + q0 + quad * 4 + r) * 1024 + h * 64;
        #pragma unroll
        for (int nt = 0; nt < 4; ++nt) {
            const float o = oacc[nt][r] * inv;
            const u16 hi = f2bf(o);
            AOh[orow + nt * 16 + l15] = hi;
            AOl[orow + nt * 16 + l15] = f2bf(o - bf2f(hi));
        }
    }
}

// ---------------------------------------------------------------------------
// Host launcher
// ---------------------------------------------------------------------------
extern "C" void kernel_launch(void* const* d_in, const int* in_sizes, int n_in,
                              void* d_out, int out_size, void* d_ws,
                              size_t ws_size, hipStream_t stream)
{
    const float* hidden = (const float*)d_in[0];
    const float* sinp   = (const float*)d_in[1];
    const float* cosp   = (const float*)d_in[2];
    // d_in[3] = mask — causal, handled analytically
    const float* ln1    = (const float*)d_in[4];
    const float* ln2    = (const float*)d_in[5];
    const float* qn     = (const float*)d_in[6];
    const float* kn     = (const float*)d_in[7];
    const float* q_w    = (const float*)d_in[8];
    const float* k_w    = (const float*)d_in[9];
    const float* v_w    = (const float*)d_in[10];
    const float* o_w    = (const float*)d_in[11];
    const float* gate_w = (const float*)d_in[12];
    const float* up_w   = (const float*)d_in[13];
    const float* down_w = (const float*)d_in[14];
    float* out = (float*)d_out;

    // ---- workspace layout (116.4 MB, with aliasing) ----
    char* base = (char*)d_ws;
    u16*   OTh  = (u16*)(base);                       //  2,097,152
    u16*   OTl  = (u16*)(base + 2097152);             //  2,097,152
    u16*   GTh  = (u16*)(base + 4194304);             //  8,388,608
    u16*   UTh  = (u16*)(base + 12582912);            //  8,388,608
    u16*   DTh  = (u16*)(base + 20971520);            //  8,388,608
    float* QKV  = (float*)(base + 29360128);          // 25,165,824 fp32
    u16*   Qbh  = (u16*)(base + 54525952);            //  8,388,608
    u16*   Qbl  = (u16*)(base + 62914560);            //  8,388,608
    u16*   FFh  = (u16*)(base + 71303168);            // 33,554,432
    u16*   QKVT = (u16*)(base + 104857600);           //  3,145,728
    // Xh directly after QKVT: combined 11.5 MB region later reused for K/V bf16
    u16*   Xh   = (u16*)(base + 108003328);           //  8,388,608  (end 116,391,936)

    // aliases (lifetime-checked):
    u16*   Kbh  = QKVT;                                // 2,097,152 (post-QKV-gemm)
    u16*   Kbl  = Kbh + (size_t)4096 * 256;
    u16*   Vth  = Kbl + (size_t)4096 * 256;            // 2,097,152
    u16*   Vtl  = Vth + (size_t)8 * 64 * 2048;
    u16*   AOh  = (u16*)QKV;                           // over QKV (dead post-vtrans)
    u16*   AOl  = AOh + (size_t)4096 * 1024;
    u16*   Yl   = (u16*)(base + 29360128 + 16777216);  // QKV tail (8,388,608)
    float* H2   = (float*)Qbh;                         // over Qh/Ql (dead post-attn)
    u16*   Yh   = Kbh;                                 // over K/V bf16 (dead post-attn)

    // 0. weight prep
    wprep_kernel<0><<<dim3(32, 32), 256, 0, stream>>>(q_w, QKVT, nullptr, 1024, 1024);
    wprep_kernel<0><<<dim3(8, 32), 256, 0, stream>>>(k_w, QKVT + (size_t)1024 * 1024, nullptr, 1024, 256);
    wprep_kernel<0><<<dim3(8, 32), 256, 0, stream>>>(v_w, QKVT + (size_t)1280 * 1024, nullptr, 1024, 256);
    wprep_kernel<1><<<dim3(32, 32), 256, 0, stream>>>(o_w, OTh, OTl, 1024, 1024);
    wprep_kernel<0><<<dim3(128, 32), 256, 0, stream>>>(gate_w, GTh, nullptr, 1024, 4096);
    wprep_kernel<0><<<dim3(128, 32), 256, 0, stream>>>(up_w, UTh, nullptr, 1024, 4096);
    wprep_kernel<0><<<dim3(32, 128), 256, 0, stream>>>(down_w, DTh, nullptr, 4096, 1024);

    // 1. x = rmsnorm(hidden, ln1) -> bf16
    rmsnorm_split_kernel<0><<<Mrows, 256, 0, stream>>>(hidden, ln1, Xh, nullptr);

    // 2. fused qkv projection -> QKV fp32
    mfma_gemm_kernel<0, 0, 0><<<dim3(QKVN / 128, Mrows / 128), 256, 0, stream>>>(
        Xh, nullptr, QKVT, nullptr, nullptr, QKV, Mrows, QKVN, 1024);

    // 3. qk-norm + rope -> bf16 hi/lo (Q scaled by K^-0.5); V transpose+split
    qkrope_bf16_kernel<<<Mrows * Hh / 4, 256, 0, stream>>>(
        QKV, qn, sinp, cosp, Qbh, Qbl, Hh, 0.125f);
    qkrope_bf16_kernel<<<Mrows * Gg / 4, 256, 0, stream>>>(
        QKV + 1024, kn, sinp, cosp, Kbh, Kbl, Gg, 1.0f);
    vtrans_kernel<<<dim3(Tseq / 64, Bsz * Gg), 256, 0, stream>>>(QKV, Vth, Vtl);

    // 4. MFMA flash attention -> AO bf16 hi/lo
    attn_mfma_kernel<<<Mrows * Hh / 16 / 4, 256, 0, stream>>>(
        Qbh, Qbl, Kbh, Kbl, Vth, Vtl, AOh, AOl);

    // 5. hidden2 = hidden + attn @ o_w  (split x split)
    mfma_gemm_kernel<1, 1, 1><<<dim3(8, 32), 256, 0, stream>>>(
        AOh, AOl, OTh, OTl, hidden, H2, Mrows, Dmod, 1024);

    // 6. y = rmsnorm(hidden2, ln2) -> bf16 hi/lo
    rmsnorm_split_kernel<1><<<Mrows, 256, 0, stream>>>(H2, ln2, Yh, Yl);

    // 7. ff = silu(y@gate_w) * (y@up_w) -> FF bf16
    mfma_gateup_kernel<<<dim3(32, 32), 256, 0, stream>>>(
        Yh, Yl, GTh, UTh, FFh, Mrows, Ff, 1024);

    // 8. out = hidden2 + ff @ down_w
    mfma_gemm_kernel<0, 0, 1><<<dim3(8, 32), 256, 0, stream>>>(
        FFh, nullptr, DTh, nullptr, H2, out, Mrows, Dmod, 4096);
}

// Round 5
// 657.899 us; speedup vs baseline: 5.3484x; 1.3689x over previous
//
#include <hip/hip_runtime.h>
#include <hip/hip_bf16.h>

// Problem constants: B=2, T=2048, D=1024, H=16, G=4, K=64, F=4096
#define EPSF 1e-6f
constexpr int Bsz  = 2;
constexpr int Tseq = 2048;
constexpr int Dmod = 1024;
constexpr int Hh   = 16;
constexpr int Gg   = 4;
constexpr int Ff   = 4096;
constexpr int Mrows = Bsz * Tseq;          // 4096 tokens
constexpr int QKVN = 1536;                 // fused q(1024)|k(256)|v(256)

typedef __attribute__((ext_vector_type(8))) short bf16x8;   // 8 bf16 (4 VGPRs)
typedef __attribute__((ext_vector_type(4))) float f32x4;
typedef unsigned short u16;

// RNE fp32 -> bf16 (bit pattern as u16)
__device__ inline u16 f2bf(float x) {
    union { float f; unsigned u; } v; v.f = x;
    unsigned r = v.u + 0x7fff + ((v.u >> 16) & 1);
    return (u16)(r >> 16);
}
__device__ inline float bf2f(u16 h) {
    union { unsigned u; float f; } v; v.u = ((unsigned)h) << 16; return v.f;
}

// ---------------------------------------------------------------------------
// Weight prep: W[Kd][N] fp32 -> Th[N][Kd] bf16 (hi) and optional Tl (lo).
// ---------------------------------------------------------------------------
template <int LO>
__global__ __launch_bounds__(256) void wprep_kernel(
    const float* __restrict__ W, u16* __restrict__ Th, u16* __restrict__ Tl,
    int Kd, int N)
{
    __shared__ float tile[32][33];
    const int n0 = blockIdx.x * 32, k0 = blockIdx.y * 32;
    const int r = threadIdx.x >> 3, c4 = (threadIdx.x & 7) * 4;
    const float4 v = *reinterpret_cast<const float4*>(&W[(size_t)(k0 + r) * N + n0 + c4]);
    tile[r][c4 + 0] = v.x; tile[r][c4 + 1] = v.y;
    tile[r][c4 + 2] = v.z; tile[r][c4 + 3] = v.w;
    __syncthreads();
    const int nl = threadIdx.x >> 3, kq = (threadIdx.x & 7) * 4;
    float x0 = tile[kq + 0][nl], x1 = tile[kq + 1][nl];
    float x2 = tile[kq + 2][nl], x3 = tile[kq + 3][nl];
    ushort4 h;
    h.x = f2bf(x0); h.y = f2bf(x1); h.z = f2bf(x2); h.w = f2bf(x3);
    *reinterpret_cast<ushort4*>(&Th[(size_t)(n0 + nl) * Kd + k0 + kq]) = h;
    if (LO) {
        ushort4 l;
        l.x = f2bf(x0 - bf2f(h.x)); l.y = f2bf(x1 - bf2f(h.y));
        l.z = f2bf(x2 - bf2f(h.z)); l.w = f2bf(x3 - bf2f(h.w));
        *reinterpret_cast<ushort4*>(&Tl[(size_t)(n0 + nl) * Kd + k0 + kq]) = l;
    }
}

// ---------------------------------------------------------------------------
// RMSNorm over D=1024 -> bf16 hi (+ optional lo). One block per token.
// ---------------------------------------------------------------------------
template <int LO>
__global__ __launch_bounds__(256) void rmsnorm_split_kernel(
    const float* __restrict__ x, const float* __restrict__ scale,
    u16* __restrict__ oh, u16* __restrict__ ol)
{
    const int row = blockIdx.x;
    const int tid = threadIdx.x;
    const float4 v = reinterpret_cast<const float4*>(x + (size_t)row * Dmod)[tid];
    float ss = v.x * v.x + v.y * v.y + v.z * v.z + v.w * v.w;
    #pragma unroll
    for (int off = 32; off; off >>= 1) ss += __shfl_xor(ss, off, 64);
    __shared__ float part[4];
    if ((tid & 63) == 0) part[tid >> 6] = ss;
    __syncthreads();
    const float tot = part[0] + part[1] + part[2] + part[3];
    const float rstd = rsqrtf(tot * (1.0f / Dmod) + EPSF);
    const float4 sc = reinterpret_cast<const float4*>(scale)[tid];
    float o0 = v.x * rstd * sc.x, o1 = v.y * rstd * sc.y;
    float o2 = v.z * rstd * sc.z, o3 = v.w * rstd * sc.w;
    ushort4 h;
    h.x = f2bf(o0); h.y = f2bf(o1); h.z = f2bf(o2); h.w = f2bf(o3);
    *reinterpret_cast<ushort4*>(&oh[(size_t)row * Dmod + tid * 4]) = h;
    if (LO) {
        ushort4 l;
        l.x = f2bf(o0 - bf2f(h.x)); l.y = f2bf(o1 - bf2f(h.y));
        l.z = f2bf(o2 - bf2f(h.z)); l.w = f2bf(o3 - bf2f(h.w));
        *reinterpret_cast<ushort4*>(&ol[(size_t)row * Dmod + tid * 4]) = l;
    }
}

// ---------------------------------------------------------------------------
// Split-bf16 MFMA GEMM (unchanged).
// ---------------------------------------------------------------------------
template <int ASPLIT, int BSPLIT, int RES>
__global__ __launch_bounds__(256) void mfma_gemm_kernel(
    const u16* __restrict__ Ah, const u16* __restrict__ Al,
    const u16* __restrict__ Bh, const u16* __restrict__ Bl,
    const float* __restrict__ res, float* __restrict__ C,
    int M, int N, int Kd)
{
    __shared__ u16 As_h[128 * 32];
    __shared__ u16 As_l[128 * 32];
    __shared__ u16 Bs_h[128 * 32];
    __shared__ u16 Bs_l[128 * 32];

    const int tid = threadIdx.x;
    const int lane = tid & 63, wave = tid >> 6;
    const int wm = (wave >> 1) * 64, wn = (wave & 1) * 64;
    const int m0 = blockIdx.y * 128, n0 = blockIdx.x * 128;
    const int fm = lane & 15, fq = (lane >> 4) * 8;

    f32x4 acc[4][4];
    #pragma unroll
    for (int i = 0; i < 4; ++i)
        #pragma unroll
        for (int j = 0; j < 4; ++j) acc[i][j] = (f32x4){0.f, 0.f, 0.f, 0.f};

    const int sr = tid >> 2, sq = (tid & 3) * 8;

    for (int k0 = 0; k0 < Kd; k0 += 32) {
        __syncthreads();
        #pragma unroll
        for (int p = 0; p < 2; ++p) {
            const int row = sr + p * 64;
            const size_t ga = (size_t)(m0 + row) * Kd + k0 + sq;
            const size_t gb = (size_t)(n0 + row) * Kd + k0 + sq;
            const int ls = row * 32 + sq;
            *reinterpret_cast<uint4*>(&As_h[ls]) =
                *reinterpret_cast<const uint4*>(&Ah[ga]);
            if (ASPLIT)
                *reinterpret_cast<uint4*>(&As_l[ls]) =
                    *reinterpret_cast<const uint4*>(&Al[ga]);
            *reinterpret_cast<uint4*>(&Bs_h[ls]) =
                *reinterpret_cast<const uint4*>(&Bh[gb]);
            if (BSPLIT)
                *reinterpret_cast<uint4*>(&Bs_l[ls]) =
                    *reinterpret_cast<const uint4*>(&Bl[gb]);
        }
        __syncthreads();

        bf16x8 ah[4], al[4], bh[4], bl[4];
        #pragma unroll
        for (int t = 0; t < 4; ++t) {
            ah[t] = *reinterpret_cast<const bf16x8*>(&As_h[(wm + t * 16 + fm) * 32 + fq]);
            bh[t] = *reinterpret_cast<const bf16x8*>(&Bs_h[(wn + t * 16 + fm) * 32 + fq]);
            if (ASPLIT)
                al[t] = *reinterpret_cast<const bf16x8*>(&As_l[(wm + t * 16 + fm) * 32 + fq]);
            if (BSPLIT)
                bl[t] = *reinterpret_cast<const bf16x8*>(&Bs_l[(wn + t * 16 + fm) * 32 + fq]);
        }
        #pragma unroll
        for (int mt = 0; mt < 4; ++mt)
            #pragma unroll
            for (int nt = 0; nt < 4; ++nt) {
                acc[mt][nt] = __builtin_amdgcn_mfma_f32_16x16x32_bf16(
                    ah[mt], bh[nt], acc[mt][nt], 0, 0, 0);
                if (BSPLIT)
                    acc[mt][nt] = __builtin_amdgcn_mfma_f32_16x16x32_bf16(
                        ah[mt], bl[nt], acc[mt][nt], 0, 0, 0);
                if (ASPLIT)
                    acc[mt][nt] = __builtin_amdgcn_mfma_f32_16x16x32_bf16(
                        al[mt], bh[nt], acc[mt][nt], 0, 0, 0);
            }
    }

    const int cr = (lane >> 4) * 4, cn = lane & 15;
    #pragma unroll
    for (int mt = 0; mt < 4; ++mt)
        #pragma unroll
        for (int nt = 0; nt < 4; ++nt)
            #pragma unroll
            for (int r = 0; r < 4; ++r) {
                const int gm = m0 + wm + mt * 16 + cr + r;
                const int gn = n0 + wn + nt * 16 + cn;
                float v = acc[mt][nt][r];
                if (RES) v += res[(size_t)gm * N + gn];
                C[(size_t)gm * N + gn] = v;
            }
}

// ---------------------------------------------------------------------------
// Fused gate/up MFMA GEMM + silu epilogue (unchanged).
// ---------------------------------------------------------------------------
__global__ __launch_bounds__(256) void mfma_gateup_kernel(
    const u16* __restrict__ Ah, const u16* __restrict__ Al,
    const u16* __restrict__ Bg, const u16* __restrict__ Bu,
    u16* __restrict__ FF, int M, int N, int Kd)
{
    __shared__ u16 As_h[128 * 32];
    __shared__ u16 As_l[128 * 32];
    __shared__ u16 Gs[128 * 32];
    __shared__ u16 Us[128 * 32];

    const int tid = threadIdx.x;
    const int lane = tid & 63, wave = tid >> 6;
    const int wm = (wave >> 1) * 64, wn = (wave & 1) * 64;
    const int m0 = blockIdx.y * 128, n0 = blockIdx.x * 128;
    const int fm = lane & 15, fq = (lane >> 4) * 8;

    f32x4 accg[4][4], accu[4][4];
    #pragma unroll
    for (int i = 0; i < 4; ++i)
        #pragma unroll
        for (int j = 0; j < 4; ++j) {
            accg[i][j] = (f32x4){0.f, 0.f, 0.f, 0.f};
            accu[i][j] = (f32x4){0.f, 0.f, 0.f, 0.f};
        }

    const int sr = tid >> 2, sq = (tid & 3) * 8;

    for (int k0 = 0; k0 < Kd; k0 += 32) {
        __syncthreads();
        #pragma unroll
        for (int p = 0; p < 2; ++p) {
            const int row = sr + p * 64;
            const size_t ga = (size_t)(m0 + row) * Kd + k0 + sq;
            const size_t gb = (size_t)(n0 + row) * Kd + k0 + sq;
            const int ls = row * 32 + sq;
            *reinterpret_cast<uint4*>(&As_h[ls]) =
                *reinterpret_cast<const uint4*>(&Ah[ga]);
            *reinterpret_cast<uint4*>(&As_l[ls]) =
                *reinterpret_cast<const uint4*>(&Al[ga]);
            *reinterpret_cast<uint4*>(&Gs[ls]) =
                *reinterpret_cast<const uint4*>(&Bg[gb]);
            *reinterpret_cast<uint4*>(&Us[ls]) =
                *reinterpret_cast<const uint4*>(&Bu[gb]);
        }
        __syncthreads();

        bf16x8 ah[4], al[4], bg[4], bu[4];
        #pragma unroll
        for (int t = 0; t < 4; ++t) {
            ah[t] = *reinterpret_cast<const bf16x8*>(&As_h[(wm + t * 16 + fm) * 32 + fq]);
            al[t] = *reinterpret_cast<const bf16x8*>(&As_l[(wm + t * 16 + fm) * 32 + fq]);
            bg[t] = *reinterpret_cast<const bf16x8*>(&Gs[(wn + t * 16 + fm) * 32 + fq]);
            bu[t] = *reinterpret_cast<const bf16x8*>(&Us[(wn + t * 16 + fm) * 32 + fq]);
        }
        #pragma unroll
        for (int mt = 0; mt < 4; ++mt)
            #pragma unroll
            for (int nt = 0; nt < 4; ++nt) {
                accg[mt][nt] = __builtin_amdgcn_mfma_f32_16x16x32_bf16(
                    ah[mt], bg[nt], accg[mt][nt], 0, 0, 0);
                accg[mt][nt] = __builtin_amdgcn_mfma_f32_16x16x32_bf16(
                    al[mt], bg[nt], accg[mt][nt], 0, 0, 0);
                accu[mt][nt] = __builtin_amdgcn_mfma_f32_16x16x32_bf16(
                    ah[mt], bu[nt], accu[mt][nt], 0, 0, 0);
                accu[mt][nt] = __builtin_amdgcn_mfma_f32_16x16x32_bf16(
                    al[mt], bu[nt], accu[mt][nt], 0, 0, 0);
            }
    }

    const int cr = (lane >> 4) * 4, cn = lane & 15;
    #pragma unroll
    for (int mt = 0; mt < 4; ++mt)
        #pragma unroll
        for (int nt = 0; nt < 4; ++nt)
            #pragma unroll
            for (int r = 0; r < 4; ++r) {
                const int gm = m0 + wm + mt * 16 + cr + r;
                const int gn = n0 + wn + nt * 16 + cn;
                const float g = accg[mt][nt][r];
                const float ff = (g / (1.0f + __expf(-g))) * accu[mt][nt][r];
                FF[(size_t)gm * N + gn] = f2bf(ff);
            }
}

// ---------------------------------------------------------------------------
// Per-head RMSNorm + RoPE, fp32 QKV (stride 1536) -> bf16 hi/lo (scale folded).
// ---------------------------------------------------------------------------
__global__ __launch_bounds__(256) void qkrope_bf16_kernel(
    const float* __restrict__ src, const float* __restrict__ nsc,
    const float* __restrict__ sinp, const float* __restrict__ cosp,
    u16* __restrict__ outh, u16* __restrict__ outl,
    int NH, float oscale)
{
    const int lane = threadIdx.x & 63;
    const int w = threadIdx.x >> 6;
    const int head = blockIdx.x * 4 + w;
    const int bt = head / NH;
    const int h = head % NH;

    const float v = src[(size_t)bt * QKVN + h * 64 + lane];
    float ss = v * v;
    #pragma unroll
    for (int off = 32; off; off >>= 1) ss += __shfl_xor(ss, off, 64);
    const float rstd = rsqrtf(ss * (1.0f / 64.0f) + EPSF);
    const float nv = v * rstd * nsc[lane];

    const float p = __shfl_xor(nv, 32, 64);
    const float s = sinp[(size_t)bt * 32 + (lane & 31)];
    const float c = cosp[(size_t)bt * 32 + (lane & 31)];
    const float o = ((lane < 32) ? (nv * c - p * s) : (nv * c + p * s)) * oscale;

    const size_t oi = (size_t)bt * (NH * 64) + h * 64 + lane;
    const u16 hi = f2bf(o);
    outh[oi] = hi;
    outl[oi] = f2bf(o - bf2f(hi));
}

// ---------------------------------------------------------------------------
// V transpose + bf16 split (unchanged).
// ---------------------------------------------------------------------------
__global__ __launch_bounds__(256) void vtrans_kernel(
    const float* __restrict__ QKV, u16* __restrict__ Vth, u16* __restrict__ Vtl)
{
    __shared__ float tile[64][65];
    const int t0 = blockIdx.x * 64;
    const int bg = blockIdx.y;
    const int b = bg >> 2, g = bg & 3;
    const int tid = threadIdx.x;

    const int tl = tid >> 4, dq = (tid & 15) * 4;
    #pragma unroll
    for (int p = 0; p < 4; ++p) {
        const int t = tl + p * 16;
        const float4 v = *reinterpret_cast<const float4*>(
            &QKV[(size_t)(b * Tseq + t0 + t) * QKVN + 1280 + g * 64 + dq]);
        tile[t][dq + 0] = v.x; tile[t][dq + 1] = v.y;
        tile[t][dq + 2] = v.z; tile[t][dq + 3] = v.w;
    }
    __syncthreads();

    const int d = tid >> 2, tq = (tid & 3) * 16;
    u16 hv[16], lv[16];
    #pragma unroll
    for (int i = 0; i < 16; ++i) {
        const float v = tile[tq + i][d];
        hv[i] = f2bf(v);
        lv[i] = f2bf(v - bf2f(hv[i]));
    }
    const size_t oi = ((size_t)(bg * 64 + d)) * Tseq + t0 + tq;
    *reinterpret_cast<uint4*>(&Vth[oi])     = *reinterpret_cast<uint4*>(&hv[0]);
    *reinterpret_cast<uint4*>(&Vth[oi + 8]) = *reinterpret_cast<uint4*>(&hv[8]);
    *reinterpret_cast<uint4*>(&Vtl[oi])     = *reinterpret_cast<uint4*>(&lv[0]);
    *reinterpret_cast<uint4*>(&Vtl[oi + 8]) = *reinterpret_cast<uint4*>(&lv[8]);
}

// ---------------------------------------------------------------------------
// MFMA flash attention v3: LDS-shared K/V across the GQA group.
// Block = (b, g, 16-row q-window); wave w = head g*4+w. All 4 waves share the
// SAME K/V tiles (identical causal range), staged cooperatively into LDS per
// 64-key tile with global->reg prefetch of tile n+1 during compute of n.
// S = Qh*Kh + Ql*Kh + Qh*Kl; PV = P*Vh + P*Vl (Ootomo split, ~fp32 quality).
// P round-trips through wave-private LDS. Heavy windows launch first.
// Grid: B*G*(T/16) = 1024 blocks; blockIdx&7 -> (b,g) for XCD/L2 locality.
// ---------------------------------------------------------------------------
__global__ __launch_bounds__(256) void attn_mfma_kernel(
    const u16* __restrict__ Qh, const u16* __restrict__ Ql,
    const u16* __restrict__ Kh, const u16* __restrict__ Kl,
    const u16* __restrict__ Vth, const u16* __restrict__ Vtl,
    u16* __restrict__ AOh, u16* __restrict__ AOl)
{
    __shared__ u16 KsH[64 * 72];   // [s][k], stride 72 elems (144B)
    __shared__ u16 KsL[64 * 72];
    __shared__ u16 VsH[64 * 72];   // [d][t]
    __shared__ u16 VsL[64 * 72];
    __shared__ u16 Ps[4][16 * 72]; // wave-private P tiles

    const int tid = threadIdx.x;
    const int wave = tid >> 6, lane = tid & 63;
    const int l15 = lane & 15, quad = lane >> 4;

    const int bg = blockIdx.x & 7;             // (b,g): XCD/L2 locality
    const int b = bg >> 2, g = bg & 3;
    const int win = 127 - (blockIdx.x >> 3);   // heavy-first
    const int t0 = win * 16;
    const int h = g * 4 + wave;                // this wave's head

    // Q fragments (A-layout: row=l15, k=quad*8+j); scale folded upstream.
    bf16x8 qh[2], ql[2];
    {
        const size_t qrow = (size_t)(b * Tseq + t0 + l15) * 1024 + h * 64;
        #pragma unroll
        for (int ks = 0; ks < 2; ++ks) {
            qh[ks] = *reinterpret_cast<const bf16x8*>(&Qh[qrow + ks * 32 + quad * 8]);
            ql[ks] = *reinterpret_cast<const bf16x8*>(&Ql[qrow + ks * 32 + quad * 8]);
        }
    }

    // Cooperative staging assignment: thread -> (row 0..63, 16-elem col pair).
    const int srow = tid >> 2;
    const int scol = (tid & 3) * 16;
    const size_t kgb = (size_t)(b * Tseq) * 256 + g * 64 + scol; // + (s0+srow)*256
    const size_t vgb = (size_t)(bg * 64 + srow) * Tseq + scol;   // + s0

    const int nit = t0 / 64 + 1;

    // Preload tile 0 into registers.
    uint4 ck0, ck1, cl0, cl1, cv0, cv1, cw0, cw1;
    {
        const size_t ka = kgb + (size_t)srow * 256;
        ck0 = *reinterpret_cast<const uint4*>(&Kh[ka]);
        ck1 = *reinterpret_cast<const uint4*>(&Kh[ka + 8]);
        cl0 = *reinterpret_cast<const uint4*>(&Kl[ka]);
        cl1 = *reinterpret_cast<const uint4*>(&Kl[ka + 8]);
        cv0 = *reinterpret_cast<const uint4*>(&Vth[vgb]);
        cv1 = *reinterpret_cast<const uint4*>(&Vth[vgb + 8]);
        cw0 = *reinterpret_cast<const uint4*>(&Vtl[vgb]);
        cw1 = *reinterpret_cast<const uint4*>(&Vtl[vgb + 8]);
    }

    f32x4 oacc[4];
    #pragma unroll
    for (int nt = 0; nt < 4; ++nt) oacc[nt] = (f32x4){0.f, 0.f, 0.f, 0.f};
    float m_r[4], l_r[4];
    #pragma unroll
    for (int r = 0; r < 4; ++r) { m_r[r] = -1e30f; l_r[r] = 0.0f; }

    u16* psw = &Ps[wave][0];
    const int lb = srow * 72 + scol;

    for (int it = 0; it < nit; ++it) {
        const int s0 = it * 64;
        const bool diag = (it == nit - 1);

        __syncthreads();   // previous tile fully consumed
        *reinterpret_cast<uint4*>(&KsH[lb])     = ck0;
        *reinterpret_cast<uint4*>(&KsH[lb + 8]) = ck1;
        *reinterpret_cast<uint4*>(&KsL[lb])     = cl0;
        *reinterpret_cast<uint4*>(&KsL[lb + 8]) = cl1;
        *reinterpret_cast<uint4*>(&VsH[lb])     = cv0;
        *reinterpret_cast<uint4*>(&VsH[lb + 8]) = cv1;
        *reinterpret_cast<uint4*>(&VsL[lb])     = cw0;
        *reinterpret_cast<uint4*>(&VsL[lb + 8]) = cw1;
        if (it + 1 < nit) {   // prefetch next tile (in flight during compute)
            const size_t ka = kgb + (size_t)(s0 + 64 + srow) * 256;
            ck0 = *reinterpret_cast<const uint4*>(&Kh[ka]);
            ck1 = *reinterpret_cast<const uint4*>(&Kh[ka + 8]);
            cl0 = *reinterpret_cast<const uint4*>(&Kl[ka]);
            cl1 = *reinterpret_cast<const uint4*>(&Kl[ka + 8]);
            const size_t va = vgb + s0 + 64;
            cv0 = *reinterpret_cast<const uint4*>(&Vth[va]);
            cv1 = *reinterpret_cast<const uint4*>(&Vth[va + 8]);
            cw0 = *reinterpret_cast<const uint4*>(&Vtl[va]);
            cw1 = *reinterpret_cast<const uint4*>(&Vtl[va + 8]);
        }
        __syncthreads();   // tile visible

        // ---- S = Q K^T (split x3), fragments from LDS ----
        f32x4 sacc[4];
        #pragma unroll
        for (int nt = 0; nt < 4; ++nt) sacc[nt] = (f32x4){0.f, 0.f, 0.f, 0.f};

        #pragma unroll
        for (int ks = 0; ks < 2; ++ks) {
            bf16x8 kfh[4], kfl[4];
            #pragma unroll
            for (int nt = 0; nt < 4; ++nt) {
                const int a = (nt * 16 + l15) * 72 + ks * 32 + quad * 8;
                kfh[nt] = *reinterpret_cast<const bf16x8*>(&KsH[a]);
                kfl[nt] = *reinterpret_cast<const bf16x8*>(&KsL[a]);
            }
            #pragma unroll
            for (int nt = 0; nt < 4; ++nt) {
                sacc[nt] = __builtin_amdgcn_mfma_f32_16x16x32_bf16(qh[ks], kfh[nt], sacc[nt], 0, 0, 0);
                sacc[nt] = __builtin_amdgcn_mfma_f32_16x16x32_bf16(ql[ks], kfh[nt], sacc[nt], 0, 0, 0);
                sacc[nt] = __builtin_amdgcn_mfma_f32_16x16x32_bf16(qh[ks], kfl[nt], sacc[nt], 0, 0, 0);
            }
        }

        if (diag) {
            #pragma unroll
            for (int nt = 0; nt < 4; ++nt) {
                const int sg = s0 + nt * 16 + l15;
                #pragma unroll
                for (int r = 0; r < 4; ++r)
                    if (sg > t0 + quad * 4 + r) sacc[nt][r] = -1e30f;
            }
        }

        // ---- online softmax (row group = 16 lanes within quad) ----
        #pragma unroll
        for (int r = 0; r < 4; ++r) {
            float mx = fmaxf(fmaxf(sacc[0][r], sacc[1][r]),
                             fmaxf(sacc[2][r], sacc[3][r]));
            #pragma unroll
            for (int off = 1; off < 16; off <<= 1)
                mx = fmaxf(mx, __shfl_xor(mx, off, 16));
            const float mnew = fmaxf(m_r[r], mx);
            const float alpha = __expf(m_r[r] - mnew);
            m_r[r] = mnew;

            float rs = 0.0f;
            #pragma unroll
            for (int nt = 0; nt < 4; ++nt) {
                const float p = __expf(sacc[nt][r] - mnew);
                sacc[nt][r] = p;
                rs += p;
            }
            #pragma unroll
            for (int off = 1; off < 16; off <<= 1)
                rs += __shfl_xor(rs, off, 16);
            l_r[r] = l_r[r] * alpha + rs;
            #pragma unroll
            for (int nt = 0; nt < 4; ++nt) oacc[nt][r] *= alpha;
            #pragma unroll
            for (int nt = 0; nt < 4; ++nt)
                psw[(quad * 4 + r) * 72 + nt * 16 + l15] = f2bf(sacc[nt][r]);
        }
        // wave-private P: compiler's lgkmcnt ordering suffices, no barrier.

        // ---- O += P V (split V x2) ----
        #pragma unroll
        for (int ks = 0; ks < 2; ++ks) {
            const bf16x8 pa = *reinterpret_cast<const bf16x8*>(
                &psw[l15 * 72 + ks * 32 + quad * 8]);
            bf16x8 vfh[4], vfl[4];
            #pragma unroll
            for (int nt = 0; nt < 4; ++nt) {
                const int a = (nt * 16 + l15) * 72 + ks * 32 + quad * 8;
                vfh[nt] = *reinterpret_cast<const bf16x8*>(&VsH[a]);
                vfl[nt] = *reinterpret_cast<const bf16x8*>(&VsL[a]);
            }
            #pragma unroll
            for (int nt = 0; nt < 4; ++nt) {
                oacc[nt] = __builtin_amdgcn_mfma_f32_16x16x32_bf16(pa, vfh[nt], oacc[nt], 0, 0, 0);
                oacc[nt] = __builtin_amdgcn_mfma_f32_16x16x32_bf16(pa, vfl[nt], oacc[nt], 0, 0, 0);
            }
        }
    }

    // ---- epilogue: normalize, split bf16, store ----
    #pragma unroll
    for (int r = 0; r < 4; ++r) {
        const float inv = 1.0f / l_r[r];
        const size_t orow = (size_t)(b * Tseq + t0 + quad * 4 + r) * 1024 + h * 64;
        #pragma unroll
        for (int nt = 0; nt < 4; ++nt) {
            const float o = oacc[nt][r] * inv;
            const u16 hi = f2bf(o);
            AOh[orow + nt * 16 + l15] = hi;
            AOl[orow + nt * 16 + l15] = f2bf(o - bf2f(hi));
        }
    }
}

// ---------------------------------------------------------------------------
// Host launcher
// ---------------------------------------------------------------------------
extern "C" void kernel_launch(void* const* d_in, const int* in_sizes, int n_in,
                              void* d_out, int out_size, void* d_ws,
                              size_t ws_size, hipStream_t stream)
{
    const float* hidden = (const float*)d_in[0];
    const float* sinp   = (const float*)d_in[1];
    const float* cosp   = (const float*)d_in[2];
    // d_in[3] = mask — causal, handled analytically
    const float* ln1    = (const float*)d_in[4];
    const float* ln2    = (const float*)d_in[5];
    const float* qn     = (const float*)d_in[6];
    const float* kn     = (const float*)d_in[7];
    const float* q_w    = (const float*)d_in[8];
    const float* k_w    = (const float*)d_in[9];
    const float* v_w    = (const float*)d_in[10];
    const float* o_w    = (const float*)d_in[11];
    const float* gate_w = (const float*)d_in[12];
    const float* up_w   = (const float*)d_in[13];
    const float* down_w = (const float*)d_in[14];
    float* out = (float*)d_out;

    // ---- workspace layout (116.4 MB, with aliasing) ----
    char* base = (char*)d_ws;
    u16*   OTh  = (u16*)(base);                       //  2,097,152
    u16*   OTl  = (u16*)(base + 2097152);             //  2,097,152
    u16*   GTh  = (u16*)(base + 4194304);             //  8,388,608
    u16*   UTh  = (u16*)(base + 12582912);            //  8,388,608
    u16*   DTh  = (u16*)(base + 20971520);            //  8,388,608
    float* QKV  = (float*)(base + 29360128);          // 25,165,824 fp32
    u16*   Qbh  = (u16*)(base + 54525952);            //  8,388,608
    u16*   Qbl  = (u16*)(base + 62914560);            //  8,388,608
    u16*   FFh  = (u16*)(base + 71303168);            // 33,554,432
    u16*   QKVT = (u16*)(base + 104857600);           //  3,145,728
    u16*   Xh   = (u16*)(base + 108003328);           //  8,388,608  (end 116,391,936)

    // aliases (lifetime-checked):
    u16*   Kbh  = QKVT;                                // post-QKV-gemm
    u16*   Kbl  = Kbh + (size_t)4096 * 256;
    u16*   Vth  = Kbl + (size_t)4096 * 256;
    u16*   Vtl  = Vth + (size_t)8 * 64 * 2048;
    u16*   AOh  = (u16*)QKV;                           // over QKV (dead post-vtrans)
    u16*   AOl  = AOh + (size_t)4096 * 1024;
    u16*   Yl   = (u16*)(base + 29360128 + 16777216);  // QKV tail
    float* H2   = (float*)Qbh;                         // over Qh/Ql (dead post-attn)
    u16*   Yh   = Kbh;                                 // over K/V bf16 (dead post-attn)

    // 0. weight prep
    wprep_kernel<0><<<dim3(32, 32), 256, 0, stream>>>(q_w, QKVT, nullptr, 1024, 1024);
    wprep_kernel<0><<<dim3(8, 32), 256, 0, stream>>>(k_w, QKVT + (size_t)1024 * 1024, nullptr, 1024, 256);
    wprep_kernel<0><<<dim3(8, 32), 256, 0, stream>>>(v_w, QKVT + (size_t)1280 * 1024, nullptr, 1024, 256);
    wprep_kernel<1><<<dim3(32, 32), 256, 0, stream>>>(o_w, OTh, OTl, 1024, 1024);
    wprep_kernel<0><<<dim3(128, 32), 256, 0, stream>>>(gate_w, GTh, nullptr, 1024, 4096);
    wprep_kernel<0><<<dim3(128, 32), 256, 0, stream>>>(up_w, UTh, nullptr, 1024, 4096);
    wprep_kernel<0><<<dim3(32, 128), 256, 0, stream>>>(down_w, DTh, nullptr, 4096, 1024);

    // 1. x = rmsnorm(hidden, ln1) -> bf16
    rmsnorm_split_kernel<0><<<Mrows, 256, 0, stream>>>(hidden, ln1, Xh, nullptr);

    // 2. fused qkv projection -> QKV fp32
    mfma_gemm_kernel<0, 0, 0><<<dim3(QKVN / 128, Mrows / 128), 256, 0, stream>>>(
        Xh, nullptr, QKVT, nullptr, nullptr, QKV, Mrows, QKVN, 1024);

    // 3. qk-norm + rope -> bf16 hi/lo (Q scaled by K^-0.5); V transpose+split
    qkrope_bf16_kernel<<<Mrows * Hh / 4, 256, 0, stream>>>(
        QKV, qn, sinp, cosp, Qbh, Qbl, Hh, 0.125f);
    qkrope_bf16_kernel<<<Mrows * Gg / 4, 256, 0, stream>>>(
        QKV + 1024, kn, sinp, cosp, Kbh, Kbl, Gg, 1.0f);
    vtrans_kernel<<<dim3(Tseq / 64, Bsz * Gg), 256, 0, stream>>>(QKV, Vth, Vtl);

    // 4. MFMA flash attention v3 -> AO bf16 hi/lo
    attn_mfma_kernel<<<Bsz * Gg * (Tseq / 16), 256, 0, stream>>>(
        Qbh, Qbl, Kbh, Kbl, Vth, Vtl, AOh, AOl);

    // 5. hidden2 = hidden + attn @ o_w  (split x split)
    mfma_gemm_kernel<1, 1, 1><<<dim3(8, 32), 256, 0, stream>>>(
        AOh, AOl, OTh, OTl, hidden, H2, Mrows, Dmod, 1024);

    // 6. y = rmsnorm(hidden2, ln2) -> bf16 hi/lo
    rmsnorm_split_kernel<1><<<Mrows, 256, 0, stream>>>(H2, ln2, Yh, Yl);

    // 7. ff = silu(y@gate_w) * (y@up_w) -> FF bf16
    mfma_gateup_kernel<<<dim3(32, 32), 256, 0, stream>>>(
        Yh, Yl, GTh, UTh, FFh, Mrows, Ff, 1024);

    // 8. out = hidden2 + ff @ down_w
    mfma_gemm_kernel<0, 0, 1><<<dim3(8, 32), 256, 0, stream>>>(
        FFh, nullptr, DTh, nullptr, H2, out, Mrows, Dmod, 4096);
}

// Round 6
// 655.568 us; speedup vs baseline: 5.3674x; 1.0036x over previous
//
#include <hip/hip_runtime.h>
#include <hip/hip_bf16.h>

// Problem constants: B=2, T=2048, D=1024, H=16, G=4, K=64, F=4096
#define EPSF 1e-6f
constexpr int Bsz  = 2;
constexpr int Tseq = 2048;
constexpr int Dmod = 1024;
constexpr int Hh   = 16;
constexpr int Gg   = 4;
constexpr int Ff   = 4096;
constexpr int Mrows = Bsz * Tseq;          // 4096 tokens
constexpr int QKVN = 1536;                 // fused q(1024)|k(256)|v(256)

typedef __attribute__((ext_vector_type(8))) short bf16x8;   // 8 bf16 (4 VGPRs)
typedef __attribute__((ext_vector_type(4))) float f32x4;
typedef unsigned short u16;

// RNE fp32 -> bf16 (bit pattern as u16)
__device__ inline u16 f2bf(float x) {
    union { float f; unsigned u; } v; v.f = x;
    unsigned r = v.u + 0x7fff + ((v.u >> 16) & 1);
    return (u16)(r >> 16);
}
__device__ inline float bf2f(u16 h) {
    union { unsigned u; float f; } v; v.u = ((unsigned)h) << 16; return v.f;
}

// Async global->LDS DMA, 16 B per lane. LDS dest is wave-uniform base +
// lane*16 (m104 caveat) -- callers arrange lane's lds ptr == base + lane*16.
__device__ __forceinline__ void async_copy16(const u16* g, u16* l) {
    __builtin_amdgcn_global_load_lds(
        (const __attribute__((address_space(1))) void*)g,
        (__attribute__((address_space(3))) void*)l, 16, 0, 0);
}

// ---------------------------------------------------------------------------
// Weight prep: W[Kd][N] fp32 -> Th[N][Kd] bf16 (hi) and optional Tl (lo).
// ---------------------------------------------------------------------------
template <int LO>
__global__ __launch_bounds__(256) void wprep_kernel(
    const float* __restrict__ W, u16* __restrict__ Th, u16* __restrict__ Tl,
    int Kd, int N)
{
    __shared__ float tile[32][33];
    const int n0 = blockIdx.x * 32, k0 = blockIdx.y * 32;
    const int r = threadIdx.x >> 3, c4 = (threadIdx.x & 7) * 4;
    const float4 v = *reinterpret_cast<const float4*>(&W[(size_t)(k0 + r) * N + n0 + c4]);
    tile[r][c4 + 0] = v.x; tile[r][c4 + 1] = v.y;
    tile[r][c4 + 2] = v.z; tile[r][c4 + 3] = v.w;
    __syncthreads();
    const int nl = threadIdx.x >> 3, kq = (threadIdx.x & 7) * 4;
    float x0 = tile[kq + 0][nl], x1 = tile[kq + 1][nl];
    float x2 = tile[kq + 2][nl], x3 = tile[kq + 3][nl];
    ushort4 h;
    h.x = f2bf(x0); h.y = f2bf(x1); h.z = f2bf(x2); h.w = f2bf(x3);
    *reinterpret_cast<ushort4*>(&Th[(size_t)(n0 + nl) * Kd + k0 + kq]) = h;
    if (LO) {
        ushort4 l;
        l.x = f2bf(x0 - bf2f(h.x)); l.y = f2bf(x1 - bf2f(h.y));
        l.z = f2bf(x2 - bf2f(h.z)); l.w = f2bf(x3 - bf2f(h.w));
        *reinterpret_cast<ushort4*>(&Tl[(size_t)(n0 + nl) * Kd + k0 + kq]) = l;
    }
}

// ---------------------------------------------------------------------------
// RMSNorm over D=1024 -> bf16 hi (+ optional lo). One block per token.
// ---------------------------------------------------------------------------
template <int LO>
__global__ __launch_bounds__(256) void rmsnorm_split_kernel(
    const float* __restrict__ x, const float* __restrict__ scale,
    u16* __restrict__ oh, u16* __restrict__ ol)
{
    const int row = blockIdx.x;
    const int tid = threadIdx.x;
    const float4 v = reinterpret_cast<const float4*>(x + (size_t)row * Dmod)[tid];
    float ss = v.x * v.x + v.y * v.y + v.z * v.z + v.w * v.w;
    #pragma unroll
    for (int off = 32; off; off >>= 1) ss += __shfl_xor(ss, off, 64);
    __shared__ float part[4];
    if ((tid & 63) == 0) part[tid >> 6] = ss;
    __syncthreads();
    const float tot = part[0] + part[1] + part[2] + part[3];
    const float rstd = rsqrtf(tot * (1.0f / Dmod) + EPSF);
    const float4 sc = reinterpret_cast<const float4*>(scale)[tid];
    float o0 = v.x * rstd * sc.x, o1 = v.y * rstd * sc.y;
    float o2 = v.z * rstd * sc.z, o3 = v.w * rstd * sc.w;
    ushort4 h;
    h.x = f2bf(o0); h.y = f2bf(o1); h.z = f2bf(o2); h.w = f2bf(o3);
    *reinterpret_cast<ushort4*>(&oh[(size_t)row * Dmod + tid * 4]) = h;
    if (LO) {
        ushort4 l;
        l.x = f2bf(o0 - bf2f(h.x)); l.y = f2bf(o1 - bf2f(h.y));
        l.z = f2bf(o2 - bf2f(h.z)); l.w = f2bf(o3 - bf2f(h.w));
        *reinterpret_cast<ushort4*>(&ol[(size_t)row * Dmod + tid * 4]) = l;
    }
}

// ---------------------------------------------------------------------------
// Split-bf16 MFMA GEMM with async global_load_lds staging (m97 structure).
// 128x128 tile, BK=32, 4 waves; wave w stages rows [w*32,(w+1)*32) of each
// LDS buffer: lane -> row lane/4, 16B chunk lane%4 => lds off = lane*16.
// ---------------------------------------------------------------------------
template <int ASPLIT, int BSPLIT, int RES>
__global__ __launch_bounds__(256) void mfma_gemm_kernel(
    const u16* __restrict__ Ah, const u16* __restrict__ Al,
    const u16* __restrict__ Bh, const u16* __restrict__ Bl,
    const float* __restrict__ res, float* __restrict__ C,
    int M, int N, int Kd)
{
    __shared__ u16 As_h[128 * 32];
    __shared__ u16 As_l[128 * 32];
    __shared__ u16 Bs_h[128 * 32];
    __shared__ u16 Bs_l[128 * 32];

    const int tid = threadIdx.x;
    const int lane = tid & 63, wave = tid >> 6;
    const int wm = (wave >> 1) * 64, wn = (wave & 1) * 64;
    const int m0 = blockIdx.y * 128, n0 = blockIdx.x * 128;
    const int fm = lane & 15, fq = (lane >> 4) * 8;

    f32x4 acc[4][4];
    #pragma unroll
    for (int i = 0; i < 4; ++i)
        #pragma unroll
        for (int j = 0; j < 4; ++j) acc[i][j] = (f32x4){0.f, 0.f, 0.f, 0.f};

    const int lrow = lane >> 2;          // 0..15
    const int lcol = (lane & 3) * 8;     // element offset (16 B chunks)

    for (int k0 = 0; k0 < Kd; k0 += 32) {
        __syncthreads();   // previous tile consumed
        #pragma unroll
        for (int p = 0; p < 2; ++p) {
            const int row = wave * 32 + p * 16 + lrow;
            const size_t ga = (size_t)(m0 + row) * Kd + k0 + lcol;
            const size_t gb = (size_t)(n0 + row) * Kd + k0 + lcol;
            const int ls = row * 32 + lcol;
            async_copy16(&Ah[ga], &As_h[ls]);
            if (ASPLIT) async_copy16(&Al[ga], &As_l[ls]);
            async_copy16(&Bh[gb], &Bs_h[ls]);
            if (BSPLIT) async_copy16(&Bl[gb], &Bs_l[ls]);
        }
        __syncthreads();   // drains vmcnt -> tile visible

        bf16x8 ah[4], al[4], bh[4], bl[4];
        #pragma unroll
        for (int t = 0; t < 4; ++t) {
            ah[t] = *reinterpret_cast<const bf16x8*>(&As_h[(wm + t * 16 + fm) * 32 + fq]);
            bh[t] = *reinterpret_cast<const bf16x8*>(&Bs_h[(wn + t * 16 + fm) * 32 + fq]);
            if (ASPLIT)
                al[t] = *reinterpret_cast<const bf16x8*>(&As_l[(wm + t * 16 + fm) * 32 + fq]);
            if (BSPLIT)
                bl[t] = *reinterpret_cast<const bf16x8*>(&Bs_l[(wn + t * 16 + fm) * 32 + fq]);
        }
        #pragma unroll
        for (int mt = 0; mt < 4; ++mt)
            #pragma unroll
            for (int nt = 0; nt < 4; ++nt) {
                acc[mt][nt] = __builtin_amdgcn_mfma_f32_16x16x32_bf16(
                    ah[mt], bh[nt], acc[mt][nt], 0, 0, 0);
                if (BSPLIT)
                    acc[mt][nt] = __builtin_amdgcn_mfma_f32_16x16x32_bf16(
                        ah[mt], bl[nt], acc[mt][nt], 0, 0, 0);
                if (ASPLIT)
                    acc[mt][nt] = __builtin_amdgcn_mfma_f32_16x16x32_bf16(
                        al[mt], bh[nt], acc[mt][nt], 0, 0, 0);
            }
    }

    const int cr = (lane >> 4) * 4, cn = lane & 15;
    #pragma unroll
    for (int mt = 0; mt < 4; ++mt)
        #pragma unroll
        for (int nt = 0; nt < 4; ++nt)
            #pragma unroll
            for (int r = 0; r < 4; ++r) {
                const int gm = m0 + wm + mt * 16 + cr + r;
                const int gn = n0 + wn + nt * 16 + cn;
                float v = acc[mt][nt][r];
                if (RES) v += res[(size_t)gm * N + gn];
                C[(size_t)gm * N + gn] = v;
            }
}

// ---------------------------------------------------------------------------
// Fused gate/up MFMA GEMM + silu epilogue, async global_load_lds staging.
// ---------------------------------------------------------------------------
__global__ __launch_bounds__(256) void mfma_gateup_kernel(
    const u16* __restrict__ Ah, const u16* __restrict__ Al,
    const u16* __restrict__ Bg, const u16* __restrict__ Bu,
    u16* __restrict__ FF, int M, int N, int Kd)
{
    __shared__ u16 As_h[128 * 32];
    __shared__ u16 As_l[128 * 32];
    __shared__ u16 Gs[128 * 32];
    __shared__ u16 Us[128 * 32];

    const int tid = threadIdx.x;
    const int lane = tid & 63, wave = tid >> 6;
    const int wm = (wave >> 1) * 64, wn = (wave & 1) * 64;
    const int m0 = blockIdx.y * 128, n0 = blockIdx.x * 128;
    const int fm = lane & 15, fq = (lane >> 4) * 8;

    f32x4 accg[4][4], accu[4][4];
    #pragma unroll
    for (int i = 0; i < 4; ++i)
        #pragma unroll
        for (int j = 0; j < 4; ++j) {
            accg[i][j] = (f32x4){0.f, 0.f, 0.f, 0.f};
            accu[i][j] = (f32x4){0.f, 0.f, 0.f, 0.f};
        }

    const int lrow = lane >> 2;
    const int lcol = (lane & 3) * 8;

    for (int k0 = 0; k0 < Kd; k0 += 32) {
        __syncthreads();
        #pragma unroll
        for (int p = 0; p < 2; ++p) {
            const int row = wave * 32 + p * 16 + lrow;
            const size_t ga = (size_t)(m0 + row) * Kd + k0 + lcol;
            const size_t gb = (size_t)(n0 + row) * Kd + k0 + lcol;
            const int ls = row * 32 + lcol;
            async_copy16(&Ah[ga], &As_h[ls]);
            async_copy16(&Al[ga], &As_l[ls]);
            async_copy16(&Bg[gb], &Gs[ls]);
            async_copy16(&Bu[gb], &Us[ls]);
        }
        __syncthreads();

        bf16x8 ah[4], al[4], bg[4], bu[4];
        #pragma unroll
        for (int t = 0; t < 4; ++t) {
            ah[t] = *reinterpret_cast<const bf16x8*>(&As_h[(wm + t * 16 + fm) * 32 + fq]);
            al[t] = *reinterpret_cast<const bf16x8*>(&As_l[(wm + t * 16 + fm) * 32 + fq]);
            bg[t] = *reinterpret_cast<const bf16x8*>(&Gs[(wn + t * 16 + fm) * 32 + fq]);
            bu[t] = *reinterpret_cast<const bf16x8*>(&Us[(wn + t * 16 + fm) * 32 + fq]);
        }
        #pragma unroll
        for (int mt = 0; mt < 4; ++mt)
            #pragma unroll
            for (int nt = 0; nt < 4; ++nt) {
                accg[mt][nt] = __builtin_amdgcn_mfma_f32_16x16x32_bf16(
                    ah[mt], bg[nt], accg[mt][nt], 0, 0, 0);
                accg[mt][nt] = __builtin_amdgcn_mfma_f32_16x16x32_bf16(
                    al[mt], bg[nt], accg[mt][nt], 0, 0, 0);
                accu[mt][nt] = __builtin_amdgcn_mfma_f32_16x16x32_bf16(
                    ah[mt], bu[nt], accu[mt][nt], 0, 0, 0);
                accu[mt][nt] = __builtin_amdgcn_mfma_f32_16x16x32_bf16(
                    al[mt], bu[nt], accu[mt][nt], 0, 0, 0);
            }
    }

    const int cr = (lane >> 4) * 4, cn = lane & 15;
    #pragma unroll
    for (int mt = 0; mt < 4; ++mt)
        #pragma unroll
        for (int nt = 0; nt < 4; ++nt)
            #pragma unroll
            for (int r = 0; r < 4; ++r) {
                const int gm = m0 + wm + mt * 16 + cr + r;
                const int gn = n0 + wn + nt * 16 + cn;
                const float g = accg[mt][nt][r];
                const float ff = (g / (1.0f + __expf(-g))) * accu[mt][nt][r];
                FF[(size_t)gm * N + gn] = f2bf(ff);
            }
}

// ---------------------------------------------------------------------------
// Per-head RMSNorm + RoPE, fp32 QKV (stride 1536) -> bf16 hi/lo (scale folded).
// ---------------------------------------------------------------------------
__global__ __launch_bounds__(256) void qkrope_bf16_kernel(
    const float* __restrict__ src, const float* __restrict__ nsc,
    const float* __restrict__ sinp, const float* __restrict__ cosp,
    u16* __restrict__ outh, u16* __restrict__ outl,
    int NH, float oscale)
{
    const int lane = threadIdx.x & 63;
    const int w = threadIdx.x >> 6;
    const int head = blockIdx.x * 4 + w;
    const int bt = head / NH;
    const int h = head % NH;

    const float v = src[(size_t)bt * QKVN + h * 64 + lane];
    float ss = v * v;
    #pragma unroll
    for (int off = 32; off; off >>= 1) ss += __shfl_xor(ss, off, 64);
    const float rstd = rsqrtf(ss * (1.0f / 64.0f) + EPSF);
    const float nv = v * rstd * nsc[lane];

    const float p = __shfl_xor(nv, 32, 64);
    const float s = sinp[(size_t)bt * 32 + (lane & 31)];
    const float c = cosp[(size_t)bt * 32 + (lane & 31)];
    const float o = ((lane < 32) ? (nv * c - p * s) : (nv * c + p * s)) * oscale;

    const size_t oi = (size_t)bt * (NH * 64) + h * 64 + lane;
    const u16 hi = f2bf(o);
    outh[oi] = hi;
    outl[oi] = f2bf(o - bf2f(hi));
}

// ---------------------------------------------------------------------------
// V transpose + bf16 split (unchanged).
// ---------------------------------------------------------------------------
__global__ __launch_bounds__(256) void vtrans_kernel(
    const float* __restrict__ QKV, u16* __restrict__ Vth, u16* __restrict__ Vtl)
{
    __shared__ float tile[64][65];
    const int t0 = blockIdx.x * 64;
    const int bg = blockIdx.y;
    const int b = bg >> 2, g = bg & 3;
    const int tid = threadIdx.x;

    const int tl = tid >> 4, dq = (tid & 15) * 4;
    #pragma unroll
    for (int p = 0; p < 4; ++p) {
        const int t = tl + p * 16;
        const float4 v = *reinterpret_cast<const float4*>(
            &QKV[(size_t)(b * Tseq + t0 + t) * QKVN + 1280 + g * 64 + dq]);
        tile[t][dq + 0] = v.x; tile[t][dq + 1] = v.y;
        tile[t][dq + 2] = v.z; tile[t][dq + 3] = v.w;
    }
    __syncthreads();

    const int d = tid >> 2, tq = (tid & 3) * 16;
    u16 hv[16], lv[16];
    #pragma unroll
    for (int i = 0; i < 16; ++i) {
        const float v = tile[tq + i][d];
        hv[i] = f2bf(v);
        lv[i] = f2bf(v - bf2f(hv[i]));
    }
    const size_t oi = ((size_t)(bg * 64 + d)) * Tseq + t0 + tq;
    *reinterpret_cast<uint4*>(&Vth[oi])     = *reinterpret_cast<uint4*>(&hv[0]);
    *reinterpret_cast<uint4*>(&Vth[oi + 8]) = *reinterpret_cast<uint4*>(&hv[8]);
    *reinterpret_cast<uint4*>(&Vtl[oi])     = *reinterpret_cast<uint4*>(&lv[0]);
    *reinterpret_cast<uint4*>(&Vtl[oi + 8]) = *reinterpret_cast<uint4*>(&lv[8]);
}

// ---------------------------------------------------------------------------
// MFMA flash attention v3 (unchanged from round 5).
// ---------------------------------------------------------------------------
__global__ __launch_bounds__(256) void attn_mfma_kernel(
    const u16* __restrict__ Qh, const u16* __restrict__ Ql,
    const u16* __restrict__ Kh, const u16* __restrict__ Kl,
    const u16* __restrict__ Vth, const u16* __restrict__ Vtl,
    u16* __restrict__ AOh, u16* __restrict__ AOl)
{
    __shared__ u16 KsH[64 * 72];   // [s][k], stride 72 elems (144B)
    __shared__ u16 KsL[64 * 72];
    __shared__ u16 VsH[64 * 72];   // [d][t]
    __shared__ u16 VsL[64 * 72];
    __shared__ u16 Ps[4][16 * 72]; // wave-private P tiles

    const int tid = threadIdx.x;
    const int wave = tid >> 6, lane = tid & 63;
    const int l15 = lane & 15, quad = lane >> 4;

    const int bg = blockIdx.x & 7;             // (b,g): XCD/L2 locality
    const int b = bg >> 2, g = bg & 3;
    const int win = 127 - (blockIdx.x >> 3);   // heavy-first
    const int t0 = win * 16;
    const int h = g * 4 + wave;                // this wave's head

    bf16x8 qh[2], ql[2];
    {
        const size_t qrow = (size_t)(b * Tseq + t0 + l15) * 1024 + h * 64;
        #pragma unroll
        for (int ks = 0; ks < 2; ++ks) {
            qh[ks] = *reinterpret_cast<const bf16x8*>(&Qh[qrow + ks * 32 + quad * 8]);
            ql[ks] = *reinterpret_cast<const bf16x8*>(&Ql[qrow + ks * 32 + quad * 8]);
        }
    }

    const int srow = tid >> 2;
    const int scol = (tid & 3) * 16;
    const size_t kgb = (size_t)(b * Tseq) * 256 + g * 64 + scol;
    const size_t vgb = (size_t)(bg * 64 + srow) * Tseq + scol;

    const int nit = t0 / 64 + 1;

    uint4 ck0, ck1, cl0, cl1, cv0, cv1, cw0, cw1;
    {
        const size_t ka = kgb + (size_t)srow * 256;
        ck0 = *reinterpret_cast<const uint4*>(&Kh[ka]);
        ck1 = *reinterpret_cast<const uint4*>(&Kh[ka + 8]);
        cl0 = *reinterpret_cast<const uint4*>(&Kl[ka]);
        cl1 = *reinterpret_cast<const uint4*>(&Kl[ka + 8]);
        cv0 = *reinterpret_cast<const uint4*>(&Vth[vgb]);
        cv1 = *reinterpret_cast<const uint4*>(&Vth[vgb + 8]);
        cw0 = *reinterpret_cast<const uint4*>(&Vtl[vgb]);
        cw1 = *reinterpret_cast<const uint4*>(&Vtl[vgb + 8]);
    }

    f32x4 oacc[4];
    #pragma unroll
    for (int nt = 0; nt < 4; ++nt) oacc[nt] = (f32x4){0.f, 0.f, 0.f, 0.f};
    float m_r[4], l_r[4];
    #pragma unroll
    for (int r = 0; r < 4; ++r) { m_r[r] = -1e30f; l_r[r] = 0.0f; }

    u16* psw = &Ps[wave][0];
    const int lb = srow * 72 + scol;

    for (int it = 0; it < nit; ++it) {
        const int s0 = it * 64;
        const bool diag = (it == nit - 1);

        __syncthreads();
        *reinterpret_cast<uint4*>(&KsH[lb])     = ck0;
        *reinterpret_cast<uint4*>(&KsH[lb + 8]) = ck1;
        *reinterpret_cast<uint4*>(&KsL[lb])     = cl0;
        *reinterpret_cast<uint4*>(&KsL[lb + 8]) = cl1;
        *reinterpret_cast<uint4*>(&VsH[lb])     = cv0;
        *reinterpret_cast<uint4*>(&VsH[lb + 8]) = cv1;
        *reinterpret_cast<uint4*>(&VsL[lb])     = cw0;
        *reinterpret_cast<uint4*>(&VsL[lb + 8]) = cw1;
        if (it + 1 < nit) {
            const size_t ka = kgb + (size_t)(s0 + 64 + srow) * 256;
            ck0 = *reinterpret_cast<const uint4*>(&Kh[ka]);
            ck1 = *reinterpret_cast<const uint4*>(&Kh[ka + 8]);
            cl0 = *reinterpret_cast<const uint4*>(&Kl[ka]);
            cl1 = *reinterpret_cast<const uint4*>(&Kl[ka + 8]);
            const size_t va = vgb + s0 + 64;
            cv0 = *reinterpret_cast<const uint4*>(&Vth[va]);
            cv1 = *reinterpret_cast<const uint4*>(&Vth[va + 8]);
            cw0 = *reinterpret_cast<const uint4*>(&Vtl[va]);
            cw1 = *reinterpret_cast<const uint4*>(&Vtl[va + 8]);
        }
        __syncthreads();

        f32x4 sacc[4];
        #pragma unroll
        for (int nt = 0; nt < 4; ++nt) sacc[nt] = (f32x4){0.f, 0.f, 0.f, 0.f};

        #pragma unroll
        for (int ks = 0; ks < 2; ++ks) {
            bf16x8 kfh[4], kfl[4];
            #pragma unroll
            for (int nt = 0; nt < 4; ++nt) {
                const int a = (nt * 16 + l15) * 72 + ks * 32 + quad * 8;
                kfh[nt] = *reinterpret_cast<const bf16x8*>(&KsH[a]);
                kfl[nt] = *reinterpret_cast<const bf16x8*>(&KsL[a]);
            }
            #pragma unroll
            for (int nt = 0; nt < 4; ++nt) {
                sacc[nt] = __builtin_amdgcn_mfma_f32_16x16x32_bf16(qh[ks], kfh[nt], sacc[nt], 0, 0, 0);
                sacc[nt] = __builtin_amdgcn_mfma_f32_16x16x32_bf16(ql[ks], kfh[nt], sacc[nt], 0, 0, 0);
                sacc[nt] = __builtin_amdgcn_mfma_f32_16x16x32_bf16(qh[ks], kfl[nt], sacc[nt], 0, 0, 0);
            }
        }

        if (diag) {
            #pragma unroll
            for (int nt = 0; nt < 4; ++nt) {
                const int sg = s0 + nt * 16 + l15;
                #pragma unroll
                for (int r = 0; r < 4; ++r)
                    if (sg > t0 + quad * 4 + r) sacc[nt][r] = -1e30f;
            }
        }

        #pragma unroll
        for (int r = 0; r < 4; ++r) {
            float mx = fmaxf(fmaxf(sacc[0][r], sacc[1][r]),
                             fmaxf(sacc[2][r], sacc[3][r]));
            #pragma unroll
            for (int off = 1; off < 16; off <<= 1)
                mx = fmaxf(mx, __shfl_xor(mx, off, 16));
            const float mnew = fmaxf(m_r[r], mx);
            const float alpha = __expf(m_r[r] - mnew);
            m_r[r] = mnew;

            float rs = 0.0f;
            #pragma unroll
            for (int nt = 0; nt < 4; ++nt) {
                const float p = __expf(sacc[nt][r] - mnew);
                sacc[nt][r] = p;
                rs += p;
            }
            #pragma unroll
            for (int off = 1; off < 16; off <<= 1)
                rs += __shfl_xor(rs, off, 16);
            l_r[r] = l_r[r] * alpha + rs;
            #pragma unroll
            for (int nt = 0; nt < 4; ++nt) oacc[nt][r] *= alpha;
            #pragma unroll
            for (int nt = 0; nt < 4; ++nt)
                psw[(quad * 4 + r) * 72 + nt * 16 + l15] = f2bf(sacc[nt][r]);
        }

        #pragma unroll
        for (int ks = 0; ks < 2; ++ks) {
            const bf16x8 pa = *reinterpret_cast<const bf16x8*>(
                &psw[l15 * 72 + ks * 32 + quad * 8]);
            bf16x8 vfh[4], vfl[4];
            #pragma unroll
            for (int nt = 0; nt < 4; ++nt) {
                const int a = (nt * 16 + l15) * 72 + ks * 32 + quad * 8;
                vfh[nt] = *reinterpret_cast<const bf16x8*>(&VsH[a]);
                vfl[nt] = *reinterpret_cast<const bf16x8*>(&VsL[a]);
            }
            #pragma unroll
            for (int nt = 0; nt < 4; ++nt) {
                oacc[nt] = __builtin_amdgcn_mfma_f32_16x16x32_bf16(pa, vfh[nt], oacc[nt], 0, 0, 0);
                oacc[nt] = __builtin_amdgcn_mfma_f32_16x16x32_bf16(pa, vfl[nt], oacc[nt], 0, 0, 0);
            }
        }
    }

    #pragma unroll
    for (int r = 0; r < 4; ++r) {
        const float inv = 1.0f / l_r[r];
        const size_t orow = (size_t)(b * Tseq + t0 + quad * 4 + r) * 1024 + h * 64;
        #pragma unroll
        for (int nt = 0; nt < 4; ++nt) {
            const float o = oacc[nt][r] * inv;
            const u16 hi = f2bf(o);
            AOh[orow + nt * 16 + l15] = hi;
            AOl[orow + nt * 16 + l15] = f2bf(o - bf2f(hi));
        }
    }
}

// ---------------------------------------------------------------------------
// Host launcher
// ---------------------------------------------------------------------------
extern "C" void kernel_launch(void* const* d_in, const int* in_sizes, int n_in,
                              void* d_out, int out_size, void* d_ws,
                              size_t ws_size, hipStream_t stream)
{
    const float* hidden = (const float*)d_in[0];
    const float* sinp   = (const float*)d_in[1];
    const float* cosp   = (const float*)d_in[2];
    // d_in[3] = mask — causal, handled analytically
    const float* ln1    = (const float*)d_in[4];
    const float* ln2    = (const float*)d_in[5];
    const float* qn     = (const float*)d_in[6];
    const float* kn     = (const float*)d_in[7];
    const float* q_w    = (const float*)d_in[8];
    const float* k_w    = (const float*)d_in[9];
    const float* v_w    = (const float*)d_in[10];
    const float* o_w    = (const float*)d_in[11];
    const float* gate_w = (const float*)d_in[12];
    const float* up_w   = (const float*)d_in[13];
    const float* down_w = (const float*)d_in[14];
    float* out = (float*)d_out;

    // ---- workspace layout (116.4 MB, with aliasing) ----
    char* base = (char*)d_ws;
    u16*   OTh  = (u16*)(base);                       //  2,097,152
    u16*   OTl  = (u16*)(base + 2097152);             //  2,097,152
    u16*   GTh  = (u16*)(base + 4194304);             //  8,388,608
    u16*   UTh  = (u16*)(base + 12582912);            //  8,388,608
    u16*   DTh  = (u16*)(base + 20971520);            //  8,388,608
    float* QKV  = (float*)(base + 29360128);          // 25,165,824 fp32
    u16*   Qbh  = (u16*)(base + 54525952);            //  8,388,608
    u16*   Qbl  = (u16*)(base + 62914560);            //  8,388,608
    u16*   FFh  = (u16*)(base + 71303168);            // 33,554,432
    u16*   QKVT = (u16*)(base + 104857600);           //  3,145,728
    u16*   Xh   = (u16*)(base + 108003328);           //  8,388,608  (end 116,391,936)

    // aliases (lifetime-checked):
    u16*   Kbh  = QKVT;                                // post-QKV-gemm
    u16*   Kbl  = Kbh + (size_t)4096 * 256;
    u16*   Vth  = Kbl + (size_t)4096 * 256;
    u16*   Vtl  = Vth + (size_t)8 * 64 * 2048;
    u16*   AOh  = (u16*)QKV;                           // over QKV (dead post-vtrans)
    u16*   AOl  = AOh + (size_t)4096 * 1024;
    u16*   Yl   = (u16*)(base + 29360128 + 16777216);  // QKV tail
    float* H2   = (float*)Qbh;                         // over Qh/Ql (dead post-attn)
    u16*   Yh   = Kbh;                                 // over K/V bf16 (dead post-attn)

    // 0. weight prep
    wprep_kernel<0><<<dim3(32, 32), 256, 0, stream>>>(q_w, QKVT, nullptr, 1024, 1024);
    wprep_kernel<0><<<dim3(8, 32), 256, 0, stream>>>(k_w, QKVT + (size_t)1024 * 1024, nullptr, 1024, 256);
    wprep_kernel<0><<<dim3(8, 32), 256, 0, stream>>>(v_w, QKVT + (size_t)1280 * 1024, nullptr, 1024, 256);
    wprep_kernel<1><<<dim3(32, 32), 256, 0, stream>>>(o_w, OTh, OTl, 1024, 1024);
    wprep_kernel<0><<<dim3(128, 32), 256, 0, stream>>>(gate_w, GTh, nullptr, 1024, 4096);
    wprep_kernel<0><<<dim3(128, 32), 256, 0, stream>>>(up_w, UTh, nullptr, 1024, 4096);
    wprep_kernel<0><<<dim3(32, 128), 256, 0, stream>>>(down_w, DTh, nullptr, 4096, 1024);

    // 1. x = rmsnorm(hidden, ln1) -> bf16
    rmsnorm_split_kernel<0><<<Mrows, 256, 0, stream>>>(hidden, ln1, Xh, nullptr);

    // 2. fused qkv projection -> QKV fp32
    mfma_gemm_kernel<0, 0, 0><<<dim3(QKVN / 128, Mrows / 128), 256, 0, stream>>>(
        Xh, nullptr, QKVT, nullptr, nullptr, QKV, Mrows, QKVN, 1024);

    // 3. qk-norm + rope -> bf16 hi/lo (Q scaled by K^-0.5); V transpose+split
    qkrope_bf16_kernel<<<Mrows * Hh / 4, 256, 0, stream>>>(
        QKV, qn, sinp, cosp, Qbh, Qbl, Hh, 0.125f);
    qkrope_bf16_kernel<<<Mrows * Gg / 4, 256, 0, stream>>>(
        QKV + 1024, kn, sinp, cosp, Kbh, Kbl, Gg, 1.0f);
    vtrans_kernel<<<dim3(Tseq / 64, Bsz * Gg), 256, 0, stream>>>(QKV, Vth, Vtl);

    // 4. MFMA flash attention v3 -> AO bf16 hi/lo
    attn_mfma_kernel<<<Bsz * Gg * (Tseq / 16), 256, 0, stream>>>(
        Qbh, Qbl, Kbh, Kbl, Vth, Vtl, AOh, AOl);

    // 5. hidden2 = hidden + attn @ o_w  (split x split)
    mfma_gemm_kernel<1, 1, 1><<<dim3(8, 32), 256, 0, stream>>>(
        AOh, AOl, OTh, OTl, hidden, H2, Mrows, Dmod, 1024);

    // 6. y = rmsnorm(hidden2, ln2) -> bf16 hi/lo
    rmsnorm_split_kernel<1><<<Mrows, 256, 0, stream>>>(H2, ln2, Yh, Yl);

    // 7. ff = silu(y@gate_w) * (y@up_w) -> FF bf16
    mfma_gateup_kernel<<<dim3(32, 32), 256, 0, stream>>>(
        Yh, Yl, GTh, UTh, FFh, Mrows, Ff, 1024);

    // 8. out = hidden2 + ff @ down_w
    mfma_gemm_kernel<0, 0, 1><<<dim3(8, 32), 256, 0, stream>>>(
        FFh, nullptr, DTh, nullptr, H2, out, Mrows, Dmod, 4096);
}

// Round 7
// 561.667 us; speedup vs baseline: 6.2647x; 1.1672x over previous
//
#include <hip/hip_runtime.h>
#include <hip/hip_bf16.h>

// Problem constants: B=2, T=2048, D=1024, H=16, G=4, K=64, F=4096
#define EPSF 1e-6f
constexpr int Bsz  = 2;
constexpr int Tseq = 2048;
constexpr int Dmod = 1024;
constexpr int Hh   = 16;
constexpr int Gg   = 4;
constexpr int Ff   = 4096;
constexpr int Mrows = Bsz * Tseq;          // 4096 tokens
constexpr int QKVN = 1536;                 // fused q(1024)|k(256)|v(256)

typedef __attribute__((ext_vector_type(8))) short bf16x8;   // 8 bf16 (4 VGPRs)
typedef __attribute__((ext_vector_type(4))) float f32x4;
typedef unsigned short u16;

// RNE fp32 -> bf16 (bit pattern as u16)
__device__ inline u16 f2bf(float x) {
    union { float f; unsigned u; } v; v.f = x;
    unsigned r = v.u + 0x7fff + ((v.u >> 16) & 1);
    return (u16)(r >> 16);
}
__device__ inline float bf2f(u16 h) {
    union { unsigned u; float f; } v; v.u = ((unsigned)h) << 16; return v.f;
}

// Async global->LDS DMA, 16 B per lane. LDS dest is wave-uniform base +
// lane*16 (m104 caveat) -- callers arrange lane's lds ptr == base + lane*16.
__device__ __forceinline__ void async_copy16(const u16* g, u16* l) {
    __builtin_amdgcn_global_load_lds(
        (const __attribute__((address_space(1))) void*)g,
        (__attribute__((address_space(3))) void*)l, 16, 0, 0);
}

// Bank-swizzle note: LDS tiles are [row][32] bf16 (64 B rows). Logical k-chunk
// q (16 B) of row R is stored at LDS chunk q ^ ((R>>1)&3). Staging achieves
// this by fetching global chunk (lane&3)^((row>>1)&3) into linear dest
// lane*16; fragment reads XOR the same term. Bank = 16(R&1)+4c -> 2-way (free)
// instead of the 8-way conflict of the linear layout (m136).

// ---------------------------------------------------------------------------
// Weight prep: W[Kd][N] fp32 -> Th[N][Kd] bf16 (hi) and optional Tl (lo).
// ---------------------------------------------------------------------------
template <int LO>
__global__ __launch_bounds__(256) void wprep_kernel(
    const float* __restrict__ W, u16* __restrict__ Th, u16* __restrict__ Tl,
    int Kd, int N)
{
    __shared__ float tile[32][33];
    const int n0 = blockIdx.x * 32, k0 = blockIdx.y * 32;
    const int r = threadIdx.x >> 3, c4 = (threadIdx.x & 7) * 4;
    const float4 v = *reinterpret_cast<const float4*>(&W[(size_t)(k0 + r) * N + n0 + c4]);
    tile[r][c4 + 0] = v.x; tile[r][c4 + 1] = v.y;
    tile[r][c4 + 2] = v.z; tile[r][c4 + 3] = v.w;
    __syncthreads();
    const int nl = threadIdx.x >> 3, kq = (threadIdx.x & 7) * 4;
    float x0 = tile[kq + 0][nl], x1 = tile[kq + 1][nl];
    float x2 = tile[kq + 2][nl], x3 = tile[kq + 3][nl];
    ushort4 h;
    h.x = f2bf(x0); h.y = f2bf(x1); h.z = f2bf(x2); h.w = f2bf(x3);
    *reinterpret_cast<ushort4*>(&Th[(size_t)(n0 + nl) * Kd + k0 + kq]) = h;
    if (LO) {
        ushort4 l;
        l.x = f2bf(x0 - bf2f(h.x)); l.y = f2bf(x1 - bf2f(h.y));
        l.z = f2bf(x2 - bf2f(h.z)); l.w = f2bf(x3 - bf2f(h.w));
        *reinterpret_cast<ushort4*>(&Tl[(size_t)(n0 + nl) * Kd + k0 + kq]) = l;
    }
}

// ---------------------------------------------------------------------------
// RMSNorm over D=1024 -> bf16 hi (+ optional lo). One block per token.
// ---------------------------------------------------------------------------
template <int LO>
__global__ __launch_bounds__(256) void rmsnorm_split_kernel(
    const float* __restrict__ x, const float* __restrict__ scale,
    u16* __restrict__ oh, u16* __restrict__ ol)
{
    const int row = blockIdx.x;
    const int tid = threadIdx.x;
    const float4 v = reinterpret_cast<const float4*>(x + (size_t)row * Dmod)[tid];
    float ss = v.x * v.x + v.y * v.y + v.z * v.z + v.w * v.w;
    #pragma unroll
    for (int off = 32; off; off >>= 1) ss += __shfl_xor(ss, off, 64);
    __shared__ float part[4];
    if ((tid & 63) == 0) part[tid >> 6] = ss;
    __syncthreads();
    const float tot = part[0] + part[1] + part[2] + part[3];
    const float rstd = rsqrtf(tot * (1.0f / Dmod) + EPSF);
    const float4 sc = reinterpret_cast<const float4*>(scale)[tid];
    float o0 = v.x * rstd * sc.x, o1 = v.y * rstd * sc.y;
    float o2 = v.z * rstd * sc.z, o3 = v.w * rstd * sc.w;
    ushort4 h;
    h.x = f2bf(o0); h.y = f2bf(o1); h.z = f2bf(o2); h.w = f2bf(o3);
    *reinterpret_cast<ushort4*>(&oh[(size_t)row * Dmod + tid * 4]) = h;
    if (LO) {
        ushort4 l;
        l.x = f2bf(o0 - bf2f(h.x)); l.y = f2bf(o1 - bf2f(h.y));
        l.z = f2bf(o2 - bf2f(h.z)); l.w = f2bf(o3 - bf2f(h.w));
        *reinterpret_cast<ushort4*>(&ol[(size_t)row * Dmod + tid * 4]) = l;
    }
}

// ---------------------------------------------------------------------------
// Split-bf16 MFMA GEMM, async DMA staging + bank-swizzled layout.
// 128x128 tile, BK=32, 4 waves (2x2 of 64x64).
// ---------------------------------------------------------------------------
template <int ASPLIT, int BSPLIT, int RES>
__global__ __launch_bounds__(256, 2) void mfma_gemm_kernel(
    const u16* __restrict__ Ah, const u16* __restrict__ Al,
    const u16* __restrict__ Bh, const u16* __restrict__ Bl,
    const float* __restrict__ res, float* __restrict__ C,
    int M, int N, int Kd)
{
    __shared__ u16 As_h[128 * 32];
    __shared__ u16 As_l[128 * 32];
    __shared__ u16 Bs_h[128 * 32];
    __shared__ u16 Bs_l[128 * 32];

    const int tid = threadIdx.x;
    const int lane = tid & 63, wave = tid >> 6;
    const int wm = (wave >> 1) * 64, wn = (wave & 1) * 64;
    const int m0 = blockIdx.y * 128, n0 = blockIdx.x * 128;
    const int fm = lane & 15, quad = lane >> 4;
    const int fsw = (fm >> 1) & 3;                 // fragment read swizzle
    const int fcol = ((quad ^ fsw) * 8);

    f32x4 acc[4][4];
    #pragma unroll
    for (int i = 0; i < 4; ++i)
        #pragma unroll
        for (int j = 0; j < 4; ++j) acc[i][j] = (f32x4){0.f, 0.f, 0.f, 0.f};

    const int lrow = lane >> 2;                    // 0..15
    const int lchunk = lane & 3;
    const int schunk = lchunk ^ ((lrow >> 1) & 3); // swizzled source chunk

    for (int k0 = 0; k0 < Kd; k0 += 32) {
        __syncthreads();   // previous tile consumed
        #pragma unroll
        for (int p = 0; p < 2; ++p) {
            const int row = wave * 32 + p * 16 + lrow;
            const size_t ga = (size_t)(m0 + row) * Kd + k0 + schunk * 8;
            const size_t gb = (size_t)(n0 + row) * Kd + k0 + schunk * 8;
            const int ls = row * 32 + lchunk * 8;
            async_copy16(&Ah[ga], &As_h[ls]);
            if (ASPLIT) async_copy16(&Al[ga], &As_l[ls]);
            async_copy16(&Bh[gb], &Bs_h[ls]);
            if (BSPLIT) async_copy16(&Bl[gb], &Bs_l[ls]);
        }
        __syncthreads();   // drains vmcnt -> tile visible

        bf16x8 ah[4], al[4], bh[4], bl[4];
        #pragma unroll
        for (int t = 0; t < 4; ++t) {
            const int ra = (wm + t * 16 + fm) * 32 + fcol;
            const int rb = (wn + t * 16 + fm) * 32 + fcol;
            ah[t] = *reinterpret_cast<const bf16x8*>(&As_h[ra]);
            bh[t] = *reinterpret_cast<const bf16x8*>(&Bs_h[rb]);
            if (ASPLIT) al[t] = *reinterpret_cast<const bf16x8*>(&As_l[ra]);
            if (BSPLIT) bl[t] = *reinterpret_cast<const bf16x8*>(&Bs_l[rb]);
        }
        #pragma unroll
        for (int mt = 0; mt < 4; ++mt)
            #pragma unroll
            for (int nt = 0; nt < 4; ++nt) {
                acc[mt][nt] = __builtin_amdgcn_mfma_f32_16x16x32_bf16(
                    ah[mt], bh[nt], acc[mt][nt], 0, 0, 0);
                if (BSPLIT)
                    acc[mt][nt] = __builtin_amdgcn_mfma_f32_16x16x32_bf16(
                        ah[mt], bl[nt], acc[mt][nt], 0, 0, 0);
                if (ASPLIT)
                    acc[mt][nt] = __builtin_amdgcn_mfma_f32_16x16x32_bf16(
                        al[mt], bh[nt], acc[mt][nt], 0, 0, 0);
            }
    }

    const int cr = (lane >> 4) * 4, cn = lane & 15;
    #pragma unroll
    for (int mt = 0; mt < 4; ++mt)
        #pragma unroll
        for (int nt = 0; nt < 4; ++nt)
            #pragma unroll
            for (int r = 0; r < 4; ++r) {
                const int gm = m0 + wm + mt * 16 + cr + r;
                const int gn = n0 + wn + nt * 16 + cn;
                float v = acc[mt][nt][r];
                if (RES) v += res[(size_t)gm * N + gn];
                C[(size_t)gm * N + gn] = v;
            }
}

// ---------------------------------------------------------------------------
// Fused gate/up MFMA GEMM + silu epilogue, v2:
// 128x64 block tile, 4 waves of 64x32 (mt=4, nt=2) -> acc = 64 AGPR/wave
// (2 waves/SIMD instead of 1), swizzled DMA staging (conflict-free reads).
// ---------------------------------------------------------------------------
__global__ __launch_bounds__(256, 2) void mfma_gateup_kernel(
    const u16* __restrict__ Ah, const u16* __restrict__ Al,
    const u16* __restrict__ Bg, const u16* __restrict__ Bu,
    u16* __restrict__ FF, int M, int N, int Kd)
{
    __shared__ u16 As_h[128 * 32];
    __shared__ u16 As_l[128 * 32];
    __shared__ u16 Gs[64 * 32];
    __shared__ u16 Us[64 * 32];

    const int tid = threadIdx.x;
    const int lane = tid & 63, wave = tid >> 6;
    const int wm = (wave >> 1) * 64, wn = (wave & 1) * 32;
    const int m0 = blockIdx.y * 128, n0 = blockIdx.x * 64;
    const int fm = lane & 15, quad = lane >> 4;
    const int fsw = (fm >> 1) & 3;
    const int fcol = ((quad ^ fsw) * 8);

    f32x4 accg[4][2], accu[4][2];
    #pragma unroll
    for (int i = 0; i < 4; ++i)
        #pragma unroll
        for (int j = 0; j < 2; ++j) {
            accg[i][j] = (f32x4){0.f, 0.f, 0.f, 0.f};
            accu[i][j] = (f32x4){0.f, 0.f, 0.f, 0.f};
        }

    const int lrow = lane >> 2;
    const int lchunk = lane & 3;
    const int schunk = lchunk ^ ((lrow >> 1) & 3);

    for (int k0 = 0; k0 < Kd; k0 += 32) {
        __syncthreads();
        #pragma unroll
        for (int p = 0; p < 2; ++p) {
            const int row = p * 64 + wave * 16 + lrow;   // A rows 0..127
            const size_t ga = (size_t)(m0 + row) * Kd + k0 + schunk * 8;
            const int ls = row * 32 + lchunk * 8;
            async_copy16(&Ah[ga], &As_h[ls]);
            async_copy16(&Al[ga], &As_l[ls]);
        }
        {
            const int row = wave * 16 + lrow;            // B rows 0..63
            const size_t gb = (size_t)(n0 + row) * Kd + k0 + schunk * 8;
            const int ls = row * 32 + lchunk * 8;
            async_copy16(&Bg[gb], &Gs[ls]);
            async_copy16(&Bu[gb], &Us[ls]);
        }
        __syncthreads();

        bf16x8 a_h[4], a_l[4], g_f[2], u_f[2];
        #pragma unroll
        for (int t = 0; t < 4; ++t) {
            const int ra = (wm + t * 16 + fm) * 32 + fcol;
            a_h[t] = *reinterpret_cast<const bf16x8*>(&As_h[ra]);
            a_l[t] = *reinterpret_cast<const bf16x8*>(&As_l[ra]);
        }
        #pragma unroll
        for (int j = 0; j < 2; ++j) {
            const int rb = (wn + j * 16 + fm) * 32 + fcol;
            g_f[j] = *reinterpret_cast<const bf16x8*>(&Gs[rb]);
            u_f[j] = *reinterpret_cast<const bf16x8*>(&Us[rb]);
        }
        #pragma unroll
        for (int mt = 0; mt < 4; ++mt)
            #pragma unroll
            for (int nt = 0; nt < 2; ++nt) {
                accg[mt][nt] = __builtin_amdgcn_mfma_f32_16x16x32_bf16(
                    a_h[mt], g_f[nt], accg[mt][nt], 0, 0, 0);
                accg[mt][nt] = __builtin_amdgcn_mfma_f32_16x16x32_bf16(
                    a_l[mt], g_f[nt], accg[mt][nt], 0, 0, 0);
                accu[mt][nt] = __builtin_amdgcn_mfma_f32_16x16x32_bf16(
                    a_h[mt], u_f[nt], accu[mt][nt], 0, 0, 0);
                accu[mt][nt] = __builtin_amdgcn_mfma_f32_16x16x32_bf16(
                    a_l[mt], u_f[nt], accu[mt][nt], 0, 0, 0);
            }
    }

    const int cr = (lane >> 4) * 4, cn = lane & 15;
    #pragma unroll
    for (int mt = 0; mt < 4; ++mt)
        #pragma unroll
        for (int nt = 0; nt < 2; ++nt)
            #pragma unroll
            for (int r = 0; r < 4; ++r) {
                const int gm = m0 + wm + mt * 16 + cr + r;
                const int gn = n0 + wn + nt * 16 + cn;
                const float g = accg[mt][nt][r];
                const float ff = (g / (1.0f + __expf(-g))) * accu[mt][nt][r];
                FF[(size_t)gm * N + gn] = f2bf(ff);
            }
}

// ---------------------------------------------------------------------------
// Per-head RMSNorm + RoPE, fp32 QKV (stride 1536) -> bf16 hi/lo (scale folded).
// ---------------------------------------------------------------------------
__global__ __launch_bounds__(256) void qkrope_bf16_kernel(
    const float* __restrict__ src, const float* __restrict__ nsc,
    const float* __restrict__ sinp, const float* __restrict__ cosp,
    u16* __restrict__ outh, u16* __restrict__ outl,
    int NH, float oscale)
{
    const int lane = threadIdx.x & 63;
    const int w = threadIdx.x >> 6;
    const int head = blockIdx.x * 4 + w;
    const int bt = head / NH;
    const int h = head % NH;

    const float v = src[(size_t)bt * QKVN + h * 64 + lane];
    float ss = v * v;
    #pragma unroll
    for (int off = 32; off; off >>= 1) ss += __shfl_xor(ss, off, 64);
    const float rstd = rsqrtf(ss * (1.0f / 64.0f) + EPSF);
    const float nv = v * rstd * nsc[lane];

    const float p = __shfl_xor(nv, 32, 64);
    const float s = sinp[(size_t)bt * 32 + (lane & 31)];
    const float c = cosp[(size_t)bt * 32 + (lane & 31)];
    const float o = ((lane < 32) ? (nv * c - p * s) : (nv * c + p * s)) * oscale;

    const size_t oi = (size_t)bt * (NH * 64) + h * 64 + lane;
    const u16 hi = f2bf(o);
    outh[oi] = hi;
    outl[oi] = f2bf(o - bf2f(hi));
}

// ---------------------------------------------------------------------------
// V transpose + bf16 split (unchanged).
// ---------------------------------------------------------------------------
__global__ __launch_bounds__(256) void vtrans_kernel(
    const float* __restrict__ QKV, u16* __restrict__ Vth, u16* __restrict__ Vtl)
{
    __shared__ float tile[64][65];
    const int t0 = blockIdx.x * 64;
    const int bg = blockIdx.y;
    const int b = bg >> 2, g = bg & 3;
    const int tid = threadIdx.x;

    const int tl = tid >> 4, dq = (tid & 15) * 4;
    #pragma unroll
    for (int p = 0; p < 4; ++p) {
        const int t = tl + p * 16;
        const float4 v = *reinterpret_cast<const float4*>(
            &QKV[(size_t)(b * Tseq + t0 + t) * QKVN + 1280 + g * 64 + dq]);
        tile[t][dq + 0] = v.x; tile[t][dq + 1] = v.y;
        tile[t][dq + 2] = v.z; tile[t][dq + 3] = v.w;
    }
    __syncthreads();

    const int d = tid >> 2, tq = (tid & 3) * 16;
    u16 hv[16], lv[16];
    #pragma unroll
    for (int i = 0; i < 16; ++i) {
        const float v = tile[tq + i][d];
        hv[i] = f2bf(v);
        lv[i] = f2bf(v - bf2f(hv[i]));
    }
    const size_t oi = ((size_t)(bg * 64 + d)) * Tseq + t0 + tq;
    *reinterpret_cast<uint4*>(&Vth[oi])     = *reinterpret_cast<uint4*>(&hv[0]);
    *reinterpret_cast<uint4*>(&Vth[oi + 8]) = *reinterpret_cast<uint4*>(&hv[8]);
    *reinterpret_cast<uint4*>(&Vtl[oi])     = *reinterpret_cast<uint4*>(&lv[0]);
    *reinterpret_cast<uint4*>(&Vtl[oi + 8]) = *reinterpret_cast<uint4*>(&lv[8]);
}

// ---------------------------------------------------------------------------
// MFMA flash attention v3 (unchanged).
// ---------------------------------------------------------------------------
__global__ __launch_bounds__(256) void attn_mfma_kernel(
    const u16* __restrict__ Qh, const u16* __restrict__ Ql,
    const u16* __restrict__ Kh, const u16* __restrict__ Kl,
    const u16* __restrict__ Vth, const u16* __restrict__ Vtl,
    u16* __restrict__ AOh, u16* __restrict__ AOl)
{
    __shared__ u16 KsH[64 * 72];   // [s][k], stride 72 elems (144B)
    __shared__ u16 KsL[64 * 72];
    __shared__ u16 VsH[64 * 72];   // [d][t]
    __shared__ u16 VsL[64 * 72];
    __shared__ u16 Ps[4][16 * 72]; // wave-private P tiles

    const int tid = threadIdx.x;
    const int wave = tid >> 6, lane = tid & 63;
    const int l15 = lane & 15, quad = lane >> 4;

    const int bg = blockIdx.x & 7;             // (b,g): XCD/L2 locality
    const int b = bg >> 2, g = bg & 3;
    const int win = 127 - (blockIdx.x >> 3);   // heavy-first
    const int t0 = win * 16;
    const int h = g * 4 + wave;                // this wave's head

    bf16x8 qh[2], ql[2];
    {
        const size_t qrow = (size_t)(b * Tseq + t0 + l15) * 1024 + h * 64;
        #pragma unroll
        for (int ks = 0; ks < 2; ++ks) {
            qh[ks] = *reinterpret_cast<const bf16x8*>(&Qh[qrow + ks * 32 + quad * 8]);
            ql[ks] = *reinterpret_cast<const bf16x8*>(&Ql[qrow + ks * 32 + quad * 8]);
        }
    }

    const int srow = tid >> 2;
    const int scol = (tid & 3) * 16;
    const size_t kgb = (size_t)(b * Tseq) * 256 + g * 64 + scol;
    const size_t vgb = (size_t)(bg * 64 + srow) * Tseq + scol;

    const int nit = t0 / 64 + 1;

    uint4 ck0, ck1, cl0, cl1, cv0, cv1, cw0, cw1;
    {
        const size_t ka = kgb + (size_t)srow * 256;
        ck0 = *reinterpret_cast<const uint4*>(&Kh[ka]);
        ck1 = *reinterpret_cast<const uint4*>(&Kh[ka + 8]);
        cl0 = *reinterpret_cast<const uint4*>(&Kl[ka]);
        cl1 = *reinterpret_cast<const uint4*>(&Kl[ka + 8]);
        cv0 = *reinterpret_cast<const uint4*>(&Vth[vgb]);
        cv1 = *reinterpret_cast<const uint4*>(&Vth[vgb + 8]);
        cw0 = *reinterpret_cast<const uint4*>(&Vtl[vgb]);
        cw1 = *reinterpret_cast<const uint4*>(&Vtl[vgb + 8]);
    }

    f32x4 oacc[4];
    #pragma unroll
    for (int nt = 0; nt < 4; ++nt) oacc[nt] = (f32x4){0.f, 0.f, 0.f, 0.f};
    float m_r[4], l_r[4];
    #pragma unroll
    for (int r = 0; r < 4; ++r) { m_r[r] = -1e30f; l_r[r] = 0.0f; }

    u16* psw = &Ps[wave][0];
    const int lb = srow * 72 + scol;

    for (int it = 0; it < nit; ++it) {
        const int s0 = it * 64;
        const bool diag = (it == nit - 1);

        __syncthreads();
        *reinterpret_cast<uint4*>(&KsH[lb])     = ck0;
        *reinterpret_cast<uint4*>(&KsH[lb + 8]) = ck1;
        *reinterpret_cast<uint4*>(&KsL[lb])     = cl0;
        *reinterpret_cast<uint4*>(&KsL[lb + 8]) = cl1;
        *reinterpret_cast<uint4*>(&VsH[lb])     = cv0;
        *reinterpret_cast<uint4*>(&VsH[lb + 8]) = cv1;
        *reinterpret_cast<uint4*>(&VsL[lb])     = cw0;
        *reinterpret_cast<uint4*>(&VsL[lb + 8]) = cw1;
        if (it + 1 < nit) {
            const size_t ka = kgb + (size_t)(s0 + 64 + srow) * 256;
            ck0 = *reinterpret_cast<const uint4*>(&Kh[ka]);
            ck1 = *reinterpret_cast<const uint4*>(&Kh[ka + 8]);
            cl0 = *reinterpret_cast<const uint4*>(&Kl[ka]);
            cl1 = *reinterpret_cast<const uint4*>(&Kl[ka + 8]);
            const size_t va = vgb + s0 + 64;
            cv0 = *reinterpret_cast<const uint4*>(&Vth[va]);
            cv1 = *reinterpret_cast<const uint4*>(&Vth[va + 8]);
            cw0 = *reinterpret_cast<const uint4*>(&Vtl[va]);
            cw1 = *reinterpret_cast<const uint4*>(&Vtl[va + 8]);
        }
        __syncthreads();

        f32x4 sacc[4];
        #pragma unroll
        for (int nt = 0; nt < 4; ++nt) sacc[nt] = (f32x4){0.f, 0.f, 0.f, 0.f};

        #pragma unroll
        for (int ks = 0; ks < 2; ++ks) {
            bf16x8 kfh[4], kfl[4];
            #pragma unroll
            for (int nt = 0; nt < 4; ++nt) {
                const int a = (nt * 16 + l15) * 72 + ks * 32 + quad * 8;
                kfh[nt] = *reinterpret_cast<const bf16x8*>(&KsH[a]);
                kfl[nt] = *reinterpret_cast<const bf16x8*>(&KsL[a]);
            }
            #pragma unroll
            for (int nt = 0; nt < 4; ++nt) {
                sacc[nt] = __builtin_amdgcn_mfma_f32_16x16x32_bf16(qh[ks], kfh[nt], sacc[nt], 0, 0, 0);
                sacc[nt] = __builtin_amdgcn_mfma_f32_16x16x32_bf16(ql[ks], kfh[nt], sacc[nt], 0, 0, 0);
                sacc[nt] = __builtin_amdgcn_mfma_f32_16x16x32_bf16(qh[ks], kfl[nt], sacc[nt], 0, 0, 0);
            }
        }

        if (diag) {
            #pragma unroll
            for (int nt = 0; nt < 4; ++nt) {
                const int sg = s0 + nt * 16 + l15;
                #pragma unroll
                for (int r = 0; r < 4; ++r)
                    if (sg > t0 + quad * 4 + r) sacc[nt][r] = -1e30f;
            }
        }

        #pragma unroll
        for (int r = 0; r < 4; ++r) {
            float mx = fmaxf(fmaxf(sacc[0][r], sacc[1][r]),
                             fmaxf(sacc[2][r], sacc[3][r]));
            #pragma unroll
            for (int off = 1; off < 16; off <<= 1)
                mx = fmaxf(mx, __shfl_xor(mx, off, 16));
            const float mnew = fmaxf(m_r[r], mx);
            const float alpha = __expf(m_r[r] - mnew);
            m_r[r] = mnew;

            float rs = 0.0f;
            #pragma unroll
            for (int nt = 0; nt < 4; ++nt) {
                const float p = __expf(sacc[nt][r] - mnew);
                sacc[nt][r] = p;
                rs += p;
            }
            #pragma unroll
            for (int off = 1; off < 16; off <<= 1)
                rs += __shfl_xor(rs, off, 16);
            l_r[r] = l_r[r] * alpha + rs;
            #pragma unroll
            for (int nt = 0; nt < 4; ++nt) oacc[nt][r] *= alpha;
            #pragma unroll
            for (int nt = 0; nt < 4; ++nt)
                psw[(quad * 4 + r) * 72 + nt * 16 + l15] = f2bf(sacc[nt][r]);
        }

        #pragma unroll
        for (int ks = 0; ks < 2; ++ks) {
            const bf16x8 pa = *reinterpret_cast<const bf16x8*>(
                &psw[l15 * 72 + ks * 32 + quad * 8]);
            bf16x8 vfh[4], vfl[4];
            #pragma unroll
            for (int nt = 0; nt < 4; ++nt) {
                const int a = (nt * 16 + l15) * 72 + ks * 32 + quad * 8;
                vfh[nt] = *reinterpret_cast<const bf16x8*>(&VsH[a]);
                vfl[nt] = *reinterpret_cast<const bf16x8*>(&VsL[a]);
            }
            #pragma unroll
            for (int nt = 0; nt < 4; ++nt) {
                oacc[nt] = __builtin_amdgcn_mfma_f32_16x16x32_bf16(pa, vfh[nt], oacc[nt], 0, 0, 0);
                oacc[nt] = __builtin_amdgcn_mfma_f32_16x16x32_bf16(pa, vfl[nt], oacc[nt], 0, 0, 0);
            }
        }
    }

    #pragma unroll
    for (int r = 0; r < 4; ++r) {
        const float inv = 1.0f / l_r[r];
        const size_t orow = (size_t)(b * Tseq + t0 + quad * 4 + r) * 1024 + h * 64;
        #pragma unroll
        for (int nt = 0; nt < 4; ++nt) {
            const float o = oacc[nt][r] * inv;
            const u16 hi = f2bf(o);
            AOh[orow + nt * 16 + l15] = hi;
            AOl[orow + nt * 16 + l15] = f2bf(o - bf2f(hi));
        }
    }
}

// ---------------------------------------------------------------------------
// Host launcher
// ---------------------------------------------------------------------------
extern "C" void kernel_launch(void* const* d_in, const int* in_sizes, int n_in,
                              void* d_out, int out_size, void* d_ws,
                              size_t ws_size, hipStream_t stream)
{
    const float* hidden = (const float*)d_in[0];
    const float* sinp   = (const float*)d_in[1];
    const float* cosp   = (const float*)d_in[2];
    // d_in[3] = mask — causal, handled analytically
    const float* ln1    = (const float*)d_in[4];
    const float* ln2    = (const float*)d_in[5];
    const float* qn     = (const float*)d_in[6];
    const float* kn     = (const float*)d_in[7];
    const float* q_w    = (const float*)d_in[8];
    const float* k_w    = (const float*)d_in[9];
    const float* v_w    = (const float*)d_in[10];
    const float* o_w    = (const float*)d_in[11];
    const float* gate_w = (const float*)d_in[12];
    const float* up_w   = (const float*)d_in[13];
    const float* down_w = (const float*)d_in[14];
    float* out = (float*)d_out;

    // ---- workspace layout (116.4 MB, with aliasing) ----
    char* base = (char*)d_ws;
    u16*   OTh  = (u16*)(base);                       //  2,097,152
    u16*   OTl  = (u16*)(base + 2097152);             //  2,097,152
    u16*   GTh  = (u16*)(base + 4194304);             //  8,388,608
    u16*   UTh  = (u16*)(base + 12582912);            //  8,388,608
    u16*   DTh  = (u16*)(base + 20971520);            //  8,388,608
    float* QKV  = (float*)(base + 29360128);          // 25,165,824 fp32
    u16*   Qbh  = (u16*)(base + 54525952);            //  8,388,608
    u16*   Qbl  = (u16*)(base + 62914560);            //  8,388,608
    u16*   FFh  = (u16*)(base + 71303168);            // 33,554,432
    u16*   QKVT = (u16*)(base + 104857600);           //  3,145,728
    u16*   Xh   = (u16*)(base + 108003328);           //  8,388,608  (end 116,391,936)

    // aliases (lifetime-checked):
    u16*   Kbh  = QKVT;                                // post-QKV-gemm
    u16*   Kbl  = Kbh + (size_t)4096 * 256;
    u16*   Vth  = Kbl + (size_t)4096 * 256;
    u16*   Vtl  = Vth + (size_t)8 * 64 * 2048;
    u16*   AOh  = (u16*)QKV;                           // over QKV (dead post-vtrans)
    u16*   AOl  = AOh + (size_t)4096 * 1024;
    u16*   Yl   = (u16*)(base + 29360128 + 16777216);  // QKV tail
    float* H2   = (float*)Qbh;                         // over Qh/Ql (dead post-attn)
    u16*   Yh   = Kbh;                                 // over K/V bf16 (dead post-attn)

    // 0. weight prep
    wprep_kernel<0><<<dim3(32, 32), 256, 0, stream>>>(q_w, QKVT, nullptr, 1024, 1024);
    wprep_kernel<0><<<dim3(8, 32), 256, 0, stream>>>(k_w, QKVT + (size_t)1024 * 1024, nullptr, 1024, 256);
    wprep_kernel<0><<<dim3(8, 32), 256, 0, stream>>>(v_w, QKVT + (size_t)1280 * 1024, nullptr, 1024, 256);
    wprep_kernel<1><<<dim3(32, 32), 256, 0, stream>>>(o_w, OTh, OTl, 1024, 1024);
    wprep_kernel<0><<<dim3(128, 32), 256, 0, stream>>>(gate_w, GTh, nullptr, 1024, 4096);
    wprep_kernel<0><<<dim3(128, 32), 256, 0, stream>>>(up_w, UTh, nullptr, 1024, 4096);
    wprep_kernel<0><<<dim3(32, 128), 256, 0, stream>>>(down_w, DTh, nullptr, 4096, 1024);

    // 1. x = rmsnorm(hidden, ln1) -> bf16
    rmsnorm_split_kernel<0><<<Mrows, 256, 0, stream>>>(hidden, ln1, Xh, nullptr);

    // 2. fused qkv projection -> QKV fp32
    mfma_gemm_kernel<0, 0, 0><<<dim3(QKVN / 128, Mrows / 128), 256, 0, stream>>>(
        Xh, nullptr, QKVT, nullptr, nullptr, QKV, Mrows, QKVN, 1024);

    // 3. qk-norm + rope -> bf16 hi/lo (Q scaled by K^-0.5); V transpose+split
    qkrope_bf16_kernel<<<Mrows * Hh / 4, 256, 0, stream>>>(
        QKV, qn, sinp, cosp, Qbh, Qbl, Hh, 0.125f);
    qkrope_bf16_kernel<<<Mrows * Gg / 4, 256, 0, stream>>>(
        QKV + 1024, kn, sinp, cosp, Kbh, Kbl, Gg, 1.0f);
    vtrans_kernel<<<dim3(Tseq / 64, Bsz * Gg), 256, 0, stream>>>(QKV, Vth, Vtl);

    // 4. MFMA flash attention v3 -> AO bf16 hi/lo
    attn_mfma_kernel<<<Bsz * Gg * (Tseq / 16), 256, 0, stream>>>(
        Qbh, Qbl, Kbh, Kbl, Vth, Vtl, AOh, AOl);

    // 5. hidden2 = hidden + attn @ o_w  (split x split)
    mfma_gemm_kernel<1, 1, 1><<<dim3(8, 32), 256, 0, stream>>>(
        AOh, AOl, OTh, OTl, hidden, H2, Mrows, Dmod, 1024);

    // 6. y = rmsnorm(hidden2, ln2) -> bf16 hi/lo
    rmsnorm_split_kernel<1><<<Mrows, 256, 0, stream>>>(H2, ln2, Yh, Yl);

    // 7. ff = silu(y@gate_w) * (y@up_w) -> FF bf16  (128x64 tiles)
    mfma_gateup_kernel<<<dim3(Ff / 64, Mrows / 128), 256, 0, stream>>>(
        Yh, Yl, GTh, UTh, FFh, Mrows, Ff, 1024);

    // 8. out = hidden2 + ff @ down_w
    mfma_gemm_kernel<0, 0, 1><<<dim3(8, 32), 256, 0, stream>>>(
        FFh, nullptr, DTh, nullptr, H2, out, Mrows, Dmod, 4096);
}

// Round 8
// 543.841 us; speedup vs baseline: 6.4701x; 1.0328x over previous
//
#include <hip/hip_runtime.h>
#include <hip/hip_bf16.h>

// Problem constants: B=2, T=2048, D=1024, H=16, G=4, K=64, F=4096
#define EPSF 1e-6f
constexpr int Bsz  = 2;
constexpr int Tseq = 2048;
constexpr int Dmod = 1024;
constexpr int Hh   = 16;
constexpr int Gg   = 4;
constexpr int Ff   = 4096;
constexpr int Mrows = Bsz * Tseq;          // 4096 tokens

typedef __attribute__((ext_vector_type(8))) short bf16x8;   // 8 bf16 (4 VGPRs)
typedef __attribute__((ext_vector_type(4))) float f32x4;
typedef unsigned short u16;

// RNE fp32 -> bf16 (bit pattern as u16)
__device__ inline u16 f2bf(float x) {
    union { float f; unsigned u; } v; v.f = x;
    unsigned r = v.u + 0x7fff + ((v.u >> 16) & 1);
    return (u16)(r >> 16);
}
__device__ inline float bf2f(u16 h) {
    union { unsigned u; float f; } v; v.u = ((unsigned)h) << 16; return v.f;
}

// Async global->LDS DMA, 16 B per lane (wave-uniform base + lane*16).
__device__ __forceinline__ void async_copy16(const u16* g, u16* l) {
    __builtin_amdgcn_global_load_lds(
        (const __attribute__((address_space(1))) void*)g,
        (__attribute__((address_space(3))) void*)l, 16, 0, 0);
}

// Bank-swizzle: LDS tiles [row][32] bf16 (64 B rows). Logical k-chunk q of row
// R stored at chunk q ^ ((R>>1)&3); staging fetches global chunk
// (lane&3)^((row>>1)&3) into linear dest lane*16; reads XOR the same term.
// -> 2-way (free) instead of 8-way conflicts (verified r7: conflicts = 0).

// ---------------------------------------------------------------------------
// Weight prep: W[Kd][N] fp32 -> Th[N][Kd] bf16 (hi) and optional Tl (lo).
// ---------------------------------------------------------------------------
template <int LO>
__global__ __launch_bounds__(256) void wprep_kernel(
    const float* __restrict__ W, u16* __restrict__ Th, u16* __restrict__ Tl,
    int Kd, int N)
{
    __shared__ float tile[32][33];
    const int n0 = blockIdx.x * 32, k0 = blockIdx.y * 32;
    const int r = threadIdx.x >> 3, c4 = (threadIdx.x & 7) * 4;
    const float4 v = *reinterpret_cast<const float4*>(&W[(size_t)(k0 + r) * N + n0 + c4]);
    tile[r][c4 + 0] = v.x; tile[r][c4 + 1] = v.y;
    tile[r][c4 + 2] = v.z; tile[r][c4 + 3] = v.w;
    __syncthreads();
    const int nl = threadIdx.x >> 3, kq = (threadIdx.x & 7) * 4;
    float x0 = tile[kq + 0][nl], x1 = tile[kq + 1][nl];
    float x2 = tile[kq + 2][nl], x3 = tile[kq + 3][nl];
    ushort4 h;
    h.x = f2bf(x0); h.y = f2bf(x1); h.z = f2bf(x2); h.w = f2bf(x3);
    *reinterpret_cast<ushort4*>(&Th[(size_t)(n0 + nl) * Kd + k0 + kq]) = h;
    if (LO) {
        ushort4 l;
        l.x = f2bf(x0 - bf2f(h.x)); l.y = f2bf(x1 - bf2f(h.y));
        l.z = f2bf(x2 - bf2f(h.z)); l.w = f2bf(x3 - bf2f(h.w));
        *reinterpret_cast<ushort4*>(&Tl[(size_t)(n0 + nl) * Kd + k0 + kq]) = l;
    }
}

// Combined q/k/v weight prep into QKVT [1536][1024]. Grid (48, 32).
__global__ __launch_bounds__(256) void wprep_qkv_kernel(
    const float* __restrict__ q_w, const float* __restrict__ k_w,
    const float* __restrict__ v_w, u16* __restrict__ QKVT)
{
    const int nx = blockIdx.x;
    const float* W; int N, n0s, drow;
    if (nx < 32)      { W = q_w; N = 1024; n0s = nx * 32;        drow = nx * 32; }
    else if (nx < 40) { W = k_w; N = 256;  n0s = (nx - 32) * 32; drow = 1024 + (nx - 32) * 32; }
    else              { W = v_w; N = 256;  n0s = (nx - 40) * 32; drow = 1280 + (nx - 40) * 32; }
    const int k0 = blockIdx.y * 32;
    __shared__ float tile[32][33];
    const int r = threadIdx.x >> 3, c4 = (threadIdx.x & 7) * 4;
    const float4 v = *reinterpret_cast<const float4*>(&W[(size_t)(k0 + r) * N + n0s + c4]);
    tile[r][c4 + 0] = v.x; tile[r][c4 + 1] = v.y;
    tile[r][c4 + 2] = v.z; tile[r][c4 + 3] = v.w;
    __syncthreads();
    const int nl = threadIdx.x >> 3, kq = (threadIdx.x & 7) * 4;
    ushort4 h;
    h.x = f2bf(tile[kq + 0][nl]); h.y = f2bf(tile[kq + 1][nl]);
    h.z = f2bf(tile[kq + 2][nl]); h.w = f2bf(tile[kq + 3][nl]);
    *reinterpret_cast<ushort4*>(&QKVT[(size_t)(drow + nl) * 1024 + k0 + kq]) = h;
}

// gate+up prep in one launch. Grid (128, 32, 2).
__global__ __launch_bounds__(256) void wprep_gu_kernel(
    const float* __restrict__ gate_w, const float* __restrict__ up_w,
    u16* __restrict__ GTh, u16* __restrict__ UTh)
{
    const float* W = blockIdx.z ? up_w : gate_w;
    u16* T = blockIdx.z ? UTh : GTh;
    const int n0 = blockIdx.x * 32, k0 = blockIdx.y * 32;
    __shared__ float tile[32][33];
    const int r = threadIdx.x >> 3, c4 = (threadIdx.x & 7) * 4;
    const float4 v = *reinterpret_cast<const float4*>(&W[(size_t)(k0 + r) * 4096 + n0 + c4]);
    tile[r][c4 + 0] = v.x; tile[r][c4 + 1] = v.y;
    tile[r][c4 + 2] = v.z; tile[r][c4 + 3] = v.w;
    __syncthreads();
    const int nl = threadIdx.x >> 3, kq = (threadIdx.x & 7) * 4;
    ushort4 h;
    h.x = f2bf(tile[kq + 0][nl]); h.y = f2bf(tile[kq + 1][nl]);
    h.z = f2bf(tile[kq + 2][nl]); h.w = f2bf(tile[kq + 3][nl]);
    *reinterpret_cast<ushort4*>(&T[(size_t)(n0 + nl) * 1024 + k0 + kq]) = h;
}

// ---------------------------------------------------------------------------
// RMSNorm over D=1024 -> bf16 hi (+ optional lo). One block per token.
// ---------------------------------------------------------------------------
template <int LO>
__global__ __launch_bounds__(256) void rmsnorm_split_kernel(
    const float* __restrict__ x, const float* __restrict__ scale,
    u16* __restrict__ oh, u16* __restrict__ ol)
{
    const int row = blockIdx.x;
    const int tid = threadIdx.x;
    const float4 v = reinterpret_cast<const float4*>(x + (size_t)row * Dmod)[tid];
    float ss = v.x * v.x + v.y * v.y + v.z * v.z + v.w * v.w;
    #pragma unroll
    for (int off = 32; off; off >>= 1) ss += __shfl_xor(ss, off, 64);
    __shared__ float part[4];
    if ((tid & 63) == 0) part[tid >> 6] = ss;
    __syncthreads();
    const float tot = part[0] + part[1] + part[2] + part[3];
    const float rstd = rsqrtf(tot * (1.0f / Dmod) + EPSF);
    const float4 sc = reinterpret_cast<const float4*>(scale)[tid];
    float o0 = v.x * rstd * sc.x, o1 = v.y * rstd * sc.y;
    float o2 = v.z * rstd * sc.z, o3 = v.w * rstd * sc.w;
    ushort4 h;
    h.x = f2bf(o0); h.y = f2bf(o1); h.z = f2bf(o2); h.w = f2bf(o3);
    *reinterpret_cast<ushort4*>(&oh[(size_t)row * Dmod + tid * 4]) = h;
    if (LO) {
        ushort4 l;
        l.x = f2bf(o0 - bf2f(h.x)); l.y = f2bf(o1 - bf2f(h.y));
        l.z = f2bf(o2 - bf2f(h.z)); l.w = f2bf(o3 - bf2f(h.w));
        *reinterpret_cast<ushort4*>(&ol[(size_t)row * Dmod + tid * 4]) = l;
    }
}

// ---------------------------------------------------------------------------
// Split-bf16 MFMA GEMM, async DMA + swizzle (unchanged from r7).
// ---------------------------------------------------------------------------
template <int ASPLIT, int BSPLIT, int RES>
__global__ __launch_bounds__(256, 2) void mfma_gemm_kernel(
    const u16* __restrict__ Ah, const u16* __restrict__ Al,
    const u16* __restrict__ Bh, const u16* __restrict__ Bl,
    const float* __restrict__ res, float* __restrict__ C,
    int M, int N, int Kd)
{
    __shared__ u16 As_h[128 * 32];
    __shared__ u16 As_l[128 * 32];
    __shared__ u16 Bs_h[128 * 32];
    __shared__ u16 Bs_l[128 * 32];

    const int tid = threadIdx.x;
    const int lane = tid & 63, wave = tid >> 6;
    const int wm = (wave >> 1) * 64, wn = (wave & 1) * 64;
    const int m0 = blockIdx.y * 128, n0 = blockIdx.x * 128;
    const int fm = lane & 15, quad = lane >> 4;
    const int fsw = (fm >> 1) & 3;
    const int fcol = ((quad ^ fsw) * 8);

    f32x4 acc[4][4];
    #pragma unroll
    for (int i = 0; i < 4; ++i)
        #pragma unroll
        for (int j = 0; j < 4; ++j) acc[i][j] = (f32x4){0.f, 0.f, 0.f, 0.f};

    const int lrow = lane >> 2;
    const int lchunk = lane & 3;
    const int schunk = lchunk ^ ((lrow >> 1) & 3);

    for (int k0 = 0; k0 < Kd; k0 += 32) {
        __syncthreads();
        #pragma unroll
        for (int p = 0; p < 2; ++p) {
            const int row = wave * 32 + p * 16 + lrow;
            const size_t ga = (size_t)(m0 + row) * Kd + k0 + schunk * 8;
            const size_t gb = (size_t)(n0 + row) * Kd + k0 + schunk * 8;
            const int ls = row * 32 + lchunk * 8;
            async_copy16(&Ah[ga], &As_h[ls]);
            if (ASPLIT) async_copy16(&Al[ga], &As_l[ls]);
            async_copy16(&Bh[gb], &Bs_h[ls]);
            if (BSPLIT) async_copy16(&Bl[gb], &Bs_l[ls]);
        }
        __syncthreads();

        bf16x8 ah[4], al[4], bh[4], bl[4];
        #pragma unroll
        for (int t = 0; t < 4; ++t) {
            const int ra = (wm + t * 16 + fm) * 32 + fcol;
            const int rb = (wn + t * 16 + fm) * 32 + fcol;
            ah[t] = *reinterpret_cast<const bf16x8*>(&As_h[ra]);
            bh[t] = *reinterpret_cast<const bf16x8*>(&Bs_h[rb]);
            if (ASPLIT) al[t] = *reinterpret_cast<const bf16x8*>(&As_l[ra]);
            if (BSPLIT) bl[t] = *reinterpret_cast<const bf16x8*>(&Bs_l[rb]);
        }
        #pragma unroll
        for (int mt = 0; mt < 4; ++mt)
            #pragma unroll
            for (int nt = 0; nt < 4; ++nt) {
                acc[mt][nt] = __builtin_amdgcn_mfma_f32_16x16x32_bf16(
                    ah[mt], bh[nt], acc[mt][nt], 0, 0, 0);
                if (BSPLIT)
                    acc[mt][nt] = __builtin_amdgcn_mfma_f32_16x16x32_bf16(
                        ah[mt], bl[nt], acc[mt][nt], 0, 0, 0);
                if (ASPLIT)
                    acc[mt][nt] = __builtin_amdgcn_mfma_f32_16x16x32_bf16(
                        al[mt], bh[nt], acc[mt][nt], 0, 0, 0);
            }
    }

    const int cr = (lane >> 4) * 4, cn = lane & 15;
    #pragma unroll
    for (int mt = 0; mt < 4; ++mt)
        #pragma unroll
        for (int nt = 0; nt < 4; ++nt)
            #pragma unroll
            for (int r = 0; r < 4; ++r) {
                const int gm = m0 + wm + mt * 16 + cr + r;
                const int gn = n0 + wn + nt * 16 + cn;
                float v = acc[mt][nt][r];
                if (RES) v += res[(size_t)gm * N + gn];
                C[(size_t)gm * N + gn] = v;
            }
}

// ---------------------------------------------------------------------------
// Fused QKV GEMM + qk-norm + RoPE + bf16 split epilogue.
// C cols: [0,1024) Q heads, [1024,1280) K groups, [1280,1536) V groups.
// Each wave's 64-col span = exactly one head/group; a C-row's 64 values live
// in the 16 lanes of one quad (4 regs) -> RMS = width-16 shuffle reduce,
// RoPE partner (col+-32) = reg nt^2 in the SAME lane. Numerically identical
// to the previous separate qkrope pass (same fp32 acc values).
// ---------------------------------------------------------------------------
__global__ __launch_bounds__(256, 2) void qkv_fused_kernel(
    const u16* __restrict__ Ah, const u16* __restrict__ Bh,
    const float* __restrict__ qn, const float* __restrict__ kn,
    const float* __restrict__ sinp, const float* __restrict__ cosp,
    u16* __restrict__ Qbh, u16* __restrict__ Qbl,
    u16* __restrict__ Kbh, u16* __restrict__ Kbl,
    u16* __restrict__ Vbh, u16* __restrict__ Vbl)
{
    __shared__ u16 As_h[128 * 32];
    __shared__ u16 Bs_h[128 * 32];

    const int Kd = 1024;
    const int tid = threadIdx.x;
    const int lane = tid & 63, wave = tid >> 6;
    const int wm = (wave >> 1) * 64, wn = (wave & 1) * 64;
    const int m0 = blockIdx.y * 128, n0 = blockIdx.x * 128;
    const int fm = lane & 15, quad = lane >> 4;
    const int fsw = (fm >> 1) & 3;
    const int fcol = ((quad ^ fsw) * 8);

    f32x4 acc[4][4];
    #pragma unroll
    for (int i = 0; i < 4; ++i)
        #pragma unroll
        for (int j = 0; j < 4; ++j) acc[i][j] = (f32x4){0.f, 0.f, 0.f, 0.f};

    const int lrow = lane >> 2;
    const int lchunk = lane & 3;
    const int schunk = lchunk ^ ((lrow >> 1) & 3);

    for (int k0 = 0; k0 < Kd; k0 += 32) {
        __syncthreads();
        #pragma unroll
        for (int p = 0; p < 2; ++p) {
            const int row = wave * 32 + p * 16 + lrow;
            const size_t ga = (size_t)(m0 + row) * Kd + k0 + schunk * 8;
            const size_t gb = (size_t)(n0 + row) * Kd + k0 + schunk * 8;
            const int ls = row * 32 + lchunk * 8;
            async_copy16(&Ah[ga], &As_h[ls]);
            async_copy16(&Bh[gb], &Bs_h[ls]);
        }
        __syncthreads();

        bf16x8 ah[4], bh[4];
        #pragma unroll
        for (int t = 0; t < 4; ++t) {
            ah[t] = *reinterpret_cast<const bf16x8*>(&As_h[(wm + t * 16 + fm) * 32 + fcol]);
            bh[t] = *reinterpret_cast<const bf16x8*>(&Bs_h[(wn + t * 16 + fm) * 32 + fcol]);
        }
        #pragma unroll
        for (int mt = 0; mt < 4; ++mt)
            #pragma unroll
            for (int nt = 0; nt < 4; ++nt)
                acc[mt][nt] = __builtin_amdgcn_mfma_f32_16x16x32_bf16(
                    ah[mt], bh[nt], acc[mt][nt], 0, 0, 0);
    }

    const int gn0 = n0 + wn;          // wave col base, 64-aligned
    const int l15 = lane & 15;

    if (gn0 < 1280) {
        // ---- Q or K: per-head RMSNorm + RoPE + split ----
        const bool isQ = (gn0 < 1024);
        const float* nsc = isQ ? qn : kn;
        const float osc = isQ ? 0.125f : 1.0f;
        u16* __restrict__ oh = isQ ? Qbh : Kbh;
        u16* __restrict__ ol = isQ ? Qbl : Kbl;
        const int rowstride = isQ ? 1024 : 256;
        const int colbase = isQ ? gn0 : gn0 - 1024;
        float sc[4];
        #pragma unroll
        for (int nt = 0; nt < 4; ++nt) sc[nt] = nsc[nt * 16 + l15];

        #pragma unroll
        for (int mt = 0; mt < 4; ++mt)
            #pragma unroll
            for (int r = 0; r < 4; ++r) {
                const int bt = m0 + wm + mt * 16 + quad * 4 + r;
                float v[4];
                #pragma unroll
                for (int nt = 0; nt < 4; ++nt) v[nt] = acc[mt][nt][r];
                float ss = v[0] * v[0] + v[1] * v[1] + v[2] * v[2] + v[3] * v[3];
                #pragma unroll
                for (int off = 1; off < 16; off <<= 1)
                    ss += __shfl_xor(ss, off, 16);
                const float rstd = rsqrtf(ss * (1.0f / 64.0f) + EPSF);
                float nv[4];
                #pragma unroll
                for (int nt = 0; nt < 4; ++nt) nv[nt] = v[nt] * rstd * sc[nt];
                const float s0 = sinp[bt * 32 + l15];
                const float c0 = cosp[bt * 32 + l15];
                const float s1 = sinp[bt * 32 + 16 + l15];
                const float c1 = cosp[bt * 32 + 16 + l15];
                float o[4];
                o[0] = (nv[0] * c0 - nv[2] * s0) * osc;
                o[1] = (nv[1] * c1 - nv[3] * s1) * osc;
                o[2] = (nv[2] * c0 + nv[0] * s0) * osc;
                o[3] = (nv[3] * c1 + nv[1] * s1) * osc;
                #pragma unroll
                for (int nt = 0; nt < 4; ++nt) {
                    const size_t off = (size_t)bt * rowstride + colbase + nt * 16 + l15;
                    const u16 hi = f2bf(o[nt]);
                    oh[off] = hi;
                    ol[off] = f2bf(o[nt] - bf2f(hi));
                }
            }
    } else {
        // ---- V: plain bf16 split to [token][256] ----
        const int colbase = gn0 - 1280;
        #pragma unroll
        for (int mt = 0; mt < 4; ++mt)
            #pragma unroll
            for (int r = 0; r < 4; ++r) {
                const int bt = m0 + wm + mt * 16 + quad * 4 + r;
                #pragma unroll
                for (int nt = 0; nt < 4; ++nt) {
                    const float v = acc[mt][nt][r];
                    const size_t off = (size_t)bt * 256 + colbase + nt * 16 + l15;
                    const u16 hi = f2bf(v);
                    Vbh[off] = hi;
                    Vbl[off] = f2bf(v - bf2f(hi));
                }
            }
    }
}

// ---------------------------------------------------------------------------
// V transpose, bf16 in -> bf16 out: Vb[token][g*64+d] -> Vt[(b*4+g)*64+d][t].
// Grid (T/64, B*G).
// ---------------------------------------------------------------------------
__global__ __launch_bounds__(256) void vtrans_bf16_kernel(
    const u16* __restrict__ Vbh, const u16* __restrict__ Vbl,
    u16* __restrict__ Vth, u16* __restrict__ Vtl)
{
    __shared__ u16 th[64 * 66];
    __shared__ u16 tl[64 * 66];
    const int t0 = blockIdx.x * 64;
    const int bg = blockIdx.y;
    const int b = bg >> 2, g = bg & 3;
    const int tid = threadIdx.x;

    const int row = tid >> 2;
    const int cc = (tid & 3) * 16;
    const size_t src = (size_t)(b * Tseq + t0 + row) * 256 + g * 64 + cc;
    *reinterpret_cast<uint4*>(&th[row * 66 + cc]) =
        *reinterpret_cast<const uint4*>(&Vbh[src]);
    *reinterpret_cast<uint4*>(&th[row * 66 + cc + 8]) =
        *reinterpret_cast<const uint4*>(&Vbh[src + 8]);
    *reinterpret_cast<uint4*>(&tl[row * 66 + cc]) =
        *reinterpret_cast<const uint4*>(&Vbl[src]);
    *reinterpret_cast<uint4*>(&tl[row * 66 + cc + 8]) =
        *reinterpret_cast<const uint4*>(&Vbl[src + 8]);
    __syncthreads();

    const int d = tid >> 2;
    const int tq = (tid & 3) * 16;
    u16 oh[16], ol[16];
    #pragma unroll
    for (int i = 0; i < 16; ++i) {
        oh[i] = th[(tq + i) * 66 + d];
        ol[i] = tl[(tq + i) * 66 + d];
    }
    const size_t dst = (size_t)(bg * 64 + d) * Tseq + t0 + tq;
    *reinterpret_cast<uint4*>(&Vth[dst])     = *reinterpret_cast<uint4*>(&oh[0]);
    *reinterpret_cast<uint4*>(&Vth[dst + 8]) = *reinterpret_cast<uint4*>(&oh[8]);
    *reinterpret_cast<uint4*>(&Vtl[dst])     = *reinterpret_cast<uint4*>(&ol[0]);
    *reinterpret_cast<uint4*>(&Vtl[dst + 8]) = *reinterpret_cast<uint4*>(&ol[8]);
}

// ---------------------------------------------------------------------------
// Fused gate/up MFMA GEMM + silu epilogue (unchanged from r7).
// ---------------------------------------------------------------------------
__global__ __launch_bounds__(256, 2) void mfma_gateup_kernel(
    const u16* __restrict__ Ah, const u16* __restrict__ Al,
    const u16* __restrict__ Bg, const u16* __restrict__ Bu,
    u16* __restrict__ FF, int M, int N, int Kd)
{
    __shared__ u16 As_h[128 * 32];
    __shared__ u16 As_l[128 * 32];
    __shared__ u16 Gs[64 * 32];
    __shared__ u16 Us[64 * 32];

    const int tid = threadIdx.x;
    const int lane = tid & 63, wave = tid >> 6;
    const int wm = (wave >> 1) * 64, wn = (wave & 1) * 32;
    const int m0 = blockIdx.y * 128, n0 = blockIdx.x * 64;
    const int fm = lane & 15, quad = lane >> 4;
    const int fsw = (fm >> 1) & 3;
    const int fcol = ((quad ^ fsw) * 8);

    f32x4 accg[4][2], accu[4][2];
    #pragma unroll
    for (int i = 0; i < 4; ++i)
        #pragma unroll
        for (int j = 0; j < 2; ++j) {
            accg[i][j] = (f32x4){0.f, 0.f, 0.f, 0.f};
            accu[i][j] = (f32x4){0.f, 0.f, 0.f, 0.f};
        }

    const int lrow = lane >> 2;
    const int lchunk = lane & 3;
    const int schunk = lchunk ^ ((lrow >> 1) & 3);

    for (int k0 = 0; k0 < Kd; k0 += 32) {
        __syncthreads();
        #pragma unroll
        for (int p = 0; p < 2; ++p) {
            const int row = p * 64 + wave * 16 + lrow;
            const size_t ga = (size_t)(m0 + row) * Kd + k0 + schunk * 8;
            const int ls = row * 32 + lchunk * 8;
            async_copy16(&Ah[ga], &As_h[ls]);
            async_copy16(&Al[ga], &As_l[ls]);
        }
        {
            const int row = wave * 16 + lrow;
            const size_t gb = (size_t)(n0 + row) * Kd + k0 + schunk * 8;
            const int ls = row * 32 + lchunk * 8;
            async_copy16(&Bg[gb], &Gs[ls]);
            async_copy16(&Bu[gb], &Us[ls]);
        }
        __syncthreads();

        bf16x8 a_h[4], a_l[4], g_f[2], u_f[2];
        #pragma unroll
        for (int t = 0; t < 4; ++t) {
            const int ra = (wm + t * 16 + fm) * 32 + fcol;
            a_h[t] = *reinterpret_cast<const bf16x8*>(&As_h[ra]);
            a_l[t] = *reinterpret_cast<const bf16x8*>(&As_l[ra]);
        }
        #pragma unroll
        for (int j = 0; j < 2; ++j) {
            const int rb = (wn + j * 16 + fm) * 32 + fcol;
            g_f[j] = *reinterpret_cast<const bf16x8*>(&Gs[rb]);
            u_f[j] = *reinterpret_cast<const bf16x8*>(&Us[rb]);
        }
        #pragma unroll
        for (int mt = 0; mt < 4; ++mt)
            #pragma unroll
            for (int nt = 0; nt < 2; ++nt) {
                accg[mt][nt] = __builtin_amdgcn_mfma_f32_16x16x32_bf16(
                    a_h[mt], g_f[nt], accg[mt][nt], 0, 0, 0);
                accg[mt][nt] = __builtin_amdgcn_mfma_f32_16x16x32_bf16(
                    a_l[mt], g_f[nt], accg[mt][nt], 0, 0, 0);
                accu[mt][nt] = __builtin_amdgcn_mfma_f32_16x16x32_bf16(
                    a_h[mt], u_f[nt], accu[mt][nt], 0, 0, 0);
                accu[mt][nt] = __builtin_amdgcn_mfma_f32_16x16x32_bf16(
                    a_l[mt], u_f[nt], accu[mt][nt], 0, 0, 0);
            }
    }

    const int cr = (lane >> 4) * 4, cn = lane & 15;
    #pragma unroll
    for (int mt = 0; mt < 4; ++mt)
        #pragma unroll
        for (int nt = 0; nt < 2; ++nt)
            #pragma unroll
            for (int r = 0; r < 4; ++r) {
                const int gm = m0 + wm + mt * 16 + cr + r;
                const int gn = n0 + wn + nt * 16 + cn;
                const float g = accg[mt][nt][r];
                const float ff = (g / (1.0f + __expf(-g))) * accu[mt][nt][r];
                FF[(size_t)gm * N + gn] = f2bf(ff);
            }
}

// ---------------------------------------------------------------------------
// MFMA flash attention v3 (unchanged).
// ---------------------------------------------------------------------------
__global__ __launch_bounds__(256) void attn_mfma_kernel(
    const u16* __restrict__ Qh, const u16* __restrict__ Ql,
    const u16* __restrict__ Kh, const u16* __restrict__ Kl,
    const u16* __restrict__ Vth, const u16* __restrict__ Vtl,
    u16* __restrict__ AOh, u16* __restrict__ AOl)
{
    __shared__ u16 KsH[64 * 72];
    __shared__ u16 KsL[64 * 72];
    __shared__ u16 VsH[64 * 72];
    __shared__ u16 VsL[64 * 72];
    __shared__ u16 Ps[4][16 * 72];

    const int tid = threadIdx.x;
    const int wave = tid >> 6, lane = tid & 63;
    const int l15 = lane & 15, quad = lane >> 4;

    const int bg = blockIdx.x & 7;
    const int b = bg >> 2, g = bg & 3;
    const int win = 127 - (blockIdx.x >> 3);
    const int t0 = win * 16;
    const int h = g * 4 + wave;

    bf16x8 qh[2], ql[2];
    {
        const size_t qrow = (size_t)(b * Tseq + t0 + l15) * 1024 + h * 64;
        #pragma unroll
        for (int ks = 0; ks < 2; ++ks) {
            qh[ks] = *reinterpret_cast<const bf16x8*>(&Qh[qrow + ks * 32 + quad * 8]);
            ql[ks] = *reinterpret_cast<const bf16x8*>(&Ql[qrow + ks * 32 + quad * 8]);
        }
    }

    const int srow = tid >> 2;
    const int scol = (tid & 3) * 16;
    const size_t kgb = (size_t)(b * Tseq) * 256 + g * 64 + scol;
    const size_t vgb = (size_t)(bg * 64 + srow) * Tseq + scol;

    const int nit = t0 / 64 + 1;

    uint4 ck0, ck1, cl0, cl1, cv0, cv1, cw0, cw1;
    {
        const size_t ka = kgb + (size_t)srow * 256;
        ck0 = *reinterpret_cast<const uint4*>(&Kh[ka]);
        ck1 = *reinterpret_cast<const uint4*>(&Kh[ka + 8]);
        cl0 = *reinterpret_cast<const uint4*>(&Kl[ka]);
        cl1 = *reinterpret_cast<const uint4*>(&Kl[ka + 8]);
        cv0 = *reinterpret_cast<const uint4*>(&Vth[vgb]);
        cv1 = *reinterpret_cast<const uint4*>(&Vth[vgb + 8]);
        cw0 = *reinterpret_cast<const uint4*>(&Vtl[vgb]);
        cw1 = *reinterpret_cast<const uint4*>(&Vtl[vgb + 8]);
    }

    f32x4 oacc[4];
    #pragma unroll
    for (int nt = 0; nt < 4; ++nt) oacc[nt] = (f32x4){0.f, 0.f, 0.f, 0.f};
    float m_r[4], l_r[4];
    #pragma unroll
    for (int r = 0; r < 4; ++r) { m_r[r] = -1e30f; l_r[r] = 0.0f; }

    u16* psw = &Ps[wave][0];
    const int lb = srow * 72 + scol;

    for (int it = 0; it < nit; ++it) {
        const int s0 = it * 64;
        const bool diag = (it == nit - 1);

        __syncthreads();
        *reinterpret_cast<uint4*>(&KsH[lb])     = ck0;
        *reinterpret_cast<uint4*>(&KsH[lb + 8]) = ck1;
        *reinterpret_cast<uint4*>(&KsL[lb])     = cl0;
        *reinterpret_cast<uint4*>(&KsL[lb + 8]) = cl1;
        *reinterpret_cast<uint4*>(&VsH[lb])     = cv0;
        *reinterpret_cast<uint4*>(&VsH[lb + 8]) = cv1;
        *reinterpret_cast<uint4*>(&VsL[lb])     = cw0;
        *reinterpret_cast<uint4*>(&VsL[lb + 8]) = cw1;
        if (it + 1 < nit) {
            const size_t ka = kgb + (size_t)(s0 + 64 + srow) * 256;
            ck0 = *reinterpret_cast<const uint4*>(&Kh[ka]);
            ck1 = *reinterpret_cast<const uint4*>(&Kh[ka + 8]);
            cl0 = *reinterpret_cast<const uint4*>(&Kl[ka]);
            cl1 = *reinterpret_cast<const uint4*>(&Kl[ka + 8]);
            const size_t va = vgb + s0 + 64;
            cv0 = *reinterpret_cast<const uint4*>(&Vth[va]);
            cv1 = *reinterpret_cast<const uint4*>(&Vth[va + 8]);
            cw0 = *reinterpret_cast<const uint4*>(&Vtl[va]);
            cw1 = *reinterpret_cast<const uint4*>(&Vtl[va + 8]);
        }
        __syncthreads();

        f32x4 sacc[4];
        #pragma unroll
        for (int nt = 0; nt < 4; ++nt) sacc[nt] = (f32x4){0.f, 0.f, 0.f, 0.f};

        #pragma unroll
        for (int ks = 0; ks < 2; ++ks) {
            bf16x8 kfh[4], kfl[4];
            #pragma unroll
            for (int nt = 0; nt < 4; ++nt) {
                const int a = (nt * 16 + l15) * 72 + ks * 32 + quad * 8;
                kfh[nt] = *reinterpret_cast<const bf16x8*>(&KsH[a]);
                kfl[nt] = *reinterpret_cast<const bf16x8*>(&KsL[a]);
            }
            #pragma unroll
            for (int nt = 0; nt < 4; ++nt) {
                sacc[nt] = __builtin_amdgcn_mfma_f32_16x16x32_bf16(qh[ks], kfh[nt], sacc[nt], 0, 0, 0);
                sacc[nt] = __builtin_amdgcn_mfma_f32_16x16x32_bf16(ql[ks], kfh[nt], sacc[nt], 0, 0, 0);
                sacc[nt] = __builtin_amdgcn_mfma_f32_16x16x32_bf16(qh[ks], kfl[nt], sacc[nt], 0, 0, 0);
            }
        }

        if (diag) {
            #pragma unroll
            for (int nt = 0; nt < 4; ++nt) {
                const int sg = s0 + nt * 16 + l15;
                #pragma unroll
                for (int r = 0; r < 4; ++r)
                    if (sg > t0 + quad * 4 + r) sacc[nt][r] = -1e30f;
            }
        }

        #pragma unroll
        for (int r = 0; r < 4; ++r) {
            float mx = fmaxf(fmaxf(sacc[0][r], sacc[1][r]),
                             fmaxf(sacc[2][r], sacc[3][r]));
            #pragma unroll
            for (int off = 1; off < 16; off <<= 1)
                mx = fmaxf(mx, __shfl_xor(mx, off, 16));
            const float mnew = fmaxf(m_r[r], mx);
            const float alpha = __expf(m_r[r] - mnew);
            m_r[r] = mnew;

            float rs = 0.0f;
            #pragma unroll
            for (int nt = 0; nt < 4; ++nt) {
                const float p = __expf(sacc[nt][r] - mnew);
                sacc[nt][r] = p;
                rs += p;
            }
            #pragma unroll
            for (int off = 1; off < 16; off <<= 1)
                rs += __shfl_xor(rs, off, 16);
            l_r[r] = l_r[r] * alpha + rs;
            #pragma unroll
            for (int nt = 0; nt < 4; ++nt) oacc[nt][r] *= alpha;
            #pragma unroll
            for (int nt = 0; nt < 4; ++nt)
                psw[(quad * 4 + r) * 72 + nt * 16 + l15] = f2bf(sacc[nt][r]);
        }

        #pragma unroll
        for (int ks = 0; ks < 2; ++ks) {
            const bf16x8 pa = *reinterpret_cast<const bf16x8*>(
                &psw[l15 * 72 + ks * 32 + quad * 8]);
            bf16x8 vfh[4], vfl[4];
            #pragma unroll
            for (int nt = 0; nt < 4; ++nt) {
                const int a = (nt * 16 + l15) * 72 + ks * 32 + quad * 8;
                vfh[nt] = *reinterpret_cast<const bf16x8*>(&VsH[a]);
                vfl[nt] = *reinterpret_cast<const bf16x8*>(&VsL[a]);
            }
            #pragma unroll
            for (int nt = 0; nt < 4; ++nt) {
                oacc[nt] = __builtin_amdgcn_mfma_f32_16x16x32_bf16(pa, vfh[nt], oacc[nt], 0, 0, 0);
                oacc[nt] = __builtin_amdgcn_mfma_f32_16x16x32_bf16(pa, vfl[nt], oacc[nt], 0, 0, 0);
            }
        }
    }

    #pragma unroll
    for (int r = 0; r < 4; ++r) {
        const float inv = 1.0f / l_r[r];
        const size_t orow = (size_t)(b * Tseq + t0 + quad * 4 + r) * 1024 + h * 64;
        #pragma unroll
        for (int nt = 0; nt < 4; ++nt) {
            const float o = oacc[nt][r] * inv;
            const u16 hi = f2bf(o);
            AOh[orow + nt * 16 + l15] = hi;
            AOl[orow + nt * 16 + l15] = f2bf(o - bf2f(hi));
        }
    }
}

// ---------------------------------------------------------------------------
// Host launcher
// ---------------------------------------------------------------------------
extern "C" void kernel_launch(void* const* d_in, const int* in_sizes, int n_in,
                              void* d_out, int out_size, void* d_ws,
                              size_t ws_size, hipStream_t stream)
{
    const float* hidden = (const float*)d_in[0];
    const float* sinp   = (const float*)d_in[1];
    const float* cosp   = (const float*)d_in[2];
    // d_in[3] = mask — causal, handled analytically
    const float* ln1    = (const float*)d_in[4];
    const float* ln2    = (const float*)d_in[5];
    const float* qn     = (const float*)d_in[6];
    const float* kn     = (const float*)d_in[7];
    const float* q_w    = (const float*)d_in[8];
    const float* k_w    = (const float*)d_in[9];
    const float* v_w    = (const float*)d_in[10];
    const float* o_w    = (const float*)d_in[11];
    const float* gate_w = (const float*)d_in[12];
    const float* up_w   = (const float*)d_in[13];
    const float* down_w = (const float*)d_in[14];
    float* out = (float*)d_out;

    // ---- workspace layout (115.0 MB; proven capacity >= 120 MB) ----
    char* base = (char*)d_ws;
    u16*   OTh  = (u16*)(base);                //  2 MB
    u16*   OTl  = (u16*)(base + 2097152);      //  2 MB
    u16*   GTh  = (u16*)(base + 4194304);      //  8 MB
    u16*   UTh  = (u16*)(base + 12582912);     //  8 MB
    u16*   DTh  = (u16*)(base + 20971520);     //  8 MB
    u16*   QKVT = (u16*)(base + 29360128);     //  3 MB (weights, live through qkv_fused)
    u16*   Xh   = (u16*)(base + 32505856);     //  8 MB
    u16*   Qbh  = (u16*)(base + 40894464);     //  8 MB
    u16*   Qbl  = (u16*)(base + 49283072);     //  8 MB
    u16*   Kbh  = (u16*)(base + 57671680);     //  2 MB
    u16*   Kbl  = (u16*)(base + 59768832);     //  2 MB
    u16*   Vbh  = (u16*)(base + 61865984);     //  2 MB
    u16*   Vbl  = (u16*)(base + 63963136);     //  2 MB
    u16*   Vth  = (u16*)(base + 66060288);     //  2 MB
    u16*   Vtl  = (u16*)(base + 68157440);     //  2 MB
    u16*   AOh  = (u16*)(base + 70254592);     //  8 MB
    u16*   AOl  = (u16*)(base + 78643200);     //  8 MB
    u16*   FFh  = (u16*)(base + 87031808);     // 32 MB  (end 120,586,240)

    // aliases (lifetime-checked):
    float* H2 = (float*)Qbh;                   // 16 MB over Qbh/Qbl (Q dead post-attn)
    u16*   Yh = Kbh;                           // 8 MB over Kb/Vb (dead post-attn)
    u16*   Yl = Vth;                           // 8 MB over Vt + first 4MB of AOh (dead post-o-proj)

    // 0. weight prep (4 launches)
    wprep_qkv_kernel<<<dim3(48, 32), 256, 0, stream>>>(q_w, k_w, v_w, QKVT);
    wprep_kernel<1><<<dim3(32, 32), 256, 0, stream>>>(o_w, OTh, OTl, 1024, 1024);
    wprep_gu_kernel<<<dim3(128, 32, 2), 256, 0, stream>>>(gate_w, up_w, GTh, UTh);
    wprep_kernel<0><<<dim3(32, 128), 256, 0, stream>>>(down_w, DTh, nullptr, 4096, 1024);

    // 1. x = rmsnorm(hidden, ln1) -> bf16
    rmsnorm_split_kernel<0><<<Mrows, 256, 0, stream>>>(hidden, ln1, Xh, nullptr);

    // 2. fused qkv projection + qknorm + rope + split (no fp32 QKV round-trip)
    qkv_fused_kernel<<<dim3(12, 32), 256, 0, stream>>>(
        Xh, QKVT, qn, kn, sinp, cosp, Qbh, Qbl, Kbh, Kbl, Vbh, Vbl);

    // 3. V transpose (bf16 -> bf16)
    vtrans_bf16_kernel<<<dim3(Tseq / 64, Bsz * Gg), 256, 0, stream>>>(
        Vbh, Vbl, Vth, Vtl);

    // 4. MFMA flash attention -> AO bf16 hi/lo
    attn_mfma_kernel<<<Bsz * Gg * (Tseq / 16), 256, 0, stream>>>(
        Qbh, Qbl, Kbh, Kbl, Vth, Vtl, AOh, AOl);

    // 5. hidden2 = hidden + attn @ o_w  (split x split)
    mfma_gemm_kernel<1, 1, 1><<<dim3(8, 32), 256, 0, stream>>>(
        AOh, AOl, OTh, OTl, hidden, H2, Mrows, Dmod, 1024);

    // 6. y = rmsnorm(hidden2, ln2) -> bf16 hi/lo
    rmsnorm_split_kernel<1><<<Mrows, 256, 0, stream>>>(H2, ln2, Yh, Yl);

    // 7. ff = silu(y@gate_w) * (y@up_w) -> FF bf16  (128x64 tiles)
    mfma_gateup_kernel<<<dim3(Ff / 64, Mrows / 128), 256, 0, stream>>>(
        Yh, Yl, GTh, UTh, FFh, Mrows, Ff, 1024);

    // 8. out = hidden2 + ff @ down_w
    mfma_gemm_kernel<0, 0, 1><<<dim3(8, 32), 256, 0, stream>>>(
        FFh, nullptr, DTh, nullptr, H2, out, Mrows, Dmod, 4096);
}